// Round 1
// baseline (739.315 us; speedup 1.0000x reference)
//
#include <hip/hip_runtime.h>
#include <hip/hip_bf16.h>
#include <math.h>

// TMSA R7: R6's LDS-fed flash attention WITHOUT the occupancy bound.
// R6 lesson: __launch_bounds__(NK,4) on gfx950 caps the unified VGPR/AGPR
// file at 128 -> with 64 AGPRs live the arch side fell to 64 and the kt-loop
// spilled to scratch (WRITE_SIZE 24MB->233MB). This kernel needs ~150 VGPRs;
// let the compiler have them (R5 compiled 156, zero spill).
//
// ws (bytes), guard 110,100,480:
//   attn phase: Hb bf16 [0,31457280) | QKVc bf16 [31457280,78643200)
//               XOUTc bf16 [78643200,110100480)
//   mlp  phase: TMP fp32 [0,62914560) (d2d copy of X2) |
//               H2c bf16 [62914560,78643200) | HIDc bf16 [78643200,110100480)

typedef __attribute__((ext_vector_type(8))) short bf16x8;
typedef __attribute__((ext_vector_type(4))) float f32x4;

#define SCALE2 (0.22360679774997896f * 1.44269504088896340f)  // d^-0.5 * log2(e)
#define CHROWS 65536
#define QPLANE 7864320u   // 65536*120 elems per q/k/v plane (chunk)

union B8U { bf16x8 v; uint4 u4; uint2 u2[2]; unsigned u[4]; short s[8]; };

__device__ __forceinline__ short bf16b(float f) {
    __hip_bfloat16 h = __float2bfloat16(f);
    return *reinterpret_cast<short*>(&h);
}
__device__ __forceinline__ float bf2f(short s) {
    return __uint_as_float(((unsigned)(unsigned short)s) << 16);
}
__device__ __forceinline__ unsigned packbf(float a, float b) {
    return (unsigned)(unsigned short)bf16b(a) |
           ((unsigned)(unsigned short)bf16b(b) << 16);
}

// partitioned row r -> global row g
__device__ __forceinline__ int rev_row(int r) {
    int w = r >> 8, t = r & 255;
    int w8 = w & 7, h8 = (w >> 3) & 7, d2 = (w >> 6) & 1, n2 = w >> 7;
    int www = t & 7, hh = (t >> 3) & 7, dd = (t >> 6) & 1, nn = t >> 7;
    int n = n2 * 2 + nn, d = d2 * 2 + dd;
    int Hc = h8 * 8 + hh, Wc = w8 * 8 + www;
    return ((n * 4 + d) << 12) + (Hc << 6) + Wc;
}
// global row g -> partitioned row
__device__ __forceinline__ int part_row(int g) {
    int ww = g & 63, hh = (g >> 6) & 63, d = (g >> 12) & 3, n = g >> 14;
    int w = ((n >> 1) * 2 + (d >> 1)) * 64 + ((hh >> 3) << 3) + (ww >> 3);
    int t = (((n & 1) * 2 + (d & 1)) << 6) + ((hh & 7) << 3) + (ww & 7);
    return (w << 8) + t;
}
__device__ __forceinline__ float gelu_exact(float x) {
    return 0.5f * x * (1.0f + erff(x * 0.70710678118654752f));
}

// load B-frag from a 20-elem bf16 row (stride 20), k = quad*8..+7, zero-padded.
__device__ __forceinline__ bf16x8 load_frag20(const short* row, int quad) {
    B8U r;
    const uint2* p = (const uint2*)(row + quad * 8);
    r.u2[0] = p[0]; r.u2[1] = p[1];
    if (quad == 2) { r.u[2] = 0; r.u[3] = 0; }
    else if (quad == 3) { r.u[0] = r.u[1] = r.u[2] = r.u[3] = 0; }
    return r.v;
}

// ---------------- LayerNorm (C=120) fp32 in -> bf16 out ---------------------
template <bool REMAP>
__global__ __launch_bounds__(256) void ln_kernel(const float* __restrict__ in,
                                                 const float* __restrict__ w,
                                                 const float* __restrict__ b,
                                                 short* __restrict__ out) {
    int row  = blockIdx.x * 4 + (threadIdx.x >> 6);
    int lane = threadIdx.x & 63;
    const float* xr = in + (size_t)row * 120;
    float2 v = make_float2(0.f, 0.f);
    if (lane < 60) v = *(const float2*)(xr + lane * 2);
    float s = v.x + v.y;
#pragma unroll
    for (int off = 32; off; off >>= 1) s += __shfl_down(s, off, 64);
    s = __shfl(s, 0, 64);
    float mean = s * (1.f / 120.f);
    float dx = v.x - mean, dy = v.y - mean;
    float q = (lane < 60) ? (dx * dx + dy * dy) : 0.f;
#pragma unroll
    for (int off = 32; off; off >>= 1) q += __shfl_down(q, off, 64);
    q = __shfl(q, 0, 64);
    float rstd = rsqrtf(q * (1.f / 120.f) + 1e-5f);
    int orow = REMAP ? part_row(row) : row;
    if (lane < 60) {
        float2 wv = *(const float2*)(w + lane * 2);
        float2 bv = *(const float2*)(b + lane * 2);
        unsigned u = packbf(dx * rstd * wv.x + bv.x, dy * rstd * wv.y + bv.y);
        *(unsigned*)(out + (size_t)orow * 120 + lane * 2) = u;
    }
}

// ------------- MFMA GEMM: out = A(M x K, bf16) @ W(N x K, fp32)^T + bias ----
// MODE: 0 QKV scatter (q pre-scaled by SCALE2) | 1 proj(+x res -> X2 fp32)
//       2 gelu bf16 | 3 multiply-into bf16 | 4 fc2(+TMP res -> d_out @rev_row)
template <int MODE, int K, int N>
__global__ __launch_bounds__(256) void mm(const short* __restrict__ A,
                                          const float* __restrict__ W,
                                          const float* __restrict__ bias,
                                          void* __restrict__ outp,
                                          const float* __restrict__ aux,
                                          int m0) {
    const int lane = threadIdx.x & 63, wave = threadIdx.x >> 6;
    const int quad = lane >> 4, l16 = lane & 15;
    const int bm = blockIdx.x * 128 + (wave >> 1) * 64;
    const int bn = blockIdx.y * 64 + (wave & 1) * 32;

    f32x4 acc[4][2];
#pragma unroll
    for (int i = 0; i < 4; ++i)
#pragma unroll
        for (int j = 0; j < 2; ++j) acc[i][j] = (f32x4){0.f, 0.f, 0.f, 0.f};

    const short* Ar[4];
#pragma unroll
    for (int i = 0; i < 4; ++i) Ar[i] = A + (size_t)(bm + i * 16 + l16) * K;
    const int n0 = bn + l16, n1 = bn + 16 + l16;
    const int nc0 = n0 < N ? n0 : N - 1;
    const int nc1 = n1 < N ? n1 : N - 1;
    const float* W0 = W + (size_t)nc0 * K;
    const float* W1 = W + (size_t)nc1 * K;

    const int KT = (K + 31) / 32;
#pragma unroll
    for (int kt = 0; kt < KT; ++kt) {
        int kk = kt * 32 + quad * 8;
        bool kok = kk < K;
        int kc = kok ? kk : 0;
        bf16x8 a[4], b0v, b1v;
#pragma unroll
        for (int i = 0; i < 4; ++i) a[i] = *(const bf16x8*)(Ar[i] + kc);
        {
            f32x4 w0 = *(const f32x4*)(W0 + kc);
            f32x4 w1 = *(const f32x4*)(W0 + kc + 4);
            b0v = (bf16x8){bf16b(w0.x), bf16b(w0.y), bf16b(w0.z), bf16b(w0.w),
                           bf16b(w1.x), bf16b(w1.y), bf16b(w1.z), bf16b(w1.w)};
            f32x4 w2 = *(const f32x4*)(W1 + kc);
            f32x4 w3 = *(const f32x4*)(W1 + kc + 4);
            b1v = (bf16x8){bf16b(w2.x), bf16b(w2.y), bf16b(w2.z), bf16b(w2.w),
                           bf16b(w3.x), bf16b(w3.y), bf16b(w3.z), bf16b(w3.w)};
        }
        if (!kok) {
            bf16x8 zz = {0, 0, 0, 0, 0, 0, 0, 0};
            a[0] = a[1] = a[2] = a[3] = b0v = b1v = zz;
        }
#pragma unroll
        for (int i = 0; i < 4; ++i) {
            acc[i][0] = __builtin_amdgcn_mfma_f32_16x16x32_bf16(a[i], b0v, acc[i][0], 0, 0, 0);
            acc[i][1] = __builtin_amdgcn_mfma_f32_16x16x32_bf16(a[i], b1v, acc[i][1], 0, 0, 0);
        }
    }

#pragma unroll
    for (int j = 0; j < 2; ++j) {
        const int n = j ? n1 : n0;
        if (n >= N) continue;
        const float bs = bias[n];
        int which = 0, head = 0, e = 0;
        if (MODE == 0) { which = n / 120; int hn = n % 120; head = hn / 20; e = hn % 20; }
#pragma unroll
        for (int i = 0; i < 4; ++i) {
#pragma unroll
            for (int r = 0; r < 4; ++r) {
                int m = bm + i * 16 + quad * 4 + r;
                float val = acc[i][j][r] + bs;
                if (MODE == 0) {
                    if (which == 0) val *= SCALE2;
                    int wl = m >> 8, t = m & 255;
                    ((short*)outp)[(size_t)which * QPLANE +
                                   ((size_t)((wl * 6 + head) * 256 + t)) * 20 + e] = bf16b(val);
                } else if (MODE == 1) {
                    int g = rev_row(m0 + m);
                    val += aux[(size_t)g * 120 + n];
                    ((float*)outp)[(size_t)(m0 + m) * 120 + n] = val;
                } else if (MODE == 2) {
                    ((short*)outp)[(size_t)m * 240 + n] = bf16b(gelu_exact(val));
                } else if (MODE == 3) {
                    size_t idx = (size_t)m * 240 + n;
                    short* o = (short*)outp;
                    o[idx] = bf16b(bf2f(o[idx]) * val);
                } else { // MODE 4: aux pre-offset by m0*120; scatter to d_out
                    int g = rev_row(m0 + m);
                    val += aux[(size_t)m * 120 + n];
                    ((float*)outp)[(size_t)g * 120 + n] = val;
                }
            }
        }
    }
}

// ---------------- MFMA flash attention, LDS-fed, zero-shuffle ----------------
// K staged to LDS in fragment order: frag (kt,f) for lane(quad,l16) at uint4
// index ((kt*2+f)*64 + quad*16 + l16)  -> consecutive-lane ds_read_b128.
// S^T = mfma(A=K[perm rows], B=Q): C regs are directly the P^T B-frag.
// No-max softmax (scale*log2e folded into q upstream); l reduced in epilogue.
// NOTE: no occupancy bound — needs ~150 VGPRs; capping spills (R6: 233MB scratch).
template <int NK, bool MUT>
__global__ __launch_bounds__(NK) void attn_flash(const short* __restrict__ qkv,
                                                 short* __restrict__ xout) {
    constexpr int NKT = NK / 32;
    constexpr int VSTR2 = NK + 4;                  // u32 stride (16B-aligned rows)
    __shared__ __align__(16) short Kf[NKT * 2 * 64 * 8];
    __shared__ __align__(16) unsigned Vt2[16 * VSTR2];
    const int b = blockIdx.x;
    int wl, hd, half;
    if (MUT) { half = b & 1; hd = (b >> 1) % 6; wl = b / 12; }
    else     { half = 0;     hd = b % 6;        wl = b / 6;  }
    const int tid  = threadIdx.x;
    const int lane = tid & 63, wave = tid >> 6;
    const int quad = lane >> 4, l16 = lane & 15;

    const size_t rb = (size_t)(wl * 6 + hd) * 256;
    const short* qpl = qkv + rb * 20;
    const short* kpl = qkv + (size_t)QPLANE + rb * 20;
    const short* vpl = qkv + 2 * (size_t)QPLANE + rb * 20;
    const int koff = MUT ? half * 128 : 0;
    const int qoff = MUT ? (1 - half) * 128 : 0;

    // ---- stage V^T (u32 dim-pairs) and K (fragment order) ----
    {
        const uint2* p = (const uint2*)(vpl + (size_t)(koff + tid) * 20);
        unsigned tmp[10];
#pragma unroll
        for (int i = 0; i < 5; ++i) ((uint2*)tmp)[i] = p[i];
#pragma unroll
        for (int i = 0; i < 10; ++i) Vt2[i * VSTR2 + tid] = tmp[i];
#pragma unroll
        for (int i = 10; i < 16; ++i) Vt2[i * VSTR2 + tid] = 0;

        int skt = tid >> 5, sf = (tid >> 4) & 1, sl = tid & 15;
        int srow = koff + skt * 32 + sf * 4 + ((sl >> 2) << 3) + (sl & 3);
        const uint2* kp = (const uint2*)(kpl + (size_t)srow * 20);
        uint2 k0 = kp[0], k1 = kp[1], k2 = kp[2], k3 = kp[3], k4 = kp[4];
        uint4* dst = (uint4*)Kf + ((skt * 2 + sf) * 64 + sl);
        dst[0]  = make_uint4(k0.x, k0.y, k1.x, k1.y);   // quad0: d0-7
        dst[16] = make_uint4(k2.x, k2.y, k3.x, k3.y);   // quad1: d8-15
        dst[32] = make_uint4(k4.x, k4.y, 0u, 0u);       // quad2: d16-23
        dst[48] = make_uint4(0u, 0u, 0u, 0u);           // quad3: pad
    }
    __syncthreads();

    // Q B-frags (pre-scaled by SCALE2 in mm<0>)
    bf16x8 bq[4];
#pragma unroll
    for (int nt = 0; nt < 4; ++nt)
        bq[nt] = load_frag20(qpl + (size_t)(qoff + wave * 64 + nt * 16 + l16) * 20, quad);

    const uint4* kfrag = (const uint4*)Kf + quad * 16 + l16;
    const unsigned sel = (l16 & 1) ? 0x07060302u : 0x05040100u;
    const unsigned* vbase0 = Vt2 + (l16 >> 1) * VSTR2;
    const unsigned* vbase1 = Vt2 + (8 + (l16 >> 1)) * VSTR2;

    f32x4 accO[4][2];
#pragma unroll
    for (int nt = 0; nt < 4; ++nt) {
        accO[nt][0] = (f32x4){0.f, 0.f, 0.f, 0.f};
        accO[nt][1] = (f32x4){0.f, 0.f, 0.f, 0.f};
    }
    float lst[4] = {0.f, 0.f, 0.f, 0.f};
    const f32x4 z4 = {0.f, 0.f, 0.f, 0.f};

#pragma unroll
    for (int kt = 0; kt < NKT; ++kt) {
        B8U ak0, ak1;
        ak0.u4 = kfrag[(kt * 2 + 0) * 64];
        ak1.u4 = kfrag[(kt * 2 + 1) * 64];
        B8U av0, av1;
        {
            uint4 va = *(const uint4*)(vbase0 + kt * 32 + quad * 8);
            uint4 vb = *(const uint4*)(vbase0 + kt * 32 + quad * 8 + 4);
            av0.u[0] = __builtin_amdgcn_perm(va.y, va.x, sel);
            av0.u[1] = __builtin_amdgcn_perm(va.w, va.z, sel);
            av0.u[2] = __builtin_amdgcn_perm(vb.y, vb.x, sel);
            av0.u[3] = __builtin_amdgcn_perm(vb.w, vb.z, sel);
            uint4 vc = *(const uint4*)(vbase1 + kt * 32 + quad * 8);
            uint4 vd = *(const uint4*)(vbase1 + kt * 32 + quad * 8 + 4);
            av1.u[0] = __builtin_amdgcn_perm(vc.y, vc.x, sel);
            av1.u[1] = __builtin_amdgcn_perm(vc.w, vc.z, sel);
            av1.u[2] = __builtin_amdgcn_perm(vd.y, vd.x, sel);
            av1.u[3] = __builtin_amdgcn_perm(vd.w, vd.z, sel);
        }
#pragma unroll
        for (int nt = 0; nt < 4; ++nt) {
            f32x4 s0 = __builtin_amdgcn_mfma_f32_16x16x32_bf16(ak0.v, bq[nt], z4, 0, 0, 0);
            f32x4 s1 = __builtin_amdgcn_mfma_f32_16x16x32_bf16(ak1.v, bq[nt], z4, 0, 0, 0);
            float p0 = __builtin_amdgcn_exp2f(s0[0]), p1 = __builtin_amdgcn_exp2f(s0[1]);
            float p2 = __builtin_amdgcn_exp2f(s0[2]), p3 = __builtin_amdgcn_exp2f(s0[3]);
            float p4 = __builtin_amdgcn_exp2f(s1[0]), p5 = __builtin_amdgcn_exp2f(s1[1]);
            float p6 = __builtin_amdgcn_exp2f(s1[2]), p7 = __builtin_amdgcn_exp2f(s1[3]);
            lst[nt] += ((p0 + p1) + (p2 + p3)) + ((p4 + p5) + (p6 + p7));
            B8U bp;   // P^T B-frag: j=0..3 <- s0 regs, j=4..7 <- s1 regs
            bp.u[0] = packbf(p0, p1);
            bp.u[1] = packbf(p2, p3);
            bp.u[2] = packbf(p4, p5);
            bp.u[3] = packbf(p6, p7);
            accO[nt][0] = __builtin_amdgcn_mfma_f32_16x16x32_bf16(av0.v, bp.v, accO[nt][0], 0, 0, 0);
            accO[nt][1] = __builtin_amdgcn_mfma_f32_16x16x32_bf16(av1.v, bp.v, accO[nt][1], 0, 0, 0);
        }
    }

    // epilogue: O^T C-layout (col l16=query, row quad*4+r=dim); reduce l over quads
#pragma unroll
    for (int nt = 0; nt < 4; ++nt) {
        float l = lst[nt];
        l += __shfl_xor(l, 16, 64);
        l += __shfl_xor(l, 32, 64);
        float inv = 1.f / l;
        int tok = (MUT ? half * 128 : 0) + wave * 64 + nt * 16 + l16;
        short* orow = xout + (size_t)(wl * 256 + tok) * 240 + (MUT ? hd * 20 : 120 + hd * 20);
        unsigned lo = packbf(accO[nt][0][0] * inv, accO[nt][0][1] * inv);
        unsigned hi2 = packbf(accO[nt][0][2] * inv, accO[nt][0][3] * inv);
        *(uint2*)(orow + quad * 4) = make_uint2(lo, hi2);
        if (quad == 0) {
            unsigned lo2 = packbf(accO[nt][1][0] * inv, accO[nt][1][1] * inv);
            unsigned hi3 = packbf(accO[nt][1][2] * inv, accO[nt][1][3] * inv);
            *(uint2*)(orow + 16) = make_uint2(lo2, hi3);
        }
    }
}

extern "C" void kernel_launch(void* const* d_in, const int* in_sizes, int n_in,
                              void* d_out, int out_size, void* d_ws, size_t ws_size,
                              hipStream_t stream) {
    const float* x          = (const float*)d_in[0];
    const float* norm1_w    = (const float*)d_in[1];
    const float* norm1_b    = (const float*)d_in[2];
    const float* qkv_self_w = (const float*)d_in[3];
    const float* qkv_self_b = (const float*)d_in[4];
    const float* qkv_mut_w  = (const float*)d_in[5];
    const float* qkv_mut_b  = (const float*)d_in[6];
    const float* proj_w     = (const float*)d_in[7];
    const float* proj_b     = (const float*)d_in[8];
    const float* norm2_w    = (const float*)d_in[9];
    const float* norm2_b    = (const float*)d_in[10];
    const float* fc11_w     = (const float*)d_in[11];
    const float* fc11_b     = (const float*)d_in[12];
    const float* fc12_w     = (const float*)d_in[13];
    const float* fc12_b     = (const float*)d_in[14];
    const float* fc2_w      = (const float*)d_in[15];
    const float* fc2_b      = (const float*)d_in[16];

    if (ws_size < 110100480u) return;

    char* wsb   = (char*)d_ws;
    short* Hb    = (short*)wsb;                  // 131072x120 bf16
    short* QKVc  = (short*)(wsb + 31457280);     // 3 planes, chunk
    short* XOUTc = (short*)(wsb + 78643200);     // 65536x240 bf16
    float* TMP   = (float*)wsb;                  // X2 copy, fp32 (MLP phase)
    short* H2c   = (short*)(wsb + 62914560);     // 65536x120 bf16
    short* HIDc  = (short*)(wsb + 78643200);     // 65536x240 bf16
    float* X2    = (float*)d_out;                // partitioned residual fp32
    float* out   = (float*)d_out;

    // 1. LN1 + window partition -> Hb (bf16)
    ln_kernel<true><<<32768, 256, 0, stream>>>(x, norm1_w, norm1_b, Hb);

    // 2. Attention phase: 2 chunks x 256 windows
    for (int c = 0; c < 2; ++c) {
        int m0 = c * CHROWS;
        const short* Ac = Hb + (size_t)m0 * 120;
        mm<0, 120, 360><<<dim3(512, 6), 256, 0, stream>>>(Ac, qkv_self_w, qkv_self_b,
                                                          QKVc, nullptr, 0);
        attn_flash<256, false><<<1536, 256, 0, stream>>>(QKVc, XOUTc);
        mm<0, 120, 360><<<dim3(512, 6), 256, 0, stream>>>(Ac, qkv_mut_w, qkv_mut_b,
                                                          QKVc, nullptr, 0);
        attn_flash<128, true><<<3072, 128, 0, stream>>>(QKVc, XOUTc);
        mm<1, 240, 120><<<dim3(512, 2), 256, 0, stream>>>(XOUTc, proj_w, proj_b,
                                                          X2, x, m0);
    }

    // 3. X2 -> TMP (frees d_out for scatter writes; residual source)
    hipMemcpyAsync(TMP, d_out, 62914560u, hipMemcpyDeviceToDevice, stream);

    // 4. MLP phase: 2 chunks x 65536 rows; fc2 scatters straight into d_out
    for (int c = 0; c < 2; ++c) {
        int m0 = c * CHROWS;
        ln_kernel<false><<<16384, 256, 0, stream>>>(TMP + (size_t)m0 * 120,
                                                    norm2_w, norm2_b, H2c);
        mm<2, 120, 240><<<dim3(512, 4), 256, 0, stream>>>(H2c, fc11_w, fc11_b,
                                                          HIDc, nullptr, 0);
        mm<3, 120, 240><<<dim3(512, 4), 256, 0, stream>>>(H2c, fc12_w, fc12_b,
                                                          HIDc, nullptr, 0);
        mm<4, 240, 120><<<dim3(512, 2), 256, 0, stream>>>(HIDc, fc2_w, fc2_b,
                                                          out, TMP + (size_t)m0 * 120, m0);
    }
}

// Round 2
// 671.988 us; speedup vs baseline: 1.1002x; 1.1002x over previous
//
#include <hip/hip_runtime.h>
#include <hip/hip_bf16.h>
#include <math.h>

// TMSA R8: attn_flash rework for occupancy + VALU cut.
//  - V-ones trick: V padding dim20 staged as bf16(1.0) -> PV MFMA accumulates
//    the softmax denominator l in accO[t][1][0] (quad1). Deletes lst[] adds +
//    shfl_xor reduce.
//  - nt split into 2 passes of 2 (acc live 32->16 VGPRs; Q frags reloaded per
//    pass with scalar-derived addresses - no runtime-indexed arrays).
//  - LDS 33.3KB -> 23.7KB: drop all-zero quad3 K slot (reads clamp to quad2;
//    aliased data is finite K values x bq=0), V^T rows>=11 clamp to ones-row
//    (feeds only unstored dims).
//  - mm_mlp: fused fc11+fc12 (shared A-frags), writes gelu(g)*v once; removes
//    the HIDc RMW pass and one H2c re-read.
//
// ws (bytes), guard 110,100,480:
//   attn phase: Hb bf16 [0,31457280) | QKVc bf16 [31457280,78643200)
//               XOUTc bf16 [78643200,110100480)
//   mlp  phase: TMP fp32 [0,62914560) (d2d copy of X2) |
//               H2c bf16 [62914560,78643200) | HIDc bf16 [78643200,110100480)

typedef __attribute__((ext_vector_type(8))) short bf16x8;
typedef __attribute__((ext_vector_type(4))) float f32x4;

#define SCALE2 (0.22360679774997896f * 1.44269504088896340f)  // d^-0.5 * log2(e)
#define CHROWS 65536
#define QPLANE 7864320u   // 65536*120 elems per q/k/v plane (chunk)

union B8U { bf16x8 v; uint4 u4; uint2 u2[2]; unsigned u[4]; short s[8]; };

__device__ __forceinline__ short bf16b(float f) {
    __hip_bfloat16 h = __float2bfloat16(f);
    return *reinterpret_cast<short*>(&h);
}
__device__ __forceinline__ float bf2f(short s) {
    return __uint_as_float(((unsigned)(unsigned short)s) << 16);
}
__device__ __forceinline__ unsigned packbf(float a, float b) {
    return (unsigned)(unsigned short)bf16b(a) |
           ((unsigned)(unsigned short)bf16b(b) << 16);
}

// partitioned row r -> global row g
__device__ __forceinline__ int rev_row(int r) {
    int w = r >> 8, t = r & 255;
    int w8 = w & 7, h8 = (w >> 3) & 7, d2 = (w >> 6) & 1, n2 = w >> 7;
    int www = t & 7, hh = (t >> 3) & 7, dd = (t >> 6) & 1, nn = t >> 7;
    int n = n2 * 2 + nn, d = d2 * 2 + dd;
    int Hc = h8 * 8 + hh, Wc = w8 * 8 + www;
    return ((n * 4 + d) << 12) + (Hc << 6) + Wc;
}
// global row g -> partitioned row
__device__ __forceinline__ int part_row(int g) {
    int ww = g & 63, hh = (g >> 6) & 63, d = (g >> 12) & 3, n = g >> 14;
    int w = ((n >> 1) * 2 + (d >> 1)) * 64 + ((hh >> 3) << 3) + (ww >> 3);
    int t = (((n & 1) * 2 + (d & 1)) << 6) + ((hh & 7) << 3) + (ww & 7);
    return (w << 8) + t;
}
__device__ __forceinline__ float gelu_exact(float x) {
    return 0.5f * x * (1.0f + erff(x * 0.70710678118654752f));
}

// load B-frag from a 20-elem bf16 row (stride 20), k = quad*8..+7, zero-padded.
__device__ __forceinline__ bf16x8 load_frag20(const short* row, int quad) {
    B8U r;
    const uint2* p = (const uint2*)(row + quad * 8);
    r.u2[0] = p[0]; r.u2[1] = p[1];
    if (quad == 2) { r.u[2] = 0; r.u[3] = 0; }
    else if (quad == 3) { r.u[0] = r.u[1] = r.u[2] = r.u[3] = 0; }
    return r.v;
}

// ---------------- LayerNorm (C=120) fp32 in -> bf16 out ---------------------
template <bool REMAP>
__global__ __launch_bounds__(256) void ln_kernel(const float* __restrict__ in,
                                                 const float* __restrict__ w,
                                                 const float* __restrict__ b,
                                                 short* __restrict__ out) {
    int row  = blockIdx.x * 4 + (threadIdx.x >> 6);
    int lane = threadIdx.x & 63;
    const float* xr = in + (size_t)row * 120;
    float2 v = make_float2(0.f, 0.f);
    if (lane < 60) v = *(const float2*)(xr + lane * 2);
    float s = v.x + v.y;
#pragma unroll
    for (int off = 32; off; off >>= 1) s += __shfl_down(s, off, 64);
    s = __shfl(s, 0, 64);
    float mean = s * (1.f / 120.f);
    float dx = v.x - mean, dy = v.y - mean;
    float q = (lane < 60) ? (dx * dx + dy * dy) : 0.f;
#pragma unroll
    for (int off = 32; off; off >>= 1) q += __shfl_down(q, off, 64);
    q = __shfl(q, 0, 64);
    float rstd = rsqrtf(q * (1.f / 120.f) + 1e-5f);
    int orow = REMAP ? part_row(row) : row;
    if (lane < 60) {
        float2 wv = *(const float2*)(w + lane * 2);
        float2 bv = *(const float2*)(b + lane * 2);
        unsigned u = packbf(dx * rstd * wv.x + bv.x, dy * rstd * wv.y + bv.y);
        *(unsigned*)(out + (size_t)orow * 120 + lane * 2) = u;
    }
}

// ------------- MFMA GEMM: out = A(M x K, bf16) @ W(N x K, fp32)^T + bias ----
// MODE: 0 QKV scatter (q pre-scaled by SCALE2) | 1 proj(+x res -> X2 fp32)
//       2 gelu bf16 | 3 multiply-into bf16 | 4 fc2(+TMP res -> d_out @rev_row)
template <int MODE, int K, int N>
__global__ __launch_bounds__(256) void mm(const short* __restrict__ A,
                                          const float* __restrict__ W,
                                          const float* __restrict__ bias,
                                          void* __restrict__ outp,
                                          const float* __restrict__ aux,
                                          int m0) {
    const int lane = threadIdx.x & 63, wave = threadIdx.x >> 6;
    const int quad = lane >> 4, l16 = lane & 15;
    const int bm = blockIdx.x * 128 + (wave >> 1) * 64;
    const int bn = blockIdx.y * 64 + (wave & 1) * 32;

    f32x4 acc[4][2];
#pragma unroll
    for (int i = 0; i < 4; ++i)
#pragma unroll
        for (int j = 0; j < 2; ++j) acc[i][j] = (f32x4){0.f, 0.f, 0.f, 0.f};

    const short* Ar[4];
#pragma unroll
    for (int i = 0; i < 4; ++i) Ar[i] = A + (size_t)(bm + i * 16 + l16) * K;
    const int n0 = bn + l16, n1 = bn + 16 + l16;
    const int nc0 = n0 < N ? n0 : N - 1;
    const int nc1 = n1 < N ? n1 : N - 1;
    const float* W0 = W + (size_t)nc0 * K;
    const float* W1 = W + (size_t)nc1 * K;

    const int KT = (K + 31) / 32;
#pragma unroll
    for (int kt = 0; kt < KT; ++kt) {
        int kk = kt * 32 + quad * 8;
        bool kok = kk < K;
        int kc = kok ? kk : 0;
        bf16x8 a[4], b0v, b1v;
#pragma unroll
        for (int i = 0; i < 4; ++i) a[i] = *(const bf16x8*)(Ar[i] + kc);
        {
            f32x4 w0 = *(const f32x4*)(W0 + kc);
            f32x4 w1 = *(const f32x4*)(W0 + kc + 4);
            b0v = (bf16x8){bf16b(w0.x), bf16b(w0.y), bf16b(w0.z), bf16b(w0.w),
                           bf16b(w1.x), bf16b(w1.y), bf16b(w1.z), bf16b(w1.w)};
            f32x4 w2 = *(const f32x4*)(W1 + kc);
            f32x4 w3 = *(const f32x4*)(W1 + kc + 4);
            b1v = (bf16x8){bf16b(w2.x), bf16b(w2.y), bf16b(w2.z), bf16b(w2.w),
                           bf16b(w3.x), bf16b(w3.y), bf16b(w3.z), bf16b(w3.w)};
        }
        if (!kok) {
            bf16x8 zz = {0, 0, 0, 0, 0, 0, 0, 0};
            a[0] = a[1] = a[2] = a[3] = b0v = b1v = zz;
        }
#pragma unroll
        for (int i = 0; i < 4; ++i) {
            acc[i][0] = __builtin_amdgcn_mfma_f32_16x16x32_bf16(a[i], b0v, acc[i][0], 0, 0, 0);
            acc[i][1] = __builtin_amdgcn_mfma_f32_16x16x32_bf16(a[i], b1v, acc[i][1], 0, 0, 0);
        }
    }

#pragma unroll
    for (int j = 0; j < 2; ++j) {
        const int n = j ? n1 : n0;
        if (n >= N) continue;
        const float bs = bias[n];
        int which = 0, head = 0, e = 0;
        if (MODE == 0) { which = n / 120; int hn = n % 120; head = hn / 20; e = hn % 20; }
#pragma unroll
        for (int i = 0; i < 4; ++i) {
#pragma unroll
            for (int r = 0; r < 4; ++r) {
                int m = bm + i * 16 + quad * 4 + r;
                float val = acc[i][j][r] + bs;
                if (MODE == 0) {
                    if (which == 0) val *= SCALE2;
                    int wl = m >> 8, t = m & 255;
                    ((short*)outp)[(size_t)which * QPLANE +
                                   ((size_t)((wl * 6 + head) * 256 + t)) * 20 + e] = bf16b(val);
                } else if (MODE == 1) {
                    int g = rev_row(m0 + m);
                    val += aux[(size_t)g * 120 + n];
                    ((float*)outp)[(size_t)(m0 + m) * 120 + n] = val;
                } else if (MODE == 2) {
                    ((short*)outp)[(size_t)m * 240 + n] = bf16b(gelu_exact(val));
                } else if (MODE == 3) {
                    size_t idx = (size_t)m * 240 + n;
                    short* o = (short*)outp;
                    o[idx] = bf16b(bf2f(o[idx]) * val);
                } else { // MODE 4: aux pre-offset by m0*120; scatter to d_out
                    int g = rev_row(m0 + m);
                    val += aux[(size_t)m * 120 + n];
                    ((float*)outp)[(size_t)g * 120 + n] = val;
                }
            }
        }
    }
}

// ---- fused MLP up-projection: HID = gelu(A@W1^T+b1) * (A@W2^T+b2) ----------
__global__ __launch_bounds__(256) void mm_mlp(const short* __restrict__ A,
                                              const float* __restrict__ W1,
                                              const float* __restrict__ b1,
                                              const float* __restrict__ W2,
                                              const float* __restrict__ b2,
                                              short* __restrict__ outp) {
    const int lane = threadIdx.x & 63, wave = threadIdx.x >> 6;
    const int quad = lane >> 4, l16 = lane & 15;
    const int bm = blockIdx.x * 128 + (wave >> 1) * 64;
    const int bn = blockIdx.y * 64 + (wave & 1) * 32;
    const int N = 240, K = 120;

    f32x4 acc1[4][2], acc2[4][2];
#pragma unroll
    for (int i = 0; i < 4; ++i)
#pragma unroll
        for (int j = 0; j < 2; ++j) {
            acc1[i][j] = (f32x4){0.f, 0.f, 0.f, 0.f};
            acc2[i][j] = (f32x4){0.f, 0.f, 0.f, 0.f};
        }

    const short* Ar[4];
#pragma unroll
    for (int i = 0; i < 4; ++i) Ar[i] = A + (size_t)(bm + i * 16 + l16) * K;
    const int n0 = bn + l16, n1 = bn + 16 + l16;
    const int nc0 = n0 < N ? n0 : N - 1;
    const int nc1 = n1 < N ? n1 : N - 1;
    const float* Wa0 = W1 + (size_t)nc0 * K;
    const float* Wa1 = W1 + (size_t)nc1 * K;
    const float* Wb0 = W2 + (size_t)nc0 * K;
    const float* Wb1 = W2 + (size_t)nc1 * K;

#pragma unroll
    for (int kt = 0; kt < 4; ++kt) {
        int kk = kt * 32 + quad * 8;
        bool kok = kk < K;
        int kc = kok ? kk : 0;
        bf16x8 a[4], p0v, p1v, q0v, q1v;
#pragma unroll
        for (int i = 0; i < 4; ++i) a[i] = *(const bf16x8*)(Ar[i] + kc);
        {
            f32x4 w0 = *(const f32x4*)(Wa0 + kc);
            f32x4 w1 = *(const f32x4*)(Wa0 + kc + 4);
            p0v = (bf16x8){bf16b(w0.x), bf16b(w0.y), bf16b(w0.z), bf16b(w0.w),
                           bf16b(w1.x), bf16b(w1.y), bf16b(w1.z), bf16b(w1.w)};
            f32x4 w2 = *(const f32x4*)(Wa1 + kc);
            f32x4 w3 = *(const f32x4*)(Wa1 + kc + 4);
            p1v = (bf16x8){bf16b(w2.x), bf16b(w2.y), bf16b(w2.z), bf16b(w2.w),
                           bf16b(w3.x), bf16b(w3.y), bf16b(w3.z), bf16b(w3.w)};
            f32x4 u0 = *(const f32x4*)(Wb0 + kc);
            f32x4 u1 = *(const f32x4*)(Wb0 + kc + 4);
            q0v = (bf16x8){bf16b(u0.x), bf16b(u0.y), bf16b(u0.z), bf16b(u0.w),
                           bf16b(u1.x), bf16b(u1.y), bf16b(u1.z), bf16b(u1.w)};
            f32x4 u2 = *(const f32x4*)(Wb1 + kc);
            f32x4 u3 = *(const f32x4*)(Wb1 + kc + 4);
            q1v = (bf16x8){bf16b(u2.x), bf16b(u2.y), bf16b(u2.z), bf16b(u2.w),
                           bf16b(u3.x), bf16b(u3.y), bf16b(u3.z), bf16b(u3.w)};
        }
        if (!kok) {
            bf16x8 zz = {0, 0, 0, 0, 0, 0, 0, 0};
            a[0] = a[1] = a[2] = a[3] = p0v = p1v = q0v = q1v = zz;
        }
#pragma unroll
        for (int i = 0; i < 4; ++i) {
            acc1[i][0] = __builtin_amdgcn_mfma_f32_16x16x32_bf16(a[i], p0v, acc1[i][0], 0, 0, 0);
            acc1[i][1] = __builtin_amdgcn_mfma_f32_16x16x32_bf16(a[i], p1v, acc1[i][1], 0, 0, 0);
            acc2[i][0] = __builtin_amdgcn_mfma_f32_16x16x32_bf16(a[i], q0v, acc2[i][0], 0, 0, 0);
            acc2[i][1] = __builtin_amdgcn_mfma_f32_16x16x32_bf16(a[i], q1v, acc2[i][1], 0, 0, 0);
        }
    }

#pragma unroll
    for (int j = 0; j < 2; ++j) {
        const int n = j ? n1 : n0;
        if (n >= N) continue;
        const float g1 = b1[n], g2 = b2[n];
#pragma unroll
        for (int i = 0; i < 4; ++i) {
#pragma unroll
            for (int r = 0; r < 4; ++r) {
                int m = bm + i * 16 + quad * 4 + r;
                float gv = acc1[i][j][r] + g1;
                float vv = acc2[i][j][r] + g2;
                outp[(size_t)m * 240 + n] = bf16b(gelu_exact(gv) * vv);
            }
        }
    }
}

// ---------------- MFMA flash attention, LDS-fed, zero-shuffle ----------------
// K staged to LDS in fragment order (quad3 slot dropped; reads clamp to quad2,
// safe: finite K data x bq=0). V^T staged as u32 dim-pairs, 11 rows; row 10 =
// bf16(1.0) at dim20 -> PV MFMA accumulates l in accO[t][1][0] (quad1).
// nt processed in 2 passes of 2 to halve live acc registers.
template <int NK, bool MUT>
__global__ __launch_bounds__(NK) void attn_flash(const short* __restrict__ qkv,
                                                 short* __restrict__ xout) {
    constexpr int NKT = NK / 32;
    constexpr int VSTR2 = NK + 4;                  // u32 stride (16B-aligned rows)
    __shared__ __align__(16) short Kf[NKT * 2 * 48 * 8];
    __shared__ __align__(16) unsigned Vt2[11 * VSTR2];
    const int b = blockIdx.x;
    int wl, hd, half;
    if (MUT) { half = b & 1; hd = (b >> 1) % 6; wl = b / 12; }
    else     { half = 0;     hd = b % 6;        wl = b / 6;  }
    const int tid  = threadIdx.x;
    const int lane = tid & 63, wave = tid >> 6;
    const int quad = lane >> 4, l16 = lane & 15;

    const size_t rb = (size_t)(wl * 6 + hd) * 256;
    const short* qpl = qkv + rb * 20;
    const short* kpl = qkv + (size_t)QPLANE + rb * 20;
    const short* vpl = qkv + 2 * (size_t)QPLANE + rb * 20;
    const int koff = MUT ? half * 128 : 0;
    const int qoff = MUT ? (1 - half) * 128 : 0;

    // ---- stage V^T (u32 dim-pairs; row10 = ones at dim20) and K (frag order) ----
    {
        const uint2* p = (const uint2*)(vpl + (size_t)(koff + tid) * 20);
        unsigned tmp[10];
#pragma unroll
        for (int i = 0; i < 5; ++i) ((uint2*)tmp)[i] = p[i];
#pragma unroll
        for (int i = 0; i < 10; ++i) Vt2[i * VSTR2 + tid] = tmp[i];
        Vt2[10 * VSTR2 + tid] = 0x00003F80u;   // dim20 = bf16(1.0), dim21 = 0

        int skt = tid >> 5, sf = (tid >> 4) & 1, sl = tid & 15;
        int srow = koff + skt * 32 + sf * 4 + ((sl >> 2) << 3) + (sl & 3);
        const uint2* kp = (const uint2*)(kpl + (size_t)srow * 20);
        uint2 k0 = kp[0], k1 = kp[1], k2 = kp[2], k3 = kp[3], k4 = kp[4];
        uint4* dst = (uint4*)Kf + ((skt * 2 + sf) * 48 + sl);
        dst[0]  = make_uint4(k0.x, k0.y, k1.x, k1.y);   // quad0: d0-7
        dst[16] = make_uint4(k2.x, k2.y, k3.x, k3.y);   // quad1: d8-15
        dst[32] = make_uint4(k4.x, k4.y, 0u, 0u);       // quad2: d16-23
    }
    __syncthreads();

    const int quadc = quad < 3 ? quad : 2;             // quad3 aliases quad2 (x0)
    const uint4* kfrag = (const uint4*)Kf + quadc * 16 + l16;
    const unsigned sel = (l16 & 1) ? 0x07060302u : 0x05040100u;
    const unsigned* vbase0 = Vt2 + (l16 >> 1) * VSTR2;
    int r1 = 8 + (l16 >> 1); if (r1 > 10) r1 = 10;     // rows>=11 feed unused dims
    const unsigned* vbase1 = Vt2 + r1 * VSTR2;
    const f32x4 z4 = {0.f, 0.f, 0.f, 0.f};

#pragma unroll 1
    for (int g = 0; g < 2; ++g) {
        bf16x8 bq0 = load_frag20(qpl + (size_t)(qoff + wave * 64 + (g * 2 + 0) * 16 + l16) * 20, quad);
        bf16x8 bq1 = load_frag20(qpl + (size_t)(qoff + wave * 64 + (g * 2 + 1) * 16 + l16) * 20, quad);

        f32x4 accO[2][2];
        accO[0][0] = z4; accO[0][1] = z4; accO[1][0] = z4; accO[1][1] = z4;

#pragma unroll
        for (int kt = 0; kt < NKT; ++kt) {
            B8U ak0, ak1;
            ak0.u4 = kfrag[(kt * 2 + 0) * 48];
            ak1.u4 = kfrag[(kt * 2 + 1) * 48];
            B8U av0, av1;
            {
                uint4 va = *(const uint4*)(vbase0 + kt * 32 + quad * 8);
                uint4 vb = *(const uint4*)(vbase0 + kt * 32 + quad * 8 + 4);
                av0.u[0] = __builtin_amdgcn_perm(va.y, va.x, sel);
                av0.u[1] = __builtin_amdgcn_perm(va.w, va.z, sel);
                av0.u[2] = __builtin_amdgcn_perm(vb.y, vb.x, sel);
                av0.u[3] = __builtin_amdgcn_perm(vb.w, vb.z, sel);
                uint4 vc = *(const uint4*)(vbase1 + kt * 32 + quad * 8);
                uint4 vd = *(const uint4*)(vbase1 + kt * 32 + quad * 8 + 4);
                av1.u[0] = __builtin_amdgcn_perm(vc.y, vc.x, sel);
                av1.u[1] = __builtin_amdgcn_perm(vc.w, vc.z, sel);
                av1.u[2] = __builtin_amdgcn_perm(vd.y, vd.x, sel);
                av1.u[3] = __builtin_amdgcn_perm(vd.w, vd.z, sel);
            }
#pragma unroll
            for (int t = 0; t < 2; ++t) {
                bf16x8 bqt = t ? bq1 : bq0;
                f32x4 s0 = __builtin_amdgcn_mfma_f32_16x16x32_bf16(ak0.v, bqt, z4, 0, 0, 0);
                f32x4 s1 = __builtin_amdgcn_mfma_f32_16x16x32_bf16(ak1.v, bqt, z4, 0, 0, 0);
                float p0 = __builtin_amdgcn_exp2f(s0[0]), p1 = __builtin_amdgcn_exp2f(s0[1]);
                float p2 = __builtin_amdgcn_exp2f(s0[2]), p3 = __builtin_amdgcn_exp2f(s0[3]);
                float p4 = __builtin_amdgcn_exp2f(s1[0]), p5 = __builtin_amdgcn_exp2f(s1[1]);
                float p6 = __builtin_amdgcn_exp2f(s1[2]), p7 = __builtin_amdgcn_exp2f(s1[3]);
                B8U bp;   // P^T B-frag: j=0..3 <- s0 regs, j=4..7 <- s1 regs
                bp.u[0] = packbf(p0, p1);
                bp.u[1] = packbf(p2, p3);
                bp.u[2] = packbf(p4, p5);
                bp.u[3] = packbf(p6, p7);
                accO[t][0] = __builtin_amdgcn_mfma_f32_16x16x32_bf16(av0.v, bp.v, accO[t][0], 0, 0, 0);
                accO[t][1] = __builtin_amdgcn_mfma_f32_16x16x32_bf16(av1.v, bp.v, accO[t][1], 0, 0, 0);
            }
        }

        // epilogue: O^T C-layout (col l16=query, row quad*4+r=dim);
        // l = accO[t][1][0] on quad1 (dim20 ones-column)
#pragma unroll
        for (int t = 0; t < 2; ++t) {
            int nt = g * 2 + t;
            float l = __shfl(accO[t][1][0], 16 + l16, 64);
            float inv = 1.f / l;
            int tok = (MUT ? half * 128 : 0) + wave * 64 + nt * 16 + l16;
            short* orow = xout + (size_t)(wl * 256 + tok) * 240 + (MUT ? hd * 20 : 120 + hd * 20);
            unsigned lo = packbf(accO[t][0][0] * inv, accO[t][0][1] * inv);
            unsigned hi2 = packbf(accO[t][0][2] * inv, accO[t][0][3] * inv);
            *(uint2*)(orow + quad * 4) = make_uint2(lo, hi2);
            if (quad == 0) {
                unsigned lo2 = packbf(accO[t][1][0] * inv, accO[t][1][1] * inv);
                unsigned hi3 = packbf(accO[t][1][2] * inv, accO[t][1][3] * inv);
                *(uint2*)(orow + 16) = make_uint2(lo2, hi3);
            }
        }
    }
}

extern "C" void kernel_launch(void* const* d_in, const int* in_sizes, int n_in,
                              void* d_out, int out_size, void* d_ws, size_t ws_size,
                              hipStream_t stream) {
    const float* x          = (const float*)d_in[0];
    const float* norm1_w    = (const float*)d_in[1];
    const float* norm1_b    = (const float*)d_in[2];
    const float* qkv_self_w = (const float*)d_in[3];
    const float* qkv_self_b = (const float*)d_in[4];
    const float* qkv_mut_w  = (const float*)d_in[5];
    const float* qkv_mut_b  = (const float*)d_in[6];
    const float* proj_w     = (const float*)d_in[7];
    const float* proj_b     = (const float*)d_in[8];
    const float* norm2_w    = (const float*)d_in[9];
    const float* norm2_b    = (const float*)d_in[10];
    const float* fc11_w     = (const float*)d_in[11];
    const float* fc11_b     = (const float*)d_in[12];
    const float* fc12_w     = (const float*)d_in[13];
    const float* fc12_b     = (const float*)d_in[14];
    const float* fc2_w      = (const float*)d_in[15];
    const float* fc2_b      = (const float*)d_in[16];

    if (ws_size < 110100480u) return;

    char* wsb   = (char*)d_ws;
    short* Hb    = (short*)wsb;                  // 131072x120 bf16
    short* QKVc  = (short*)(wsb + 31457280);     // 3 planes, chunk
    short* XOUTc = (short*)(wsb + 78643200);     // 65536x240 bf16
    float* TMP   = (float*)wsb;                  // X2 copy, fp32 (MLP phase)
    short* H2c   = (short*)(wsb + 62914560);     // 65536x120 bf16
    short* HIDc  = (short*)(wsb + 78643200);     // 65536x240 bf16
    float* X2    = (float*)d_out;                // partitioned residual fp32
    float* out   = (float*)d_out;

    // 1. LN1 + window partition -> Hb (bf16)
    ln_kernel<true><<<32768, 256, 0, stream>>>(x, norm1_w, norm1_b, Hb);

    // 2. Attention phase: 2 chunks x 256 windows
    for (int c = 0; c < 2; ++c) {
        int m0 = c * CHROWS;
        const short* Ac = Hb + (size_t)m0 * 120;
        mm<0, 120, 360><<<dim3(512, 6), 256, 0, stream>>>(Ac, qkv_self_w, qkv_self_b,
                                                          QKVc, nullptr, 0);
        attn_flash<256, false><<<1536, 256, 0, stream>>>(QKVc, XOUTc);
        mm<0, 120, 360><<<dim3(512, 6), 256, 0, stream>>>(Ac, qkv_mut_w, qkv_mut_b,
                                                          QKVc, nullptr, 0);
        attn_flash<128, true><<<3072, 128, 0, stream>>>(QKVc, XOUTc);
        mm<1, 240, 120><<<dim3(512, 2), 256, 0, stream>>>(XOUTc, proj_w, proj_b,
                                                          X2, x, m0);
    }

    // 3. X2 -> TMP (frees d_out for scatter writes; residual source)
    hipMemcpyAsync(TMP, d_out, 62914560u, hipMemcpyDeviceToDevice, stream);

    // 4. MLP phase: 2 chunks x 65536 rows; fc2 scatters straight into d_out
    for (int c = 0; c < 2; ++c) {
        int m0 = c * CHROWS;
        ln_kernel<false><<<16384, 256, 0, stream>>>(TMP + (size_t)m0 * 120,
                                                    norm2_w, norm2_b, H2c);
        mm_mlp<<<dim3(512, 4), 256, 0, stream>>>(H2c, fc11_w, fc11_b,
                                                 fc12_w, fc12_b, HIDc);
        mm<4, 240, 120><<<dim3(512, 2), 256, 0, stream>>>(HIDc, fc2_w, fc2_b,
                                                          out, TMP + (size_t)m0 * 120, m0);
    }
}

// Round 3
// 650.713 us; speedup vs baseline: 1.1362x; 1.0327x over previous
//
#include <hip/hip_runtime.h>
#include <hip/hip_bf16.h>
#include <math.h>

// TMSA R9: LDS-staged GEMM family.
// R8 post-mortem: mm/mm_mlp were transaction-bound (MfmaUtil 6%, VALUBusy 20%,
// HBM 13%, occ 19%) - every frag load touched 16 cache lines (per-lane 16B at
// row stride 240-960B), ~20 instr x 16 lines per wave per phase. Fix: stage
// A (bf16) and W (fp32->bf16, converted once per block) into LDS with
// coalesced loads; row stride 136 shorts (272B) -> ds_read_b128 across 16
// lanes hits 8 distinct 16B slots = 2-way = free. K=240 = two 120-phases.
// attn_flash/ln unchanged (R8-verified).
//
// ws (bytes), guard 110,100,480:
//   attn phase: Hb bf16 [0,31457280) | QKVc bf16 [31457280,78643200)
//               XOUTc bf16 [78643200,110100480)
//   mlp  phase: TMP fp32 [0,62914560) (d2d copy of X2) |
//               H2c bf16 [62914560,78643200) | HIDc bf16 [78643200,110100480)

typedef __attribute__((ext_vector_type(8))) short bf16x8;
typedef __attribute__((ext_vector_type(4))) float f32x4;

#define SCALE2 (0.22360679774997896f * 1.44269504088896340f)  // d^-0.5 * log2(e)
#define CHROWS 65536
#define QPLANE 7864320u   // 65536*120 elems per q/k/v plane (chunk)
#define KPAD 136          // LDS row stride in shorts (272B: 2-way free)

union B8U { bf16x8 v; uint4 u4; uint2 u2[2]; unsigned u[4]; short s[8]; };

__device__ __forceinline__ short bf16b(float f) {
    __hip_bfloat16 h = __float2bfloat16(f);
    return *reinterpret_cast<short*>(&h);
}
__device__ __forceinline__ float bf2f(short s) {
    return __uint_as_float(((unsigned)(unsigned short)s) << 16);
}
__device__ __forceinline__ unsigned packbf(float a, float b) {
    return (unsigned)(unsigned short)bf16b(a) |
           ((unsigned)(unsigned short)bf16b(b) << 16);
}

// partitioned row r -> global row g
__device__ __forceinline__ int rev_row(int r) {
    int w = r >> 8, t = r & 255;
    int w8 = w & 7, h8 = (w >> 3) & 7, d2 = (w >> 6) & 1, n2 = w >> 7;
    int www = t & 7, hh = (t >> 3) & 7, dd = (t >> 6) & 1, nn = t >> 7;
    int n = n2 * 2 + nn, d = d2 * 2 + dd;
    int Hc = h8 * 8 + hh, Wc = w8 * 8 + www;
    return ((n * 4 + d) << 12) + (Hc << 6) + Wc;
}
// global row g -> partitioned row
__device__ __forceinline__ int part_row(int g) {
    int ww = g & 63, hh = (g >> 6) & 63, d = (g >> 12) & 3, n = g >> 14;
    int w = ((n >> 1) * 2 + (d >> 1)) * 64 + ((hh >> 3) << 3) + (ww >> 3);
    int t = (((n & 1) * 2 + (d & 1)) << 6) + ((hh & 7) << 3) + (ww & 7);
    return (w << 8) + t;
}
__device__ __forceinline__ float gelu_exact(float x) {
    return 0.5f * x * (1.0f + erff(x * 0.70710678118654752f));
}

// load B-frag from a 20-elem bf16 row (stride 20), k = quad*8..+7, zero-padded.
__device__ __forceinline__ bf16x8 load_frag20(const short* row, int quad) {
    B8U r;
    const uint2* p = (const uint2*)(row + quad * 8);
    r.u2[0] = p[0]; r.u2[1] = p[1];
    if (quad == 2) { r.u[2] = 0; r.u[3] = 0; }
    else if (quad == 3) { r.u[0] = r.u[1] = r.u[2] = r.u[3] = 0; }
    return r.v;
}

// ---- staging helpers: 120-wide K-phase into LDS, row stride KPAD ----------
// A: bf16 global, 128 rows. 1920 16B-chunks (15/row), coalesced within rows.
__device__ __forceinline__ void stage_A(short* As, const short* __restrict__ A,
                                        int bm, int k0, int Astr, int tid) {
#pragma unroll
    for (int i = 0; i < 8; ++i) {
        int c = tid + i * 256;
        if (c < 1920) {
            int row = c / 15, slot = c - row * 15;
            uint4 v = *(const uint4*)(A + (size_t)(bm + row) * Astr + k0 + slot * 8);
            *(uint4*)(As + row * KPAD + slot * 8) = v;
        }
    }
    if (tid < 128) *(uint4*)(As + tid * KPAD + 120) = make_uint4(0u, 0u, 0u, 0u);
}
// W: fp32 global, 64 rows (clamped to N-1), converted to bf16. 1920 f32x4
// chunks (30/row), coalesced within rows.
__device__ __forceinline__ void stage_W(short* Ws, const float* __restrict__ W,
                                        int bn, int k0, int Wstr, int N, int tid) {
#pragma unroll
    for (int i = 0; i < 8; ++i) {
        int c = tid + i * 256;
        if (c < 1920) {
            int row = c / 30, slot = c - row * 30;
            int wr = bn + row; if (wr > N - 1) wr = N - 1;
            f32x4 v = *(const f32x4*)(W + (size_t)wr * Wstr + k0 + slot * 4);
            *(uint2*)(Ws + row * KPAD + slot * 4) = make_uint2(packbf(v.x, v.y),
                                                               packbf(v.z, v.w));
        }
    }
    if (tid < 64) *(uint4*)(Ws + tid * KPAD + 120) = make_uint4(0u, 0u, 0u, 0u);
}

// ---------------- LayerNorm (C=120) fp32 in -> bf16 out ---------------------
template <bool REMAP>
__global__ __launch_bounds__(256) void ln_kernel(const float* __restrict__ in,
                                                 const float* __restrict__ w,
                                                 const float* __restrict__ b,
                                                 short* __restrict__ out) {
    int row  = blockIdx.x * 4 + (threadIdx.x >> 6);
    int lane = threadIdx.x & 63;
    const float* xr = in + (size_t)row * 120;
    float2 v = make_float2(0.f, 0.f);
    if (lane < 60) v = *(const float2*)(xr + lane * 2);
    float s = v.x + v.y;
#pragma unroll
    for (int off = 32; off; off >>= 1) s += __shfl_down(s, off, 64);
    s = __shfl(s, 0, 64);
    float mean = s * (1.f / 120.f);
    float dx = v.x - mean, dy = v.y - mean;
    float q = (lane < 60) ? (dx * dx + dy * dy) : 0.f;
#pragma unroll
    for (int off = 32; off; off >>= 1) q += __shfl_down(q, off, 64);
    q = __shfl(q, 0, 64);
    float rstd = rsqrtf(q * (1.f / 120.f) + 1e-5f);
    int orow = REMAP ? part_row(row) : row;
    if (lane < 60) {
        float2 wv = *(const float2*)(w + lane * 2);
        float2 bv = *(const float2*)(b + lane * 2);
        unsigned u = packbf(dx * rstd * wv.x + bv.x, dy * rstd * wv.y + bv.y);
        *(unsigned*)(out + (size_t)orow * 120 + lane * 2) = u;
    }
}

// ------------- LDS-staged MFMA GEMM: out = A(MxK bf16) @ W(NxK fp32)^T + b --
// MODE: 0 QKV scatter (q pre-scaled by SCALE2) | 1 proj(+x res -> X2 fp32)
//       4 fc2(+TMP res -> d_out @rev_row)
template <int MODE, int K, int N>
__global__ __launch_bounds__(256) void mm(const short* __restrict__ A,
                                          const float* __restrict__ W,
                                          const float* __restrict__ bias,
                                          void* __restrict__ outp,
                                          const float* __restrict__ aux,
                                          int m0) {
    __shared__ __align__(16) short As[128 * KPAD];
    __shared__ __align__(16) short Ws[64 * KPAD];
    const int tid = threadIdx.x;
    const int lane = tid & 63, wave = tid >> 6;
    const int quad = lane >> 4, l16 = lane & 15;
    const int bmb = blockIdx.x * 128;
    const int bn  = blockIdx.y * 64;
    const int abase = (wave >> 1) * 64;
    const int wbase = (wave & 1) * 32;

    f32x4 acc[4][2];
#pragma unroll
    for (int i = 0; i < 4; ++i)
#pragma unroll
        for (int j = 0; j < 2; ++j) acc[i][j] = (f32x4){0.f, 0.f, 0.f, 0.f};

    constexpr int PH = K / 120;
#pragma unroll
    for (int p = 0; p < PH; ++p) {
        if (p) __syncthreads();
        stage_A(As, A, bmb, p * 120, K, tid);
        stage_W(Ws, W, bn, p * 120, K, N, tid);
        __syncthreads();
        const short* Ab = As + (abase + l16) * KPAD + quad * 8;
        const short* Wb = Ws + (wbase + l16) * KPAD + quad * 8;
#pragma unroll
        for (int kt = 0; kt < 4; ++kt) {
            bf16x8 b0 = *(const bf16x8*)(Wb + kt * 32);
            bf16x8 b1 = *(const bf16x8*)(Wb + 16 * KPAD + kt * 32);
#pragma unroll
            for (int i = 0; i < 4; ++i) {
                bf16x8 a = *(const bf16x8*)(Ab + i * 16 * KPAD + kt * 32);
                acc[i][0] = __builtin_amdgcn_mfma_f32_16x16x32_bf16(a, b0, acc[i][0], 0, 0, 0);
                acc[i][1] = __builtin_amdgcn_mfma_f32_16x16x32_bf16(a, b1, acc[i][1], 0, 0, 0);
            }
        }
    }

    const int bm = bmb + abase;
#pragma unroll
    for (int j = 0; j < 2; ++j) {
        const int n = bn + wbase + j * 16 + l16;
        if (n >= N) continue;
        const float bs = bias[n];
        int which = 0, head = 0, e = 0;
        if (MODE == 0) { which = n / 120; int hn = n % 120; head = hn / 20; e = hn % 20; }
#pragma unroll
        for (int i = 0; i < 4; ++i) {
#pragma unroll
            for (int r = 0; r < 4; ++r) {
                int m = bm + i * 16 + quad * 4 + r;
                float val = acc[i][j][r] + bs;
                if (MODE == 0) {
                    if (which == 0) val *= SCALE2;
                    int wl = m >> 8, t = m & 255;
                    ((short*)outp)[(size_t)which * QPLANE +
                                   ((size_t)((wl * 6 + head) * 256 + t)) * 20 + e] = bf16b(val);
                } else if (MODE == 1) {
                    int g = rev_row(m0 + m);
                    val += aux[(size_t)g * 120 + n];
                    ((float*)outp)[(size_t)(m0 + m) * 120 + n] = val;
                } else { // MODE 4: aux pre-offset by m0*120; scatter to d_out
                    int g = rev_row(m0 + m);
                    val += aux[(size_t)m * 120 + n];
                    ((float*)outp)[(size_t)g * 120 + n] = val;
                }
            }
        }
    }
}

// ---- fused MLP up-projection: HID = gelu(A@W1^T+b1) * (A@W2^T+b2) ----------
__global__ __launch_bounds__(256) void mm_mlp(const short* __restrict__ A,
                                              const float* __restrict__ W1,
                                              const float* __restrict__ b1,
                                              const float* __restrict__ W2,
                                              const float* __restrict__ b2,
                                              short* __restrict__ outp) {
    __shared__ __align__(16) short As[128 * KPAD];
    __shared__ __align__(16) short Wa[64 * KPAD];
    __shared__ __align__(16) short Wbs[64 * KPAD];
    const int tid = threadIdx.x;
    const int lane = tid & 63, wave = tid >> 6;
    const int quad = lane >> 4, l16 = lane & 15;
    const int bmb = blockIdx.x * 128;
    const int bn  = blockIdx.y * 64;
    const int abase = (wave >> 1) * 64;
    const int wbase = (wave & 1) * 32;
    const int N = 240;

    f32x4 acc1[4][2], acc2[4][2];
#pragma unroll
    for (int i = 0; i < 4; ++i)
#pragma unroll
        for (int j = 0; j < 2; ++j) {
            acc1[i][j] = (f32x4){0.f, 0.f, 0.f, 0.f};
            acc2[i][j] = (f32x4){0.f, 0.f, 0.f, 0.f};
        }

    stage_A(As, A, bmb, 0, 120, tid);
    stage_W(Wa, W1, bn, 0, 120, N, tid);
    stage_W(Wbs, W2, bn, 0, 120, N, tid);
    __syncthreads();
    const short* Ab  = As  + (abase + l16) * KPAD + quad * 8;
    const short* W1b = Wa  + (wbase + l16) * KPAD + quad * 8;
    const short* W2b = Wbs + (wbase + l16) * KPAD + quad * 8;
#pragma unroll
    for (int kt = 0; kt < 4; ++kt) {
        bf16x8 p0 = *(const bf16x8*)(W1b + kt * 32);
        bf16x8 p1 = *(const bf16x8*)(W1b + 16 * KPAD + kt * 32);
        bf16x8 q0 = *(const bf16x8*)(W2b + kt * 32);
        bf16x8 q1 = *(const bf16x8*)(W2b + 16 * KPAD + kt * 32);
#pragma unroll
        for (int i = 0; i < 4; ++i) {
            bf16x8 a = *(const bf16x8*)(Ab + i * 16 * KPAD + kt * 32);
            acc1[i][0] = __builtin_amdgcn_mfma_f32_16x16x32_bf16(a, p0, acc1[i][0], 0, 0, 0);
            acc1[i][1] = __builtin_amdgcn_mfma_f32_16x16x32_bf16(a, p1, acc1[i][1], 0, 0, 0);
            acc2[i][0] = __builtin_amdgcn_mfma_f32_16x16x32_bf16(a, q0, acc2[i][0], 0, 0, 0);
            acc2[i][1] = __builtin_amdgcn_mfma_f32_16x16x32_bf16(a, q1, acc2[i][1], 0, 0, 0);
        }
    }

    const int bm = bmb + abase;
#pragma unroll
    for (int j = 0; j < 2; ++j) {
        const int n = bn + wbase + j * 16 + l16;
        if (n >= N) continue;
        const float g1 = b1[n], g2 = b2[n];
#pragma unroll
        for (int i = 0; i < 4; ++i) {
#pragma unroll
            for (int r = 0; r < 4; ++r) {
                int m = bm + i * 16 + quad * 4 + r;
                float gv = acc1[i][j][r] + g1;
                float vv = acc2[i][j][r] + g2;
                outp[(size_t)m * 240 + n] = bf16b(gelu_exact(gv) * vv);
            }
        }
    }
}

// ---------------- MFMA flash attention, LDS-fed, zero-shuffle ----------------
// K staged to LDS in fragment order (quad3 slot dropped; reads clamp to quad2,
// safe: finite K data x bq=0). V^T staged as u32 dim-pairs, 11 rows; row 10 =
// bf16(1.0) at dim20 -> PV MFMA accumulates l in accO[t][1][0] (quad1).
// nt processed in 2 passes of 2 to halve live acc registers.
template <int NK, bool MUT>
__global__ __launch_bounds__(NK) void attn_flash(const short* __restrict__ qkv,
                                                 short* __restrict__ xout) {
    constexpr int NKT = NK / 32;
    constexpr int VSTR2 = NK + 4;                  // u32 stride (16B-aligned rows)
    __shared__ __align__(16) short Kf[NKT * 2 * 48 * 8];
    __shared__ __align__(16) unsigned Vt2[11 * VSTR2];
    const int b = blockIdx.x;
    int wl, hd, half;
    if (MUT) { half = b & 1; hd = (b >> 1) % 6; wl = b / 12; }
    else     { half = 0;     hd = b % 6;        wl = b / 6;  }
    const int tid  = threadIdx.x;
    const int lane = tid & 63, wave = tid >> 6;
    const int quad = lane >> 4, l16 = lane & 15;

    const size_t rb = (size_t)(wl * 6 + hd) * 256;
    const short* qpl = qkv + rb * 20;
    const short* kpl = qkv + (size_t)QPLANE + rb * 20;
    const short* vpl = qkv + 2 * (size_t)QPLANE + rb * 20;
    const int koff = MUT ? half * 128 : 0;
    const int qoff = MUT ? (1 - half) * 128 : 0;

    // ---- stage V^T (u32 dim-pairs; row10 = ones at dim20) and K (frag order) ----
    {
        const uint2* p = (const uint2*)(vpl + (size_t)(koff + tid) * 20);
        unsigned tmp[10];
#pragma unroll
        for (int i = 0; i < 5; ++i) ((uint2*)tmp)[i] = p[i];
#pragma unroll
        for (int i = 0; i < 10; ++i) Vt2[i * VSTR2 + tid] = tmp[i];
        Vt2[10 * VSTR2 + tid] = 0x00003F80u;   // dim20 = bf16(1.0), dim21 = 0

        int skt = tid >> 5, sf = (tid >> 4) & 1, sl = tid & 15;
        int srow = koff + skt * 32 + sf * 4 + ((sl >> 2) << 3) + (sl & 3);
        const uint2* kp = (const uint2*)(kpl + (size_t)srow * 20);
        uint2 k0 = kp[0], k1 = kp[1], k2 = kp[2], k3 = kp[3], k4 = kp[4];
        uint4* dst = (uint4*)Kf + ((skt * 2 + sf) * 48 + sl);
        dst[0]  = make_uint4(k0.x, k0.y, k1.x, k1.y);   // quad0: d0-7
        dst[16] = make_uint4(k2.x, k2.y, k3.x, k3.y);   // quad1: d8-15
        dst[32] = make_uint4(k4.x, k4.y, 0u, 0u);       // quad2: d16-23
    }
    __syncthreads();

    const int quadc = quad < 3 ? quad : 2;             // quad3 aliases quad2 (x0)
    const uint4* kfrag = (const uint4*)Kf + quadc * 16 + l16;
    const unsigned sel = (l16 & 1) ? 0x07060302u : 0x05040100u;
    const unsigned* vbase0 = Vt2 + (l16 >> 1) * VSTR2;
    int r1 = 8 + (l16 >> 1); if (r1 > 10) r1 = 10;     // rows>=11 feed unused dims
    const unsigned* vbase1 = Vt2 + r1 * VSTR2;
    const f32x4 z4 = {0.f, 0.f, 0.f, 0.f};

#pragma unroll 1
    for (int g = 0; g < 2; ++g) {
        bf16x8 bq0 = load_frag20(qpl + (size_t)(qoff + wave * 64 + (g * 2 + 0) * 16 + l16) * 20, quad);
        bf16x8 bq1 = load_frag20(qpl + (size_t)(qoff + wave * 64 + (g * 2 + 1) * 16 + l16) * 20, quad);

        f32x4 accO[2][2];
        accO[0][0] = z4; accO[0][1] = z4; accO[1][0] = z4; accO[1][1] = z4;

#pragma unroll
        for (int kt = 0; kt < NKT; ++kt) {
            B8U ak0, ak1;
            ak0.u4 = kfrag[(kt * 2 + 0) * 48];
            ak1.u4 = kfrag[(kt * 2 + 1) * 48];
            B8U av0, av1;
            {
                uint4 va = *(const uint4*)(vbase0 + kt * 32 + quad * 8);
                uint4 vb = *(const uint4*)(vbase0 + kt * 32 + quad * 8 + 4);
                av0.u[0] = __builtin_amdgcn_perm(va.y, va.x, sel);
                av0.u[1] = __builtin_amdgcn_perm(va.w, va.z, sel);
                av0.u[2] = __builtin_amdgcn_perm(vb.y, vb.x, sel);
                av0.u[3] = __builtin_amdgcn_perm(vb.w, vb.z, sel);
                uint4 vc = *(const uint4*)(vbase1 + kt * 32 + quad * 8);
                uint4 vd = *(const uint4*)(vbase1 + kt * 32 + quad * 8 + 4);
                av1.u[0] = __builtin_amdgcn_perm(vc.y, vc.x, sel);
                av1.u[1] = __builtin_amdgcn_perm(vc.w, vc.z, sel);
                av1.u[2] = __builtin_amdgcn_perm(vd.y, vd.x, sel);
                av1.u[3] = __builtin_amdgcn_perm(vd.w, vd.z, sel);
            }
#pragma unroll
            for (int t = 0; t < 2; ++t) {
                bf16x8 bqt = t ? bq1 : bq0;
                f32x4 s0 = __builtin_amdgcn_mfma_f32_16x16x32_bf16(ak0.v, bqt, z4, 0, 0, 0);
                f32x4 s1 = __builtin_amdgcn_mfma_f32_16x16x32_bf16(ak1.v, bqt, z4, 0, 0, 0);
                float p0 = __builtin_amdgcn_exp2f(s0[0]), p1 = __builtin_amdgcn_exp2f(s0[1]);
                float p2 = __builtin_amdgcn_exp2f(s0[2]), p3 = __builtin_amdgcn_exp2f(s0[3]);
                float p4 = __builtin_amdgcn_exp2f(s1[0]), p5 = __builtin_amdgcn_exp2f(s1[1]);
                float p6 = __builtin_amdgcn_exp2f(s1[2]), p7 = __builtin_amdgcn_exp2f(s1[3]);
                B8U bp;   // P^T B-frag: j=0..3 <- s0 regs, j=4..7 <- s1 regs
                bp.u[0] = packbf(p0, p1);
                bp.u[1] = packbf(p2, p3);
                bp.u[2] = packbf(p4, p5);
                bp.u[3] = packbf(p6, p7);
                accO[t][0] = __builtin_amdgcn_mfma_f32_16x16x32_bf16(av0.v, bp.v, accO[t][0], 0, 0, 0);
                accO[t][1] = __builtin_amdgcn_mfma_f32_16x16x32_bf16(av1.v, bp.v, accO[t][1], 0, 0, 0);
            }
        }

        // epilogue: O^T C-layout (col l16=query, row quad*4+r=dim);
        // l = accO[t][1][0] on quad1 (dim20 ones-column)
#pragma unroll
        for (int t = 0; t < 2; ++t) {
            int nt = g * 2 + t;
            float l = __shfl(accO[t][1][0], 16 + l16, 64);
            float inv = 1.f / l;
            int tok = (MUT ? half * 128 : 0) + wave * 64 + nt * 16 + l16;
            short* orow = xout + (size_t)(wl * 256 + tok) * 240 + (MUT ? hd * 20 : 120 + hd * 20);
            unsigned lo = packbf(accO[t][0][0] * inv, accO[t][0][1] * inv);
            unsigned hi2 = packbf(accO[t][0][2] * inv, accO[t][0][3] * inv);
            *(uint2*)(orow + quad * 4) = make_uint2(lo, hi2);
            if (quad == 0) {
                unsigned lo2 = packbf(accO[t][1][0] * inv, accO[t][1][1] * inv);
                unsigned hi3 = packbf(accO[t][1][2] * inv, accO[t][1][3] * inv);
                *(uint2*)(orow + 16) = make_uint2(lo2, hi3);
            }
        }
    }
}

extern "C" void kernel_launch(void* const* d_in, const int* in_sizes, int n_in,
                              void* d_out, int out_size, void* d_ws, size_t ws_size,
                              hipStream_t stream) {
    const float* x          = (const float*)d_in[0];
    const float* norm1_w    = (const float*)d_in[1];
    const float* norm1_b    = (const float*)d_in[2];
    const float* qkv_self_w = (const float*)d_in[3];
    const float* qkv_self_b = (const float*)d_in[4];
    const float* qkv_mut_w  = (const float*)d_in[5];
    const float* qkv_mut_b  = (const float*)d_in[6];
    const float* proj_w     = (const float*)d_in[7];
    const float* proj_b     = (const float*)d_in[8];
    const float* norm2_w    = (const float*)d_in[9];
    const float* norm2_b    = (const float*)d_in[10];
    const float* fc11_w     = (const float*)d_in[11];
    const float* fc11_b     = (const float*)d_in[12];
    const float* fc12_w     = (const float*)d_in[13];
    const float* fc12_b     = (const float*)d_in[14];
    const float* fc2_w      = (const float*)d_in[15];
    const float* fc2_b      = (const float*)d_in[16];

    if (ws_size < 110100480u) return;

    char* wsb   = (char*)d_ws;
    short* Hb    = (short*)wsb;                  // 131072x120 bf16
    short* QKVc  = (short*)(wsb + 31457280);     // 3 planes, chunk
    short* XOUTc = (short*)(wsb + 78643200);     // 65536x240 bf16
    float* TMP   = (float*)wsb;                  // X2 copy, fp32 (MLP phase)
    short* H2c   = (short*)(wsb + 62914560);     // 65536x120 bf16
    short* HIDc  = (short*)(wsb + 78643200);     // 65536x240 bf16
    float* X2    = (float*)d_out;                // partitioned residual fp32
    float* out   = (float*)d_out;

    // 1. LN1 + window partition -> Hb (bf16)
    ln_kernel<true><<<32768, 256, 0, stream>>>(x, norm1_w, norm1_b, Hb);

    // 2. Attention phase: 2 chunks x 256 windows
    for (int c = 0; c < 2; ++c) {
        int m0 = c * CHROWS;
        const short* Ac = Hb + (size_t)m0 * 120;
        mm<0, 120, 360><<<dim3(512, 6), 256, 0, stream>>>(Ac, qkv_self_w, qkv_self_b,
                                                          QKVc, nullptr, 0);
        attn_flash<256, false><<<1536, 256, 0, stream>>>(QKVc, XOUTc);
        mm<0, 120, 360><<<dim3(512, 6), 256, 0, stream>>>(Ac, qkv_mut_w, qkv_mut_b,
                                                          QKVc, nullptr, 0);
        attn_flash<128, true><<<3072, 128, 0, stream>>>(QKVc, XOUTc);
        mm<1, 240, 120><<<dim3(512, 2), 256, 0, stream>>>(XOUTc, proj_w, proj_b,
                                                          X2, x, m0);
    }

    // 3. X2 -> TMP (frees d_out for scatter writes; residual source)
    hipMemcpyAsync(TMP, d_out, 62914560u, hipMemcpyDeviceToDevice, stream);

    // 4. MLP phase: 2 chunks x 65536 rows; fc2 scatters straight into d_out
    for (int c = 0; c < 2; ++c) {
        int m0 = c * CHROWS;
        ln_kernel<false><<<16384, 256, 0, stream>>>(TMP + (size_t)m0 * 120,
                                                    norm2_w, norm2_b, H2c);
        mm_mlp<<<dim3(512, 4), 256, 0, stream>>>(H2c, fc11_w, fc11_b,
                                                 fc12_w, fc12_b, HIDc);
        mm<4, 240, 120><<<dim3(512, 2), 256, 0, stream>>>(HIDc, fc2_w, fc2_b,
                                                          out, TMP + (size_t)m0 * 120, m0);
    }
}

// Round 4
// 623.152 us; speedup vs baseline: 1.1864x; 1.0442x over previous
//
#include <hip/hip_runtime.h>
#include <hip/hip_bf16.h>
#include <math.h>

// TMSA R10: fragment-ordered LDS GEMMs, 48KB/block.
// R9 post-mortem: mm_mlp regressed 52->73us - 69.6KB LDS -> 2 blocks/CU,
// read-side layout caused 1.5M conflict-cycles, staging not overlapped.
// R10: A staged in FRAGMENT order (32KB: [tile][kt][lane] uint4; compute reads
// are consecutive-lane ds_read_b128 = contiguous 1KB, conflict-free by
// construction - same as attn Kf). W staged compact frag-packed 16KB; mm_mlp
// runs W1 then W2 sequentially through ONE 16KB buffer. LDS=48KB -> 3
// blocks/CU everywhere. Staging global reads coalesced (16 thr = 1 row).
// attn_flash/ln unchanged (R8-verified).
//
// ws (bytes), guard 110,100,480:
//   attn phase: Hb bf16 [0,31457280) | QKVc bf16 [31457280,78643200)
//               XOUTc bf16 [78643200,110100480)
//   mlp  phase: TMP fp32 [0,62914560) (d2d copy of X2) |
//               H2c bf16 [62914560,78643200) | HIDc bf16 [78643200,110100480)

typedef __attribute__((ext_vector_type(8))) short bf16x8;
typedef __attribute__((ext_vector_type(4))) float f32x4;

#define SCALE2 (0.22360679774997896f * 1.44269504088896340f)  // d^-0.5 * log2(e)
#define CHROWS 65536
#define QPLANE 7864320u   // 65536*120 elems per q/k/v plane (chunk)

union B8U { bf16x8 v; uint4 u4; uint2 u2[2]; unsigned u[4]; short s[8]; };

__device__ __forceinline__ short bf16b(float f) {
    __hip_bfloat16 h = __float2bfloat16(f);
    return *reinterpret_cast<short*>(&h);
}
__device__ __forceinline__ float bf2f(short s) {
    return __uint_as_float(((unsigned)(unsigned short)s) << 16);
}
__device__ __forceinline__ unsigned packbf(float a, float b) {
    return (unsigned)(unsigned short)bf16b(a) |
           ((unsigned)(unsigned short)bf16b(b) << 16);
}

// partitioned row r -> global row g
__device__ __forceinline__ int rev_row(int r) {
    int w = r >> 8, t = r & 255;
    int w8 = w & 7, h8 = (w >> 3) & 7, d2 = (w >> 6) & 1, n2 = w >> 7;
    int www = t & 7, hh = (t >> 3) & 7, dd = (t >> 6) & 1, nn = t >> 7;
    int n = n2 * 2 + nn, d = d2 * 2 + dd;
    int Hc = h8 * 8 + hh, Wc = w8 * 8 + www;
    return ((n * 4 + d) << 12) + (Hc << 6) + Wc;
}
// global row g -> partitioned row
__device__ __forceinline__ int part_row(int g) {
    int ww = g & 63, hh = (g >> 6) & 63, d = (g >> 12) & 3, n = g >> 14;
    int w = ((n >> 1) * 2 + (d >> 1)) * 64 + ((hh >> 3) << 3) + (ww >> 3);
    int t = (((n & 1) * 2 + (d & 1)) << 6) + ((hh & 7) << 3) + (ww & 7);
    return (w << 8) + t;
}
__device__ __forceinline__ float gelu_exact(float x) {
    return 0.5f * x * (1.0f + erff(x * 0.70710678118654752f));
}

// load B-frag from a 20-elem bf16 row (stride 20), k = quad*8..+7, zero-padded.
__device__ __forceinline__ bf16x8 load_frag20(const short* row, int quad) {
    B8U r;
    const uint2* p = (const uint2*)(row + quad * 8);
    r.u2[0] = p[0]; r.u2[1] = p[1];
    if (quad == 2) { r.u[2] = 0; r.u[3] = 0; }
    else if (quad == 3) { r.u[0] = r.u[1] = r.u[2] = r.u[3] = 0; }
    return r.v;
}

// ---- fragment-order staging: frag (tile,kt) for lane(quad,l16) at uint4 ----
// index ((tile*4+kt)*64 + quad*16 + l16). Element = src[tile*16+l16][kt*32+quad*8+e].
// A: bf16, 128 rows, K-window [k0,k0+120), chunk q=15 zero-padded.
__device__ __forceinline__ void stageA_frag(uint4* Af, const short* __restrict__ A,
                                            int bm, int k0, int Astr, int tid) {
#pragma unroll
    for (int i = 0; i < 8; ++i) {
        int c = i * 256 + tid;
        int row = c >> 4, q = c & 15;
        uint4 v = make_uint4(0u, 0u, 0u, 0u);
        if (q < 15) v = *(const uint4*)(A + (size_t)(bm + row) * Astr + k0 + q * 8);
        Af[((row >> 4) * 4 + (q >> 2)) * 64 + (q & 3) * 16 + (row & 15)] = v;
    }
}
// W: fp32, 64 rows (clamped to N-1), converted bf16, same frag layout (16KB).
__device__ __forceinline__ void stageW_frag(uint4* Wf, const float* __restrict__ W,
                                            int bn, int k0, int Wstr, int N, int tid) {
#pragma unroll
    for (int i = 0; i < 4; ++i) {
        int c = i * 256 + tid;
        int row = c >> 4, q = c & 15;
        int wr = bn + row; if (wr > N - 1) wr = N - 1;
        uint4 d = make_uint4(0u, 0u, 0u, 0u);
        if (q < 15) {
            f32x4 w0 = *(const f32x4*)(W + (size_t)wr * Wstr + k0 + q * 8);
            f32x4 w1 = *(const f32x4*)(W + (size_t)wr * Wstr + k0 + q * 8 + 4);
            d = make_uint4(packbf(w0.x, w0.y), packbf(w0.z, w0.w),
                           packbf(w1.x, w1.y), packbf(w1.z, w1.w));
        }
        Wf[((row >> 4) * 4 + (q >> 2)) * 64 + (q & 3) * 16 + (row & 15)] = d;
    }
}

// ---------------- LayerNorm (C=120) fp32 in -> bf16 out ---------------------
template <bool REMAP>
__global__ __launch_bounds__(256) void ln_kernel(const float* __restrict__ in,
                                                 const float* __restrict__ w,
                                                 const float* __restrict__ b,
                                                 short* __restrict__ out) {
    int row  = blockIdx.x * 4 + (threadIdx.x >> 6);
    int lane = threadIdx.x & 63;
    const float* xr = in + (size_t)row * 120;
    float2 v = make_float2(0.f, 0.f);
    if (lane < 60) v = *(const float2*)(xr + lane * 2);
    float s = v.x + v.y;
#pragma unroll
    for (int off = 32; off; off >>= 1) s += __shfl_down(s, off, 64);
    s = __shfl(s, 0, 64);
    float mean = s * (1.f / 120.f);
    float dx = v.x - mean, dy = v.y - mean;
    float q = (lane < 60) ? (dx * dx + dy * dy) : 0.f;
#pragma unroll
    for (int off = 32; off; off >>= 1) q += __shfl_down(q, off, 64);
    q = __shfl(q, 0, 64);
    float rstd = rsqrtf(q * (1.f / 120.f) + 1e-5f);
    int orow = REMAP ? part_row(row) : row;
    if (lane < 60) {
        float2 wv = *(const float2*)(w + lane * 2);
        float2 bv = *(const float2*)(b + lane * 2);
        unsigned u = packbf(dx * rstd * wv.x + bv.x, dy * rstd * wv.y + bv.y);
        *(unsigned*)(out + (size_t)orow * 120 + lane * 2) = u;
    }
}

// ------------- frag-LDS MFMA GEMM: out = A(MxK bf16) @ W(NxK fp32)^T + b ----
// MODE: 0 QKV scatter (q pre-scaled by SCALE2) | 1 proj(+x res -> X2 fp32)
//       4 fc2(+TMP res -> d_out @rev_row)
template <int MODE, int K, int N>
__global__ __launch_bounds__(256) void mm(const short* __restrict__ A,
                                          const float* __restrict__ W,
                                          const float* __restrict__ bias,
                                          void* __restrict__ outp,
                                          const float* __restrict__ aux,
                                          int m0) {
    __shared__ uint4 Af[2048];   // 32KB: 8 m-tiles x 4 kt x 64 lanes
    __shared__ uint4 Wf[1024];   // 16KB: 4 n-tiles x 4 kt x 64 lanes
    const int tid = threadIdx.x;
    const int lane = tid & 63, wave = tid >> 6;
    const int quad = lane >> 4, l16 = lane & 15;
    const int bmb = blockIdx.x * 128;
    const int bn  = blockIdx.y * 64;
    const int atile = (wave >> 1) * 4;
    const int wtile = (wave & 1) * 2;

    f32x4 acc[4][2];
#pragma unroll
    for (int i = 0; i < 4; ++i)
#pragma unroll
        for (int j = 0; j < 2; ++j) acc[i][j] = (f32x4){0.f, 0.f, 0.f, 0.f};

    constexpr int PH = K / 120;
#pragma unroll
    for (int p = 0; p < PH; ++p) {
        if (p) __syncthreads();
        stageA_frag(Af, A, bmb, p * 120, K, tid);
        stageW_frag(Wf, W, bn, p * 120, K, N, tid);
        __syncthreads();
#pragma unroll
        for (int kt = 0; kt < 4; ++kt) {
            B8U b0, b1;
            b0.u4 = Wf[((wtile + 0) * 4 + kt) * 64 + lane];
            b1.u4 = Wf[((wtile + 1) * 4 + kt) * 64 + lane];
#pragma unroll
            for (int i = 0; i < 4; ++i) {
                B8U a; a.u4 = Af[((atile + i) * 4 + kt) * 64 + lane];
                acc[i][0] = __builtin_amdgcn_mfma_f32_16x16x32_bf16(a.v, b0.v, acc[i][0], 0, 0, 0);
                acc[i][1] = __builtin_amdgcn_mfma_f32_16x16x32_bf16(a.v, b1.v, acc[i][1], 0, 0, 0);
            }
        }
    }

    const int bm = bmb + atile * 16;
#pragma unroll
    for (int j = 0; j < 2; ++j) {
        const int n = bn + wtile * 16 + j * 16 + l16;
        if (n >= N) continue;
        const float bs = bias[n];
        int which = 0, head = 0, e = 0;
        if (MODE == 0) { which = n / 120; int hn = n % 120; head = hn / 20; e = hn % 20; }
#pragma unroll
        for (int i = 0; i < 4; ++i) {
#pragma unroll
            for (int r = 0; r < 4; ++r) {
                int m = bm + i * 16 + quad * 4 + r;
                float val = acc[i][j][r] + bs;
                if (MODE == 0) {
                    if (which == 0) val *= SCALE2;
                    int wl = m >> 8, t = m & 255;
                    ((short*)outp)[(size_t)which * QPLANE +
                                   ((size_t)((wl * 6 + head) * 256 + t)) * 20 + e] = bf16b(val);
                } else if (MODE == 1) {
                    int g = rev_row(m0 + m);
                    val += aux[(size_t)g * 120 + n];
                    ((float*)outp)[(size_t)(m0 + m) * 120 + n] = val;
                } else { // MODE 4: aux pre-offset by m0*120; scatter to d_out
                    int g = rev_row(m0 + m);
                    val += aux[(size_t)m * 120 + n];
                    ((float*)outp)[(size_t)g * 120 + n] = val;
                }
            }
        }
    }
}

// ---- fused MLP up-projection: HID = gelu(A@W1^T+b1) * (A@W2^T+b2) ----------
// W1 and W2 staged sequentially through ONE 16KB frag buffer (LDS stays 48KB).
__global__ __launch_bounds__(256) void mm_mlp(const short* __restrict__ A,
                                              const float* __restrict__ W1,
                                              const float* __restrict__ b1,
                                              const float* __restrict__ W2,
                                              const float* __restrict__ b2,
                                              short* __restrict__ outp) {
    __shared__ uint4 Af[2048];
    __shared__ uint4 Wf[1024];
    const int tid = threadIdx.x;
    const int lane = tid & 63, wave = tid >> 6;
    const int quad = lane >> 4, l16 = lane & 15;
    const int bmb = blockIdx.x * 128;
    const int bn  = blockIdx.y * 64;
    const int atile = (wave >> 1) * 4;
    const int wtile = (wave & 1) * 2;
    const int N = 240;

    f32x4 acc1[4][2], acc2[4][2];
#pragma unroll
    for (int i = 0; i < 4; ++i)
#pragma unroll
        for (int j = 0; j < 2; ++j) {
            acc1[i][j] = (f32x4){0.f, 0.f, 0.f, 0.f};
            acc2[i][j] = (f32x4){0.f, 0.f, 0.f, 0.f};
        }

    stageA_frag(Af, A, bmb, 0, 120, tid);
    stageW_frag(Wf, W1, bn, 0, 120, N, tid);
    __syncthreads();
#pragma unroll
    for (int kt = 0; kt < 4; ++kt) {
        B8U b0, b1;
        b0.u4 = Wf[((wtile + 0) * 4 + kt) * 64 + lane];
        b1.u4 = Wf[((wtile + 1) * 4 + kt) * 64 + lane];
#pragma unroll
        for (int i = 0; i < 4; ++i) {
            B8U a; a.u4 = Af[((atile + i) * 4 + kt) * 64 + lane];
            acc1[i][0] = __builtin_amdgcn_mfma_f32_16x16x32_bf16(a.v, b0.v, acc1[i][0], 0, 0, 0);
            acc1[i][1] = __builtin_amdgcn_mfma_f32_16x16x32_bf16(a.v, b1.v, acc1[i][1], 0, 0, 0);
        }
    }
    __syncthreads();                       // all waves done with W1 frags
    stageW_frag(Wf, W2, bn, 0, 120, N, tid);
    __syncthreads();
#pragma unroll
    for (int kt = 0; kt < 4; ++kt) {
        B8U b0, b1;
        b0.u4 = Wf[((wtile + 0) * 4 + kt) * 64 + lane];
        b1.u4 = Wf[((wtile + 1) * 4 + kt) * 64 + lane];
#pragma unroll
        for (int i = 0; i < 4; ++i) {
            B8U a; a.u4 = Af[((atile + i) * 4 + kt) * 64 + lane];
            acc2[i][0] = __builtin_amdgcn_mfma_f32_16x16x32_bf16(a.v, b0.v, acc2[i][0], 0, 0, 0);
            acc2[i][1] = __builtin_amdgcn_mfma_f32_16x16x32_bf16(a.v, b1.v, acc2[i][1], 0, 0, 0);
        }
    }

    const int bm = bmb + atile * 16;
#pragma unroll
    for (int j = 0; j < 2; ++j) {
        const int n = bn + wtile * 16 + j * 16 + l16;
        if (n >= N) continue;
        const float g1 = b1[n], g2 = b2[n];
#pragma unroll
        for (int i = 0; i < 4; ++i) {
#pragma unroll
            for (int r = 0; r < 4; ++r) {
                int m = bm + i * 16 + quad * 4 + r;
                float gv = acc1[i][j][r] + g1;
                float vv = acc2[i][j][r] + g2;
                outp[(size_t)m * 240 + n] = bf16b(gelu_exact(gv) * vv);
            }
        }
    }
}

// ---------------- MFMA flash attention, LDS-fed, zero-shuffle ----------------
// K staged to LDS in fragment order (quad3 slot dropped; reads clamp to quad2,
// safe: finite K data x bq=0). V^T staged as u32 dim-pairs, 11 rows; row 10 =
// bf16(1.0) at dim20 -> PV MFMA accumulates l in accO[t][1][0] (quad1).
// nt processed in 2 passes of 2 to halve live acc registers.
template <int NK, bool MUT>
__global__ __launch_bounds__(NK) void attn_flash(const short* __restrict__ qkv,
                                                 short* __restrict__ xout) {
    constexpr int NKT = NK / 32;
    constexpr int VSTR2 = NK + 4;                  // u32 stride (16B-aligned rows)
    __shared__ __align__(16) short Kf[NKT * 2 * 48 * 8];
    __shared__ __align__(16) unsigned Vt2[11 * VSTR2];
    const int b = blockIdx.x;
    int wl, hd, half;
    if (MUT) { half = b & 1; hd = (b >> 1) % 6; wl = b / 12; }
    else     { half = 0;     hd = b % 6;        wl = b / 6;  }
    const int tid  = threadIdx.x;
    const int lane = tid & 63, wave = tid >> 6;
    const int quad = lane >> 4, l16 = lane & 15;

    const size_t rb = (size_t)(wl * 6 + hd) * 256;
    const short* qpl = qkv + rb * 20;
    const short* kpl = qkv + (size_t)QPLANE + rb * 20;
    const short* vpl = qkv + 2 * (size_t)QPLANE + rb * 20;
    const int koff = MUT ? half * 128 : 0;
    const int qoff = MUT ? (1 - half) * 128 : 0;

    // ---- stage V^T (u32 dim-pairs; row10 = ones at dim20) and K (frag order) ----
    {
        const uint2* p = (const uint2*)(vpl + (size_t)(koff + tid) * 20);
        unsigned tmp[10];
#pragma unroll
        for (int i = 0; i < 5; ++i) ((uint2*)tmp)[i] = p[i];
#pragma unroll
        for (int i = 0; i < 10; ++i) Vt2[i * VSTR2 + tid] = tmp[i];
        Vt2[10 * VSTR2 + tid] = 0x00003F80u;   // dim20 = bf16(1.0), dim21 = 0

        int skt = tid >> 5, sf = (tid >> 4) & 1, sl = tid & 15;
        int srow = koff + skt * 32 + sf * 4 + ((sl >> 2) << 3) + (sl & 3);
        const uint2* kp = (const uint2*)(kpl + (size_t)srow * 20);
        uint2 k0 = kp[0], k1 = kp[1], k2 = kp[2], k3 = kp[3], k4 = kp[4];
        uint4* dst = (uint4*)Kf + ((skt * 2 + sf) * 48 + sl);
        dst[0]  = make_uint4(k0.x, k0.y, k1.x, k1.y);   // quad0: d0-7
        dst[16] = make_uint4(k2.x, k2.y, k3.x, k3.y);   // quad1: d8-15
        dst[32] = make_uint4(k4.x, k4.y, 0u, 0u);       // quad2: d16-23
    }
    __syncthreads();

    const int quadc = quad < 3 ? quad : 2;             // quad3 aliases quad2 (x0)
    const uint4* kfrag = (const uint4*)Kf + quadc * 16 + l16;
    const unsigned sel = (l16 & 1) ? 0x07060302u : 0x05040100u;
    const unsigned* vbase0 = Vt2 + (l16 >> 1) * VSTR2;
    int r1 = 8 + (l16 >> 1); if (r1 > 10) r1 = 10;     // rows>=11 feed unused dims
    const unsigned* vbase1 = Vt2 + r1 * VSTR2;
    const f32x4 z4 = {0.f, 0.f, 0.f, 0.f};

#pragma unroll 1
    for (int g = 0; g < 2; ++g) {
        bf16x8 bq0 = load_frag20(qpl + (size_t)(qoff + wave * 64 + (g * 2 + 0) * 16 + l16) * 20, quad);
        bf16x8 bq1 = load_frag20(qpl + (size_t)(qoff + wave * 64 + (g * 2 + 1) * 16 + l16) * 20, quad);

        f32x4 accO[2][2];
        accO[0][0] = z4; accO[0][1] = z4; accO[1][0] = z4; accO[1][1] = z4;

#pragma unroll
        for (int kt = 0; kt < NKT; ++kt) {
            B8U ak0, ak1;
            ak0.u4 = kfrag[(kt * 2 + 0) * 48];
            ak1.u4 = kfrag[(kt * 2 + 1) * 48];
            B8U av0, av1;
            {
                uint4 va = *(const uint4*)(vbase0 + kt * 32 + quad * 8);
                uint4 vb = *(const uint4*)(vbase0 + kt * 32 + quad * 8 + 4);
                av0.u[0] = __builtin_amdgcn_perm(va.y, va.x, sel);
                av0.u[1] = __builtin_amdgcn_perm(va.w, va.z, sel);
                av0.u[2] = __builtin_amdgcn_perm(vb.y, vb.x, sel);
                av0.u[3] = __builtin_amdgcn_perm(vb.w, vb.z, sel);
                uint4 vc = *(const uint4*)(vbase1 + kt * 32 + quad * 8);
                uint4 vd = *(const uint4*)(vbase1 + kt * 32 + quad * 8 + 4);
                av1.u[0] = __builtin_amdgcn_perm(vc.y, vc.x, sel);
                av1.u[1] = __builtin_amdgcn_perm(vc.w, vc.z, sel);
                av1.u[2] = __builtin_amdgcn_perm(vd.y, vd.x, sel);
                av1.u[3] = __builtin_amdgcn_perm(vd.w, vd.z, sel);
            }
#pragma unroll
            for (int t = 0; t < 2; ++t) {
                bf16x8 bqt = t ? bq1 : bq0;
                f32x4 s0 = __builtin_amdgcn_mfma_f32_16x16x32_bf16(ak0.v, bqt, z4, 0, 0, 0);
                f32x4 s1 = __builtin_amdgcn_mfma_f32_16x16x32_bf16(ak1.v, bqt, z4, 0, 0, 0);
                float p0 = __builtin_amdgcn_exp2f(s0[0]), p1 = __builtin_amdgcn_exp2f(s0[1]);
                float p2 = __builtin_amdgcn_exp2f(s0[2]), p3 = __builtin_amdgcn_exp2f(s0[3]);
                float p4 = __builtin_amdgcn_exp2f(s1[0]), p5 = __builtin_amdgcn_exp2f(s1[1]);
                float p6 = __builtin_amdgcn_exp2f(s1[2]), p7 = __builtin_amdgcn_exp2f(s1[3]);
                B8U bp;   // P^T B-frag: j=0..3 <- s0 regs, j=4..7 <- s1 regs
                bp.u[0] = packbf(p0, p1);
                bp.u[1] = packbf(p2, p3);
                bp.u[2] = packbf(p4, p5);
                bp.u[3] = packbf(p6, p7);
                accO[t][0] = __builtin_amdgcn_mfma_f32_16x16x32_bf16(av0.v, bp.v, accO[t][0], 0, 0, 0);
                accO[t][1] = __builtin_amdgcn_mfma_f32_16x16x32_bf16(av1.v, bp.v, accO[t][1], 0, 0, 0);
            }
        }

        // epilogue: O^T C-layout (col l16=query, row quad*4+r=dim);
        // l = accO[t][1][0] on quad1 (dim20 ones-column)
#pragma unroll
        for (int t = 0; t < 2; ++t) {
            int nt = g * 2 + t;
            float l = __shfl(accO[t][1][0], 16 + l16, 64);
            float inv = 1.f / l;
            int tok = (MUT ? half * 128 : 0) + wave * 64 + nt * 16 + l16;
            short* orow = xout + (size_t)(wl * 256 + tok) * 240 + (MUT ? hd * 20 : 120 + hd * 20);
            unsigned lo = packbf(accO[t][0][0] * inv, accO[t][0][1] * inv);
            unsigned hi2 = packbf(accO[t][0][2] * inv, accO[t][0][3] * inv);
            *(uint2*)(orow + quad * 4) = make_uint2(lo, hi2);
            if (quad == 0) {
                unsigned lo2 = packbf(accO[t][1][0] * inv, accO[t][1][1] * inv);
                unsigned hi3 = packbf(accO[t][1][2] * inv, accO[t][1][3] * inv);
                *(uint2*)(orow + 16) = make_uint2(lo2, hi3);
            }
        }
    }
}

extern "C" void kernel_launch(void* const* d_in, const int* in_sizes, int n_in,
                              void* d_out, int out_size, void* d_ws, size_t ws_size,
                              hipStream_t stream) {
    const float* x          = (const float*)d_in[0];
    const float* norm1_w    = (const float*)d_in[1];
    const float* norm1_b    = (const float*)d_in[2];
    const float* qkv_self_w = (const float*)d_in[3];
    const float* qkv_self_b = (const float*)d_in[4];
    const float* qkv_mut_w  = (const float*)d_in[5];
    const float* qkv_mut_b  = (const float*)d_in[6];
    const float* proj_w     = (const float*)d_in[7];
    const float* proj_b     = (const float*)d_in[8];
    const float* norm2_w    = (const float*)d_in[9];
    const float* norm2_b    = (const float*)d_in[10];
    const float* fc11_w     = (const float*)d_in[11];
    const float* fc11_b     = (const float*)d_in[12];
    const float* fc12_w     = (const float*)d_in[13];
    const float* fc12_b     = (const float*)d_in[14];
    const float* fc2_w      = (const float*)d_in[15];
    const float* fc2_b      = (const float*)d_in[16];

    if (ws_size < 110100480u) return;

    char* wsb   = (char*)d_ws;
    short* Hb    = (short*)wsb;                  // 131072x120 bf16
    short* QKVc  = (short*)(wsb + 31457280);     // 3 planes, chunk
    short* XOUTc = (short*)(wsb + 78643200);     // 65536x240 bf16
    float* TMP   = (float*)wsb;                  // X2 copy, fp32 (MLP phase)
    short* H2c   = (short*)(wsb + 62914560);     // 65536x120 bf16
    short* HIDc  = (short*)(wsb + 78643200);     // 65536x240 bf16
    float* X2    = (float*)d_out;                // partitioned residual fp32
    float* out   = (float*)d_out;

    // 1. LN1 + window partition -> Hb (bf16)
    ln_kernel<true><<<32768, 256, 0, stream>>>(x, norm1_w, norm1_b, Hb);

    // 2. Attention phase: 2 chunks x 256 windows
    for (int c = 0; c < 2; ++c) {
        int m0 = c * CHROWS;
        const short* Ac = Hb + (size_t)m0 * 120;
        mm<0, 120, 360><<<dim3(512, 6), 256, 0, stream>>>(Ac, qkv_self_w, qkv_self_b,
                                                          QKVc, nullptr, 0);
        attn_flash<256, false><<<1536, 256, 0, stream>>>(QKVc, XOUTc);
        mm<0, 120, 360><<<dim3(512, 6), 256, 0, stream>>>(Ac, qkv_mut_w, qkv_mut_b,
                                                          QKVc, nullptr, 0);
        attn_flash<128, true><<<3072, 128, 0, stream>>>(QKVc, XOUTc);
        mm<1, 240, 120><<<dim3(512, 2), 256, 0, stream>>>(XOUTc, proj_w, proj_b,
                                                          X2, x, m0);
    }

    // 3. X2 -> TMP (frees d_out for scatter writes; residual source)
    hipMemcpyAsync(TMP, d_out, 62914560u, hipMemcpyDeviceToDevice, stream);

    // 4. MLP phase: 2 chunks x 65536 rows; fc2 scatters straight into d_out
    for (int c = 0; c < 2; ++c) {
        int m0 = c * CHROWS;
        ln_kernel<false><<<16384, 256, 0, stream>>>(TMP + (size_t)m0 * 120,
                                                    norm2_w, norm2_b, H2c);
        mm_mlp<<<dim3(512, 4), 256, 0, stream>>>(H2c, fc11_w, fc11_b,
                                                 fc12_w, fc12_b, HIDc);
        mm<4, 240, 120><<<dim3(512, 2), 256, 0, stream>>>(HIDc, fc2_w, fc2_b,
                                                          out, TMP + (size_t)m0 * 120, m0);
    }
}

// Round 5
// 611.984 us; speedup vs baseline: 1.2081x; 1.0182x over previous
//
#include <hip/hip_runtime.h>
#include <hip/hip_bf16.h>
#include <math.h>

// TMSA R11: W-in-LDS (swizzled frags) + A-direct GEMMs.
// R10 post-mortem: staging WRITES were 16-way bank-conflicted (8.3M cycles,
// 21%/CU) - write idx low-3-bits constant across 16 lanes. R11:
//  - only W staged to LDS (real cross-wave reuse), fragment-packed with
//    swz(idx)=idx^((idx>>4)&7): writes 2-way (free), reads still contiguous.
//  - A read direct from global per-frag (R8 style); one a-load feeds 8 MFMAs
//    in mm_mlp (W1+W2 both resident).
//  - LDS 16KB (K=120) / 32KB (K=240) -> 4-5 blocks/CU, stage latency hidden.
// attn_flash/ln unchanged (R8-verified).
//
// ws (bytes), guard 110,100,480:
//   attn phase: Hb bf16 [0,31457280) | QKVc bf16 [31457280,78643200)
//               XOUTc bf16 [78643200,110100480)
//   mlp  phase: TMP fp32 [0,62914560) (d2d copy of X2) |
//               H2c bf16 [62914560,78643200) | HIDc bf16 [78643200,110100480)

typedef __attribute__((ext_vector_type(8))) short bf16x8;
typedef __attribute__((ext_vector_type(4))) float f32x4;

#define SCALE2 (0.22360679774997896f * 1.44269504088896340f)  // d^-0.5 * log2(e)
#define CHROWS 65536
#define QPLANE 7864320u   // 65536*120 elems per q/k/v plane (chunk)

union B8U { bf16x8 v; uint4 u4; uint2 u2[2]; unsigned u[4]; short s[8]; };

__device__ __forceinline__ short bf16b(float f) {
    __hip_bfloat16 h = __float2bfloat16(f);
    return *reinterpret_cast<short*>(&h);
}
__device__ __forceinline__ float bf2f(short s) {
    return __uint_as_float(((unsigned)(unsigned short)s) << 16);
}
__device__ __forceinline__ unsigned packbf(float a, float b) {
    return (unsigned)(unsigned short)bf16b(a) |
           ((unsigned)(unsigned short)bf16b(b) << 16);
}

// LDS frag-index swizzle: staging writes (row fixed, q varies) get 8 distinct
// low-3-bit patterns -> 2-way (free); frag reads (contiguous 64-slot run) get
// a constant XOR per 16-lane group -> permutation within the run, conflict-free.
__device__ __forceinline__ int swz(int idx) { return idx ^ ((idx >> 4) & 7); }

// partitioned row r -> global row g
__device__ __forceinline__ int rev_row(int r) {
    int w = r >> 8, t = r & 255;
    int w8 = w & 7, h8 = (w >> 3) & 7, d2 = (w >> 6) & 1, n2 = w >> 7;
    int www = t & 7, hh = (t >> 3) & 7, dd = (t >> 6) & 1, nn = t >> 7;
    int n = n2 * 2 + nn, d = d2 * 2 + dd;
    int Hc = h8 * 8 + hh, Wc = w8 * 8 + www;
    return ((n * 4 + d) << 12) + (Hc << 6) + Wc;
}
// global row g -> partitioned row
__device__ __forceinline__ int part_row(int g) {
    int ww = g & 63, hh = (g >> 6) & 63, d = (g >> 12) & 3, n = g >> 14;
    int w = ((n >> 1) * 2 + (d >> 1)) * 64 + ((hh >> 3) << 3) + (ww >> 3);
    int t = (((n & 1) * 2 + (d & 1)) << 6) + ((hh & 7) << 3) + (ww & 7);
    return (w << 8) + t;
}
__device__ __forceinline__ float gelu_exact(float x) {
    return 0.5f * x * (1.0f + erff(x * 0.70710678118654752f));
}

// load B-frag from a 20-elem bf16 row (stride 20), k = quad*8..+7, zero-padded.
__device__ __forceinline__ bf16x8 load_frag20(const short* row, int quad) {
    B8U r;
    const uint2* p = (const uint2*)(row + quad * 8);
    r.u2[0] = p[0]; r.u2[1] = p[1];
    if (quad == 2) { r.u[2] = 0; r.u[3] = 0; }
    else if (quad == 3) { r.u[0] = r.u[1] = r.u[2] = r.u[3] = 0; }
    return r.v;
}

// ---- W staging: fp32 (N x K) rows [bn,bn+64) -> bf16 frags, swizzled ------
// frag f=(ntile*NKT+kt) lane(quad,l16) holds W[bn+ntile*16+l16][kt*32+quad*8..+7].
// Chunk q (8 elems) of row -> frag ((row>>4)*NKT + (q>>2)), slot (q&3)*16+(row&15).
// Zero-pad chunks with q*8 >= K (A-side address is clamped there).
template <int K>
__device__ __forceinline__ void stageW_frag(uint4* Wf, const float* __restrict__ W,
                                            int bn, int N, int tid) {
    constexpr int CH   = (K == 120) ? 16 : 32;    // padded chunks per row
    constexpr int NKT  = CH / 4;
    constexpr int ITER = 64 * CH / 256;
#pragma unroll
    for (int i = 0; i < ITER; ++i) {
        int c = i * 256 + tid;
        int row = c / CH, q = c % CH;
        int wr = bn + row; if (wr > N - 1) wr = N - 1;
        uint4 d = make_uint4(0u, 0u, 0u, 0u);
        if (q * 8 < K) {
            f32x4 w0 = *(const f32x4*)(W + (size_t)wr * K + q * 8);
            f32x4 w1 = *(const f32x4*)(W + (size_t)wr * K + q * 8 + 4);
            d = make_uint4(packbf(w0.x, w0.y), packbf(w0.z, w0.w),
                           packbf(w1.x, w1.y), packbf(w1.z, w1.w));
        }
        Wf[swz(((row >> 4) * NKT + (q >> 2)) * 64 + (q & 3) * 16 + (row & 15))] = d;
    }
}

// ---------------- LayerNorm (C=120) fp32 in -> bf16 out ---------------------
template <bool REMAP>
__global__ __launch_bounds__(256) void ln_kernel(const float* __restrict__ in,
                                                 const float* __restrict__ w,
                                                 const float* __restrict__ b,
                                                 short* __restrict__ out) {
    int row  = blockIdx.x * 4 + (threadIdx.x >> 6);
    int lane = threadIdx.x & 63;
    const float* xr = in + (size_t)row * 120;
    float2 v = make_float2(0.f, 0.f);
    if (lane < 60) v = *(const float2*)(xr + lane * 2);
    float s = v.x + v.y;
#pragma unroll
    for (int off = 32; off; off >>= 1) s += __shfl_down(s, off, 64);
    s = __shfl(s, 0, 64);
    float mean = s * (1.f / 120.f);
    float dx = v.x - mean, dy = v.y - mean;
    float q = (lane < 60) ? (dx * dx + dy * dy) : 0.f;
#pragma unroll
    for (int off = 32; off; off >>= 1) q += __shfl_down(q, off, 64);
    q = __shfl(q, 0, 64);
    float rstd = rsqrtf(q * (1.f / 120.f) + 1e-5f);
    int orow = REMAP ? part_row(row) : row;
    if (lane < 60) {
        float2 wv = *(const float2*)(w + lane * 2);
        float2 bv = *(const float2*)(b + lane * 2);
        unsigned u = packbf(dx * rstd * wv.x + bv.x, dy * rstd * wv.y + bv.y);
        *(unsigned*)(out + (size_t)orow * 120 + lane * 2) = u;
    }
}

// --- MFMA GEMM, W-in-LDS / A-direct: out = A(MxK bf16) @ W(NxK fp32)^T + b --
// MODE: 0 QKV scatter (q pre-scaled by SCALE2) | 1 proj(+x res -> X2 fp32)
//       4 fc2(+TMP res -> d_out @rev_row)
template <int MODE, int K, int N>
__global__ __launch_bounds__(256) void mm(const short* __restrict__ A,
                                          const float* __restrict__ W,
                                          const float* __restrict__ bias,
                                          void* __restrict__ outp,
                                          const float* __restrict__ aux,
                                          int m0) {
    constexpr int NKT = (K + 31) / 32;        // 4 (K=120) or 8 (K=240)
    __shared__ uint4 Wf[4 * NKT * 64];        // 16KB or 32KB
    const int tid = threadIdx.x;
    const int lane = tid & 63, wave = tid >> 6;
    const int quad = lane >> 4, l16 = lane & 15;
    const int bm  = blockIdx.x * 128 + (wave >> 1) * 64;
    const int bnb = blockIdx.y * 64;
    const int wtile = (wave & 1) * 2;

    stageW_frag<K>(Wf, W, bnb, N, tid);

    const short* Ar[4];
#pragma unroll
    for (int i = 0; i < 4; ++i) Ar[i] = A + (size_t)(bm + i * 16 + l16) * K;

    f32x4 acc[4][2];
#pragma unroll
    for (int i = 0; i < 4; ++i)
#pragma unroll
        for (int j = 0; j < 2; ++j) acc[i][j] = (f32x4){0.f, 0.f, 0.f, 0.f};

    __syncthreads();
#pragma unroll
    for (int kt = 0; kt < NKT; ++kt) {
        int k = kt * 32 + quad * 8;
        int kc = (k + 8 <= K) ? k : 0;        // clamp; W frag is zero there
        B8U b0, b1;
        b0.u4 = Wf[swz(((wtile + 0) * NKT + kt) * 64 + lane)];
        b1.u4 = Wf[swz(((wtile + 1) * NKT + kt) * 64 + lane)];
#pragma unroll
        for (int i = 0; i < 4; ++i) {
            bf16x8 a = *(const bf16x8*)(Ar[i] + kc);
            acc[i][0] = __builtin_amdgcn_mfma_f32_16x16x32_bf16(a, b0.v, acc[i][0], 0, 0, 0);
            acc[i][1] = __builtin_amdgcn_mfma_f32_16x16x32_bf16(a, b1.v, acc[i][1], 0, 0, 0);
        }
    }

#pragma unroll
    for (int j = 0; j < 2; ++j) {
        const int n = bnb + wtile * 16 + j * 16 + l16;
        if (n >= N) continue;
        const float bs = bias[n];
        int which = 0, head = 0, e = 0;
        if (MODE == 0) { which = n / 120; int hn = n % 120; head = hn / 20; e = hn % 20; }
#pragma unroll
        for (int i = 0; i < 4; ++i) {
#pragma unroll
            for (int r = 0; r < 4; ++r) {
                int m = bm + i * 16 + quad * 4 + r;
                float val = acc[i][j][r] + bs;
                if (MODE == 0) {
                    if (which == 0) val *= SCALE2;
                    int wl = m >> 8, t = m & 255;
                    ((short*)outp)[(size_t)which * QPLANE +
                                   ((size_t)((wl * 6 + head) * 256 + t)) * 20 + e] = bf16b(val);
                } else if (MODE == 1) {
                    int g = rev_row(m0 + m);
                    val += aux[(size_t)g * 120 + n];
                    ((float*)outp)[(size_t)(m0 + m) * 120 + n] = val;
                } else { // MODE 4: aux pre-offset by m0*120; scatter to d_out
                    int g = rev_row(m0 + m);
                    val += aux[(size_t)m * 120 + n];
                    ((float*)outp)[(size_t)g * 120 + n] = val;
                }
            }
        }
    }
}

// ---- fused MLP up-projection: HID = gelu(A@W1^T+b1) * (A@W2^T+b2) ----------
// Both W's resident (2x16KB swizzled frags); each a-frag load feeds 8 MFMAs.
__global__ __launch_bounds__(256) void mm_mlp(const short* __restrict__ A,
                                              const float* __restrict__ W1,
                                              const float* __restrict__ b1,
                                              const float* __restrict__ W2,
                                              const float* __restrict__ b2,
                                              short* __restrict__ outp) {
    __shared__ uint4 Wf[2][4 * 4 * 64];
    const int tid = threadIdx.x;
    const int lane = tid & 63, wave = tid >> 6;
    const int quad = lane >> 4, l16 = lane & 15;
    const int bm  = blockIdx.x * 128 + (wave >> 1) * 64;
    const int bnb = blockIdx.y * 64;
    const int wtile = (wave & 1) * 2;
    const int N = 240;

    stageW_frag<120>(Wf[0], W1, bnb, N, tid);
    stageW_frag<120>(Wf[1], W2, bnb, N, tid);

    const short* Ar[4];
#pragma unroll
    for (int i = 0; i < 4; ++i) Ar[i] = A + (size_t)(bm + i * 16 + l16) * 120;

    f32x4 acc1[4][2], acc2[4][2];
#pragma unroll
    for (int i = 0; i < 4; ++i)
#pragma unroll
        for (int j = 0; j < 2; ++j) {
            acc1[i][j] = (f32x4){0.f, 0.f, 0.f, 0.f};
            acc2[i][j] = (f32x4){0.f, 0.f, 0.f, 0.f};
        }

    __syncthreads();
#pragma unroll
    for (int kt = 0; kt < 4; ++kt) {
        int k = kt * 32 + quad * 8;
        int kc = (k + 8 <= 120) ? k : 0;
        B8U p0, p1, q0, q1;
        p0.u4 = Wf[0][swz(((wtile + 0) * 4 + kt) * 64 + lane)];
        p1.u4 = Wf[0][swz(((wtile + 1) * 4 + kt) * 64 + lane)];
        q0.u4 = Wf[1][swz(((wtile + 0) * 4 + kt) * 64 + lane)];
        q1.u4 = Wf[1][swz(((wtile + 1) * 4 + kt) * 64 + lane)];
#pragma unroll
        for (int i = 0; i < 4; ++i) {
            bf16x8 a = *(const bf16x8*)(Ar[i] + kc);
            acc1[i][0] = __builtin_amdgcn_mfma_f32_16x16x32_bf16(a, p0.v, acc1[i][0], 0, 0, 0);
            acc1[i][1] = __builtin_amdgcn_mfma_f32_16x16x32_bf16(a, p1.v, acc1[i][1], 0, 0, 0);
            acc2[i][0] = __builtin_amdgcn_mfma_f32_16x16x32_bf16(a, q0.v, acc2[i][0], 0, 0, 0);
            acc2[i][1] = __builtin_amdgcn_mfma_f32_16x16x32_bf16(a, q1.v, acc2[i][1], 0, 0, 0);
        }
    }

#pragma unroll
    for (int j = 0; j < 2; ++j) {
        const int n = bnb + wtile * 16 + j * 16 + l16;
        if (n >= N) continue;
        const float g1 = b1[n], g2 = b2[n];
#pragma unroll
        for (int i = 0; i < 4; ++i) {
#pragma unroll
            for (int r = 0; r < 4; ++r) {
                int m = bm + i * 16 + quad * 4 + r;
                float gv = acc1[i][j][r] + g1;
                float vv = acc2[i][j][r] + g2;
                outp[(size_t)m * 240 + n] = bf16b(gelu_exact(gv) * vv);
            }
        }
    }
}

// ---------------- MFMA flash attention, LDS-fed, zero-shuffle ----------------
// K staged to LDS in fragment order (quad3 slot dropped; reads clamp to quad2,
// safe: finite K data x bq=0). V^T staged as u32 dim-pairs, 11 rows; row 10 =
// bf16(1.0) at dim20 -> PV MFMA accumulates l in accO[t][1][0] (quad1).
// nt processed in 2 passes of 2 to halve live acc registers.
template <int NK, bool MUT>
__global__ __launch_bounds__(NK) void attn_flash(const short* __restrict__ qkv,
                                                 short* __restrict__ xout) {
    constexpr int NKT = NK / 32;
    constexpr int VSTR2 = NK + 4;                  // u32 stride (16B-aligned rows)
    __shared__ __align__(16) short Kf[NKT * 2 * 48 * 8];
    __shared__ __align__(16) unsigned Vt2[11 * VSTR2];
    const int b = blockIdx.x;
    int wl, hd, half;
    if (MUT) { half = b & 1; hd = (b >> 1) % 6; wl = b / 12; }
    else     { half = 0;     hd = b % 6;        wl = b / 6;  }
    const int tid  = threadIdx.x;
    const int lane = tid & 63, wave = tid >> 6;
    const int quad = lane >> 4, l16 = lane & 15;

    const size_t rb = (size_t)(wl * 6 + hd) * 256;
    const short* qpl = qkv + rb * 20;
    const short* kpl = qkv + (size_t)QPLANE + rb * 20;
    const short* vpl = qkv + 2 * (size_t)QPLANE + rb * 20;
    const int koff = MUT ? half * 128 : 0;
    const int qoff = MUT ? (1 - half) * 128 : 0;

    // ---- stage V^T (u32 dim-pairs; row10 = ones at dim20) and K (frag order) ----
    {
        const uint2* p = (const uint2*)(vpl + (size_t)(koff + tid) * 20);
        unsigned tmp[10];
#pragma unroll
        for (int i = 0; i < 5; ++i) ((uint2*)tmp)[i] = p[i];
#pragma unroll
        for (int i = 0; i < 10; ++i) Vt2[i * VSTR2 + tid] = tmp[i];
        Vt2[10 * VSTR2 + tid] = 0x00003F80u;   // dim20 = bf16(1.0), dim21 = 0

        int skt = tid >> 5, sf = (tid >> 4) & 1, sl = tid & 15;
        int srow = koff + skt * 32 + sf * 4 + ((sl >> 2) << 3) + (sl & 3);
        const uint2* kp = (const uint2*)(kpl + (size_t)srow * 20);
        uint2 k0 = kp[0], k1 = kp[1], k2 = kp[2], k3 = kp[3], k4 = kp[4];
        uint4* dst = (uint4*)Kf + ((skt * 2 + sf) * 48 + sl);
        dst[0]  = make_uint4(k0.x, k0.y, k1.x, k1.y);   // quad0: d0-7
        dst[16] = make_uint4(k2.x, k2.y, k3.x, k3.y);   // quad1: d8-15
        dst[32] = make_uint4(k4.x, k4.y, 0u, 0u);       // quad2: d16-23
    }
    __syncthreads();

    const int quadc = quad < 3 ? quad : 2;             // quad3 aliases quad2 (x0)
    const uint4* kfrag = (const uint4*)Kf + quadc * 16 + l16;
    const unsigned sel = (l16 & 1) ? 0x07060302u : 0x05040100u;
    const unsigned* vbase0 = Vt2 + (l16 >> 1) * VSTR2;
    int r1 = 8 + (l16 >> 1); if (r1 > 10) r1 = 10;     // rows>=11 feed unused dims
    const unsigned* vbase1 = Vt2 + r1 * VSTR2;
    const f32x4 z4 = {0.f, 0.f, 0.f, 0.f};

#pragma unroll 1
    for (int g = 0; g < 2; ++g) {
        bf16x8 bq0 = load_frag20(qpl + (size_t)(qoff + wave * 64 + (g * 2 + 0) * 16 + l16) * 20, quad);
        bf16x8 bq1 = load_frag20(qpl + (size_t)(qoff + wave * 64 + (g * 2 + 1) * 16 + l16) * 20, quad);

        f32x4 accO[2][2];
        accO[0][0] = z4; accO[0][1] = z4; accO[1][0] = z4; accO[1][1] = z4;

#pragma unroll
        for (int kt = 0; kt < NKT; ++kt) {
            B8U ak0, ak1;
            ak0.u4 = kfrag[(kt * 2 + 0) * 48];
            ak1.u4 = kfrag[(kt * 2 + 1) * 48];
            B8U av0, av1;
            {
                uint4 va = *(const uint4*)(vbase0 + kt * 32 + quad * 8);
                uint4 vb = *(const uint4*)(vbase0 + kt * 32 + quad * 8 + 4);
                av0.u[0] = __builtin_amdgcn_perm(va.y, va.x, sel);
                av0.u[1] = __builtin_amdgcn_perm(va.w, va.z, sel);
                av0.u[2] = __builtin_amdgcn_perm(vb.y, vb.x, sel);
                av0.u[3] = __builtin_amdgcn_perm(vb.w, vb.z, sel);
                uint4 vc = *(const uint4*)(vbase1 + kt * 32 + quad * 8);
                uint4 vd = *(const uint4*)(vbase1 + kt * 32 + quad * 8 + 4);
                av1.u[0] = __builtin_amdgcn_perm(vc.y, vc.x, sel);
                av1.u[1] = __builtin_amdgcn_perm(vc.w, vc.z, sel);
                av1.u[2] = __builtin_amdgcn_perm(vd.y, vd.x, sel);
                av1.u[3] = __builtin_amdgcn_perm(vd.w, vd.z, sel);
            }
#pragma unroll
            for (int t = 0; t < 2; ++t) {
                bf16x8 bqt = t ? bq1 : bq0;
                f32x4 s0 = __builtin_amdgcn_mfma_f32_16x16x32_bf16(ak0.v, bqt, z4, 0, 0, 0);
                f32x4 s1 = __builtin_amdgcn_mfma_f32_16x16x32_bf16(ak1.v, bqt, z4, 0, 0, 0);
                float p0 = __builtin_amdgcn_exp2f(s0[0]), p1 = __builtin_amdgcn_exp2f(s0[1]);
                float p2 = __builtin_amdgcn_exp2f(s0[2]), p3 = __builtin_amdgcn_exp2f(s0[3]);
                float p4 = __builtin_amdgcn_exp2f(s1[0]), p5 = __builtin_amdgcn_exp2f(s1[1]);
                float p6 = __builtin_amdgcn_exp2f(s1[2]), p7 = __builtin_amdgcn_exp2f(s1[3]);
                B8U bp;   // P^T B-frag: j=0..3 <- s0 regs, j=4..7 <- s1 regs
                bp.u[0] = packbf(p0, p1);
                bp.u[1] = packbf(p2, p3);
                bp.u[2] = packbf(p4, p5);
                bp.u[3] = packbf(p6, p7);
                accO[t][0] = __builtin_amdgcn_mfma_f32_16x16x32_bf16(av0.v, bp.v, accO[t][0], 0, 0, 0);
                accO[t][1] = __builtin_amdgcn_mfma_f32_16x16x32_bf16(av1.v, bp.v, accO[t][1], 0, 0, 0);
            }
        }

        // epilogue: O^T C-layout (col l16=query, row quad*4+r=dim);
        // l = accO[t][1][0] on quad1 (dim20 ones-column)
#pragma unroll
        for (int t = 0; t < 2; ++t) {
            int nt = g * 2 + t;
            float l = __shfl(accO[t][1][0], 16 + l16, 64);
            float inv = 1.f / l;
            int tok = (MUT ? half * 128 : 0) + wave * 64 + nt * 16 + l16;
            short* orow = xout + (size_t)(wl * 256 + tok) * 240 + (MUT ? hd * 20 : 120 + hd * 20);
            unsigned lo = packbf(accO[t][0][0] * inv, accO[t][0][1] * inv);
            unsigned hi2 = packbf(accO[t][0][2] * inv, accO[t][0][3] * inv);
            *(uint2*)(orow + quad * 4) = make_uint2(lo, hi2);
            if (quad == 0) {
                unsigned lo2 = packbf(accO[t][1][0] * inv, accO[t][1][1] * inv);
                unsigned hi3 = packbf(accO[t][1][2] * inv, accO[t][1][3] * inv);
                *(uint2*)(orow + 16) = make_uint2(lo2, hi3);
            }
        }
    }
}

extern "C" void kernel_launch(void* const* d_in, const int* in_sizes, int n_in,
                              void* d_out, int out_size, void* d_ws, size_t ws_size,
                              hipStream_t stream) {
    const float* x          = (const float*)d_in[0];
    const float* norm1_w    = (const float*)d_in[1];
    const float* norm1_b    = (const float*)d_in[2];
    const float* qkv_self_w = (const float*)d_in[3];
    const float* qkv_self_b = (const float*)d_in[4];
    const float* qkv_mut_w  = (const float*)d_in[5];
    const float* qkv_mut_b  = (const float*)d_in[6];
    const float* proj_w     = (const float*)d_in[7];
    const float* proj_b     = (const float*)d_in[8];
    const float* norm2_w    = (const float*)d_in[9];
    const float* norm2_b    = (const float*)d_in[10];
    const float* fc11_w     = (const float*)d_in[11];
    const float* fc11_b     = (const float*)d_in[12];
    const float* fc12_w     = (const float*)d_in[13];
    const float* fc12_b     = (const float*)d_in[14];
    const float* fc2_w      = (const float*)d_in[15];
    const float* fc2_b      = (const float*)d_in[16];

    if (ws_size < 110100480u) return;

    char* wsb   = (char*)d_ws;
    short* Hb    = (short*)wsb;                  // 131072x120 bf16
    short* QKVc  = (short*)(wsb + 31457280);     // 3 planes, chunk
    short* XOUTc = (short*)(wsb + 78643200);     // 65536x240 bf16
    float* TMP   = (float*)wsb;                  // X2 copy, fp32 (MLP phase)
    short* H2c   = (short*)(wsb + 62914560);     // 65536x120 bf16
    short* HIDc  = (short*)(wsb + 78643200);     // 65536x240 bf16
    float* X2    = (float*)d_out;                // partitioned residual fp32
    float* out   = (float*)d_out;

    // 1. LN1 + window partition -> Hb (bf16)
    ln_kernel<true><<<32768, 256, 0, stream>>>(x, norm1_w, norm1_b, Hb);

    // 2. Attention phase: 2 chunks x 256 windows
    for (int c = 0; c < 2; ++c) {
        int m0 = c * CHROWS;
        const short* Ac = Hb + (size_t)m0 * 120;
        mm<0, 120, 360><<<dim3(512, 6), 256, 0, stream>>>(Ac, qkv_self_w, qkv_self_b,
                                                          QKVc, nullptr, 0);
        attn_flash<256, false><<<1536, 256, 0, stream>>>(QKVc, XOUTc);
        mm<0, 120, 360><<<dim3(512, 6), 256, 0, stream>>>(Ac, qkv_mut_w, qkv_mut_b,
                                                          QKVc, nullptr, 0);
        attn_flash<128, true><<<3072, 128, 0, stream>>>(QKVc, XOUTc);
        mm<1, 240, 120><<<dim3(512, 2), 256, 0, stream>>>(XOUTc, proj_w, proj_b,
                                                          X2, x, m0);
    }

    // 3. X2 -> TMP (frees d_out for scatter writes; residual source)
    hipMemcpyAsync(TMP, d_out, 62914560u, hipMemcpyDeviceToDevice, stream);

    // 4. MLP phase: 2 chunks x 65536 rows; fc2 scatters straight into d_out
    for (int c = 0; c < 2; ++c) {
        int m0 = c * CHROWS;
        ln_kernel<false><<<16384, 256, 0, stream>>>(TMP + (size_t)m0 * 120,
                                                    norm2_w, norm2_b, H2c);
        mm_mlp<<<dim3(512, 4), 256, 0, stream>>>(H2c, fc11_w, fc11_b,
                                                 fc12_w, fc12_b, HIDc);
        mm<4, 240, 120><<<dim3(512, 2), 256, 0, stream>>>(HIDc, fc2_w, fc2_b,
                                                          out, TMP + (size_t)m0 * 120, m0);
    }
}

// Round 6
// 598.719 us; speedup vs baseline: 1.2348x; 1.0222x over previous
//
#include <hip/hip_runtime.h>
#include <hip/hip_bf16.h>
#include <math.h>

// TMSA R12: amortize fixed costs, stream at BW.
//  - LN rewrite: float4/lane, 2 rows/wave (half-wave rows), width-32 shfl_xor
//    butterfly (5+5). Was: 8B/lane, 1 row/wave, 12-step width-64 chain, 43us
//    at 18% HBM.
//  - Per-chunk pipeline: MLP is row-local -> run LN2/mm_mlp/fc2 inside the
//    chunk loop. mm<1> writes TMPc to ws (over dead QKV area); memcpy DELETED;
//    d_out written only by mm<4> scatter.
//  - MT=8 (256-row blocks) for all GEMMs: 2x MFMA per staged W, half the
//    blocks, half the total W-convert+stage cost.
// attn_flash unchanged (R8-verified).
//
// ws (bytes), guard 110,100,480. Per chunk c:
//   Hb   bf16 [0,31457280)            (both chunks, written once)
//   QKVc bf16 [31457280,78643200)     (dead after attn-mut)
//   XOUTc bf16 [78643200,110100480)   (dead after mm<1>)
//   TMPc fp32 [31457280,62914560)     (over dead QKV)
//   H2c  bf16 [62914560,78643200)     (over dead QKV)
//   HIDc bf16 [78643200,110100480)    (over dead XOUTc)

typedef __attribute__((ext_vector_type(8))) short bf16x8;
typedef __attribute__((ext_vector_type(4))) float f32x4;

#define SCALE2 (0.22360679774997896f * 1.44269504088896340f)  // d^-0.5 * log2(e)
#define CHROWS 65536
#define QPLANE 7864320u   // 65536*120 elems per q/k/v plane (chunk)

union B8U { bf16x8 v; uint4 u4; uint2 u2[2]; unsigned u[4]; short s[8]; };

__device__ __forceinline__ short bf16b(float f) {
    __hip_bfloat16 h = __float2bfloat16(f);
    return *reinterpret_cast<short*>(&h);
}
__device__ __forceinline__ float bf2f(short s) {
    return __uint_as_float(((unsigned)(unsigned short)s) << 16);
}
__device__ __forceinline__ unsigned packbf(float a, float b) {
    return (unsigned)(unsigned short)bf16b(a) |
           ((unsigned)(unsigned short)bf16b(b) << 16);
}

// LDS frag-index swizzle (R11-verified: writes 2-way free, reads contiguous)
__device__ __forceinline__ int swz(int idx) { return idx ^ ((idx >> 4) & 7); }

// partitioned row r -> global row g
__device__ __forceinline__ int rev_row(int r) {
    int w = r >> 8, t = r & 255;
    int w8 = w & 7, h8 = (w >> 3) & 7, d2 = (w >> 6) & 1, n2 = w >> 7;
    int www = t & 7, hh = (t >> 3) & 7, dd = (t >> 6) & 1, nn = t >> 7;
    int n = n2 * 2 + nn, d = d2 * 2 + dd;
    int Hc = h8 * 8 + hh, Wc = w8 * 8 + www;
    return ((n * 4 + d) << 12) + (Hc << 6) + Wc;
}
// global row g -> partitioned row
__device__ __forceinline__ int part_row(int g) {
    int ww = g & 63, hh = (g >> 6) & 63, d = (g >> 12) & 3, n = g >> 14;
    int w = ((n >> 1) * 2 + (d >> 1)) * 64 + ((hh >> 3) << 3) + (ww >> 3);
    int t = (((n & 1) * 2 + (d & 1)) << 6) + ((hh & 7) << 3) + (ww & 7);
    return (w << 8) + t;
}
__device__ __forceinline__ float gelu_exact(float x) {
    return 0.5f * x * (1.0f + erff(x * 0.70710678118654752f));
}

// load B-frag from a 20-elem bf16 row (stride 20), k = quad*8..+7, zero-padded.
__device__ __forceinline__ bf16x8 load_frag20(const short* row, int quad) {
    B8U r;
    const uint2* p = (const uint2*)(row + quad * 8);
    r.u2[0] = p[0]; r.u2[1] = p[1];
    if (quad == 2) { r.u[2] = 0; r.u[3] = 0; }
    else if (quad == 3) { r.u[0] = r.u[1] = r.u[2] = r.u[3] = 0; }
    return r.v;
}

// ---- W staging: fp32 (N x K) rows [bn,bn+64) -> bf16 frags, swizzled ------
template <int K>
__device__ __forceinline__ void stageW_frag(uint4* Wf, const float* __restrict__ W,
                                            int bn, int N, int tid) {
    constexpr int CH   = (K == 120) ? 16 : 32;    // padded chunks per row
    constexpr int NKT  = CH / 4;
    constexpr int ITER = 64 * CH / 256;
#pragma unroll
    for (int i = 0; i < ITER; ++i) {
        int c = i * 256 + tid;
        int row = c / CH, q = c % CH;
        int wr = bn + row; if (wr > N - 1) wr = N - 1;
        uint4 d = make_uint4(0u, 0u, 0u, 0u);
        if (q * 8 < K) {
            f32x4 w0 = *(const f32x4*)(W + (size_t)wr * K + q * 8);
            f32x4 w1 = *(const f32x4*)(W + (size_t)wr * K + q * 8 + 4);
            d = make_uint4(packbf(w0.x, w0.y), packbf(w0.z, w0.w),
                           packbf(w1.x, w1.y), packbf(w1.z, w1.w));
        }
        Wf[swz(((row >> 4) * NKT + (q >> 2)) * 64 + (q & 3) * 16 + (row & 15))] = d;
    }
}

// -------- LayerNorm (C=120) fp32 -> bf16, 2 rows/wave, width-32 butterfly ---
template <bool REMAP>
__global__ __launch_bounds__(256) void ln_kernel(const float* __restrict__ in,
                                                 const float* __restrict__ w,
                                                 const float* __restrict__ b,
                                                 short* __restrict__ out) {
    const int tid = threadIdx.x;
    const int lane = tid & 63, wave = tid >> 6;
    const int half = lane >> 5, hl = lane & 31;
    const int row = blockIdx.x * 8 + wave * 2 + half;
    const float* xr = in + (size_t)row * 120;
    f32x4 v = (f32x4){0.f, 0.f, 0.f, 0.f};
    if (hl < 30) v = *(const f32x4*)(xr + hl * 4);
    float s = (v.x + v.y) + (v.z + v.w);
#pragma unroll
    for (int off = 16; off; off >>= 1) s += __shfl_xor(s, off, 32);
    float mean = s * (1.f / 120.f);
    float d0 = v.x - mean, d1 = v.y - mean, d2 = v.z - mean, d3 = v.w - mean;
    float q = (hl < 30) ? (d0 * d0 + d1 * d1) + (d2 * d2 + d3 * d3) : 0.f;
#pragma unroll
    for (int off = 16; off; off >>= 1) q += __shfl_xor(q, off, 32);
    float rstd = rsqrtf(q * (1.f / 120.f) + 1e-5f);
    int orow = REMAP ? part_row(row) : row;
    if (hl < 30) {
        f32x4 wv = *(const f32x4*)(w + hl * 4);
        f32x4 bv = *(const f32x4*)(b + hl * 4);
        unsigned u0 = packbf(d0 * rstd * wv.x + bv.x, d1 * rstd * wv.y + bv.y);
        unsigned u1 = packbf(d2 * rstd * wv.z + bv.z, d3 * rstd * wv.w + bv.w);
        *(uint2*)(out + (size_t)orow * 120 + hl * 4) = make_uint2(u0, u1);
    }
}

// --- MFMA GEMM, W-in-LDS / A-direct, MT i-tiles per wave (M = MT*32/block) --
// MODE: 0 QKV scatter (q pre-scaled by SCALE2) | 1 proj(+x res -> TMPc local)
//       4 fc2(+TMPc res -> d_out @rev_row)
template <int MODE, int K, int N, int MT>
__global__ __launch_bounds__(256) void mm(const short* __restrict__ A,
                                          const float* __restrict__ W,
                                          const float* __restrict__ bias,
                                          void* __restrict__ outp,
                                          const float* __restrict__ aux,
                                          int m0) {
    constexpr int NKT = (K + 31) / 32;        // 4 (K=120) or 8 (K=240)
    __shared__ uint4 Wf[4 * NKT * 64];        // 16KB or 32KB
    const int tid = threadIdx.x;
    const int lane = tid & 63, wave = tid >> 6;
    const int quad = lane >> 4, l16 = lane & 15;
    const int bm  = blockIdx.x * (MT * 32) + (wave >> 1) * (MT * 16);
    const int bnb = blockIdx.y * 64;
    const int wtile = (wave & 1) * 2;

    stageW_frag<K>(Wf, W, bnb, N, tid);

    const short* Ar[MT];
#pragma unroll
    for (int i = 0; i < MT; ++i) Ar[i] = A + (size_t)(bm + i * 16 + l16) * K;

    f32x4 acc[MT][2];
#pragma unroll
    for (int i = 0; i < MT; ++i)
#pragma unroll
        for (int j = 0; j < 2; ++j) acc[i][j] = (f32x4){0.f, 0.f, 0.f, 0.f};

    __syncthreads();
#pragma unroll
    for (int kt = 0; kt < NKT; ++kt) {
        int k = kt * 32 + quad * 8;
        int kc = (k + 8 <= K) ? k : 0;        // clamp; W frag is zero there
        B8U b0, b1;
        b0.u4 = Wf[swz(((wtile + 0) * NKT + kt) * 64 + lane)];
        b1.u4 = Wf[swz(((wtile + 1) * NKT + kt) * 64 + lane)];
#pragma unroll
        for (int i = 0; i < MT; ++i) {
            bf16x8 a = *(const bf16x8*)(Ar[i] + kc);
            acc[i][0] = __builtin_amdgcn_mfma_f32_16x16x32_bf16(a, b0.v, acc[i][0], 0, 0, 0);
            acc[i][1] = __builtin_amdgcn_mfma_f32_16x16x32_bf16(a, b1.v, acc[i][1], 0, 0, 0);
        }
    }

#pragma unroll
    for (int j = 0; j < 2; ++j) {
        const int n = bnb + wtile * 16 + j * 16 + l16;
        if (n >= N) continue;
        const float bs = bias[n];
        int which = 0, head = 0, e = 0;
        if (MODE == 0) { which = n / 120; int hn = n % 120; head = hn / 20; e = hn % 20; }
#pragma unroll
        for (int i = 0; i < MT; ++i) {
#pragma unroll
            for (int r = 0; r < 4; ++r) {
                int m = bm + i * 16 + quad * 4 + r;
                float val = acc[i][j][r] + bs;
                if (MODE == 0) {
                    if (which == 0) val *= SCALE2;
                    int wl = m >> 8, t = m & 255;
                    ((short*)outp)[(size_t)which * QPLANE +
                                   ((size_t)((wl * 6 + head) * 256 + t)) * 20 + e] = bf16b(val);
                } else if (MODE == 1) {
                    int g = rev_row(m0 + m);
                    val += aux[(size_t)g * 120 + n];
                    ((float*)outp)[(size_t)m * 120 + n] = val;   // chunk-local
                } else { // MODE 4: aux = TMPc (chunk-local); scatter to d_out
                    int g = rev_row(m0 + m);
                    val += aux[(size_t)m * 120 + n];
                    ((float*)outp)[(size_t)g * 120 + n] = val;
                }
            }
        }
    }
}

// ---- fused MLP up-projection: HID = gelu(A@W1^T+b1) * (A@W2^T+b2), MT=8 ----
__global__ __launch_bounds__(256) void mm_mlp(const short* __restrict__ A,
                                              const float* __restrict__ W1,
                                              const float* __restrict__ b1,
                                              const float* __restrict__ W2,
                                              const float* __restrict__ b2,
                                              short* __restrict__ outp) {
    constexpr int MT = 8;
    __shared__ uint4 Wf[2][4 * 4 * 64];
    const int tid = threadIdx.x;
    const int lane = tid & 63, wave = tid >> 6;
    const int quad = lane >> 4, l16 = lane & 15;
    const int bm  = blockIdx.x * (MT * 32) + (wave >> 1) * (MT * 16);
    const int bnb = blockIdx.y * 64;
    const int wtile = (wave & 1) * 2;
    const int N = 240;

    stageW_frag<120>(Wf[0], W1, bnb, N, tid);
    stageW_frag<120>(Wf[1], W2, bnb, N, tid);

    const short* Ar[MT];
#pragma unroll
    for (int i = 0; i < MT; ++i) Ar[i] = A + (size_t)(bm + i * 16 + l16) * 120;

    f32x4 acc1[MT][2], acc2[MT][2];
#pragma unroll
    for (int i = 0; i < MT; ++i)
#pragma unroll
        for (int j = 0; j < 2; ++j) {
            acc1[i][j] = (f32x4){0.f, 0.f, 0.f, 0.f};
            acc2[i][j] = (f32x4){0.f, 0.f, 0.f, 0.f};
        }

    __syncthreads();
#pragma unroll
    for (int kt = 0; kt < 4; ++kt) {
        int k = kt * 32 + quad * 8;
        int kc = (k + 8 <= 120) ? k : 0;
        B8U p0, p1, q0, q1;
        p0.u4 = Wf[0][swz(((wtile + 0) * 4 + kt) * 64 + lane)];
        p1.u4 = Wf[0][swz(((wtile + 1) * 4 + kt) * 64 + lane)];
        q0.u4 = Wf[1][swz(((wtile + 0) * 4 + kt) * 64 + lane)];
        q1.u4 = Wf[1][swz(((wtile + 1) * 4 + kt) * 64 + lane)];
#pragma unroll
        for (int i = 0; i < MT; ++i) {
            bf16x8 a = *(const bf16x8*)(Ar[i] + kc);
            acc1[i][0] = __builtin_amdgcn_mfma_f32_16x16x32_bf16(a, p0.v, acc1[i][0], 0, 0, 0);
            acc1[i][1] = __builtin_amdgcn_mfma_f32_16x16x32_bf16(a, p1.v, acc1[i][1], 0, 0, 0);
            acc2[i][0] = __builtin_amdgcn_mfma_f32_16x16x32_bf16(a, q0.v, acc2[i][0], 0, 0, 0);
            acc2[i][1] = __builtin_amdgcn_mfma_f32_16x16x32_bf16(a, q1.v, acc2[i][1], 0, 0, 0);
        }
    }

#pragma unroll
    for (int j = 0; j < 2; ++j) {
        const int n = bnb + wtile * 16 + j * 16 + l16;
        if (n >= N) continue;
        const float g1 = b1[n], g2 = b2[n];
#pragma unroll
        for (int i = 0; i < MT; ++i) {
#pragma unroll
            for (int r = 0; r < 4; ++r) {
                int m = bm + i * 16 + quad * 4 + r;
                float gv = acc1[i][j][r] + g1;
                float vv = acc2[i][j][r] + g2;
                outp[(size_t)m * 240 + n] = bf16b(gelu_exact(gv) * vv);
            }
        }
    }
}

// ---------------- MFMA flash attention, LDS-fed, zero-shuffle ----------------
template <int NK, bool MUT>
__global__ __launch_bounds__(NK) void attn_flash(const short* __restrict__ qkv,
                                                 short* __restrict__ xout) {
    constexpr int NKT = NK / 32;
    constexpr int VSTR2 = NK + 4;                  // u32 stride (16B-aligned rows)
    __shared__ __align__(16) short Kf[NKT * 2 * 48 * 8];
    __shared__ __align__(16) unsigned Vt2[11 * VSTR2];
    const int b = blockIdx.x;
    int wl, hd, half;
    if (MUT) { half = b & 1; hd = (b >> 1) % 6; wl = b / 12; }
    else     { half = 0;     hd = b % 6;        wl = b / 6;  }
    const int tid  = threadIdx.x;
    const int lane = tid & 63, wave = tid >> 6;
    const int quad = lane >> 4, l16 = lane & 15;

    const size_t rb = (size_t)(wl * 6 + hd) * 256;
    const short* qpl = qkv + rb * 20;
    const short* kpl = qkv + (size_t)QPLANE + rb * 20;
    const short* vpl = qkv + 2 * (size_t)QPLANE + rb * 20;
    const int koff = MUT ? half * 128 : 0;
    const int qoff = MUT ? (1 - half) * 128 : 0;

    // ---- stage V^T (u32 dim-pairs; row10 = ones at dim20) and K (frag order) ----
    {
        const uint2* p = (const uint2*)(vpl + (size_t)(koff + tid) * 20);
        unsigned tmp[10];
#pragma unroll
        for (int i = 0; i < 5; ++i) ((uint2*)tmp)[i] = p[i];
#pragma unroll
        for (int i = 0; i < 10; ++i) Vt2[i * VSTR2 + tid] = tmp[i];
        Vt2[10 * VSTR2 + tid] = 0x00003F80u;   // dim20 = bf16(1.0), dim21 = 0

        int skt = tid >> 5, sf = (tid >> 4) & 1, sl = tid & 15;
        int srow = koff + skt * 32 + sf * 4 + ((sl >> 2) << 3) + (sl & 3);
        const uint2* kp = (const uint2*)(kpl + (size_t)srow * 20);
        uint2 k0 = kp[0], k1 = kp[1], k2 = kp[2], k3 = kp[3], k4 = kp[4];
        uint4* dst = (uint4*)Kf + ((skt * 2 + sf) * 48 + sl);
        dst[0]  = make_uint4(k0.x, k0.y, k1.x, k1.y);   // quad0: d0-7
        dst[16] = make_uint4(k2.x, k2.y, k3.x, k3.y);   // quad1: d8-15
        dst[32] = make_uint4(k4.x, k4.y, 0u, 0u);       // quad2: d16-23
    }
    __syncthreads();

    const int quadc = quad < 3 ? quad : 2;             // quad3 aliases quad2 (x0)
    const uint4* kfrag = (const uint4*)Kf + quadc * 16 + l16;
    const unsigned sel = (l16 & 1) ? 0x07060302u : 0x05040100u;
    const unsigned* vbase0 = Vt2 + (l16 >> 1) * VSTR2;
    int r1 = 8 + (l16 >> 1); if (r1 > 10) r1 = 10;     // rows>=11 feed unused dims
    const unsigned* vbase1 = Vt2 + r1 * VSTR2;
    const f32x4 z4 = {0.f, 0.f, 0.f, 0.f};

#pragma unroll 1
    for (int g = 0; g < 2; ++g) {
        bf16x8 bq0 = load_frag20(qpl + (size_t)(qoff + wave * 64 + (g * 2 + 0) * 16 + l16) * 20, quad);
        bf16x8 bq1 = load_frag20(qpl + (size_t)(qoff + wave * 64 + (g * 2 + 1) * 16 + l16) * 20, quad);

        f32x4 accO[2][2];
        accO[0][0] = z4; accO[0][1] = z4; accO[1][0] = z4; accO[1][1] = z4;

#pragma unroll
        for (int kt = 0; kt < NKT; ++kt) {
            B8U ak0, ak1;
            ak0.u4 = kfrag[(kt * 2 + 0) * 48];
            ak1.u4 = kfrag[(kt * 2 + 1) * 48];
            B8U av0, av1;
            {
                uint4 va = *(const uint4*)(vbase0 + kt * 32 + quad * 8);
                uint4 vb = *(const uint4*)(vbase0 + kt * 32 + quad * 8 + 4);
                av0.u[0] = __builtin_amdgcn_perm(va.y, va.x, sel);
                av0.u[1] = __builtin_amdgcn_perm(va.w, va.z, sel);
                av0.u[2] = __builtin_amdgcn_perm(vb.y, vb.x, sel);
                av0.u[3] = __builtin_amdgcn_perm(vb.w, vb.z, sel);
                uint4 vc = *(const uint4*)(vbase1 + kt * 32 + quad * 8);
                uint4 vd = *(const uint4*)(vbase1 + kt * 32 + quad * 8 + 4);
                av1.u[0] = __builtin_amdgcn_perm(vc.y, vc.x, sel);
                av1.u[1] = __builtin_amdgcn_perm(vc.w, vc.z, sel);
                av1.u[2] = __builtin_amdgcn_perm(vd.y, vd.x, sel);
                av1.u[3] = __builtin_amdgcn_perm(vd.w, vd.z, sel);
            }
#pragma unroll
            for (int t = 0; t < 2; ++t) {
                bf16x8 bqt = t ? bq1 : bq0;
                f32x4 s0 = __builtin_amdgcn_mfma_f32_16x16x32_bf16(ak0.v, bqt, z4, 0, 0, 0);
                f32x4 s1 = __builtin_amdgcn_mfma_f32_16x16x32_bf16(ak1.v, bqt, z4, 0, 0, 0);
                float p0 = __builtin_amdgcn_exp2f(s0[0]), p1 = __builtin_amdgcn_exp2f(s0[1]);
                float p2 = __builtin_amdgcn_exp2f(s0[2]), p3 = __builtin_amdgcn_exp2f(s0[3]);
                float p4 = __builtin_amdgcn_exp2f(s1[0]), p5 = __builtin_amdgcn_exp2f(s1[1]);
                float p6 = __builtin_amdgcn_exp2f(s1[2]), p7 = __builtin_amdgcn_exp2f(s1[3]);
                B8U bp;   // P^T B-frag: j=0..3 <- s0 regs, j=4..7 <- s1 regs
                bp.u[0] = packbf(p0, p1);
                bp.u[1] = packbf(p2, p3);
                bp.u[2] = packbf(p4, p5);
                bp.u[3] = packbf(p6, p7);
                accO[t][0] = __builtin_amdgcn_mfma_f32_16x16x32_bf16(av0.v, bp.v, accO[t][0], 0, 0, 0);
                accO[t][1] = __builtin_amdgcn_mfma_f32_16x16x32_bf16(av1.v, bp.v, accO[t][1], 0, 0, 0);
            }
        }

        // epilogue: O^T C-layout (col l16=query, row quad*4+r=dim);
        // l = accO[t][1][0] on quad1 (dim20 ones-column)
#pragma unroll
        for (int t = 0; t < 2; ++t) {
            int nt = g * 2 + t;
            float l = __shfl(accO[t][1][0], 16 + l16, 64);
            float inv = 1.f / l;
            int tok = (MUT ? half * 128 : 0) + wave * 64 + nt * 16 + l16;
            short* orow = xout + (size_t)(wl * 256 + tok) * 240 + (MUT ? hd * 20 : 120 + hd * 20);
            unsigned lo = packbf(accO[t][0][0] * inv, accO[t][0][1] * inv);
            unsigned hi2 = packbf(accO[t][0][2] * inv, accO[t][0][3] * inv);
            *(uint2*)(orow + quad * 4) = make_uint2(lo, hi2);
            if (quad == 0) {
                unsigned lo2 = packbf(accO[t][1][0] * inv, accO[t][1][1] * inv);
                unsigned hi3 = packbf(accO[t][1][2] * inv, accO[t][1][3] * inv);
                *(uint2*)(orow + 16) = make_uint2(lo2, hi3);
            }
        }
    }
}

extern "C" void kernel_launch(void* const* d_in, const int* in_sizes, int n_in,
                              void* d_out, int out_size, void* d_ws, size_t ws_size,
                              hipStream_t stream) {
    const float* x          = (const float*)d_in[0];
    const float* norm1_w    = (const float*)d_in[1];
    const float* norm1_b    = (const float*)d_in[2];
    const float* qkv_self_w = (const float*)d_in[3];
    const float* qkv_self_b = (const float*)d_in[4];
    const float* qkv_mut_w  = (const float*)d_in[5];
    const float* qkv_mut_b  = (const float*)d_in[6];
    const float* proj_w     = (const float*)d_in[7];
    const float* proj_b     = (const float*)d_in[8];
    const float* norm2_w    = (const float*)d_in[9];
    const float* norm2_b    = (const float*)d_in[10];
    const float* fc11_w     = (const float*)d_in[11];
    const float* fc11_b     = (const float*)d_in[12];
    const float* fc12_w     = (const float*)d_in[13];
    const float* fc12_b     = (const float*)d_in[14];
    const float* fc2_w      = (const float*)d_in[15];
    const float* fc2_b      = (const float*)d_in[16];

    if (ws_size < 110100480u) return;

    char* wsb   = (char*)d_ws;
    short* Hb    = (short*)wsb;                   // 131072x120 bf16
    short* QKVc  = (short*)(wsb + 31457280);      // 3 planes, chunk
    short* XOUTc = (short*)(wsb + 78643200);      // 65536x240 bf16
    float* TMPc  = (float*)(wsb + 31457280);      // 65536x120 fp32 (over dead QKV)
    short* H2c   = (short*)(wsb + 62914560);      // 65536x120 bf16 (over dead QKV)
    short* HIDc  = (short*)(wsb + 78643200);      // 65536x240 bf16 (over dead XOUT)
    float* out   = (float*)d_out;                 // final output only

    // 1. LN1 + window partition -> Hb (bf16)
    ln_kernel<true><<<16384, 256, 0, stream>>>(x, norm1_w, norm1_b, Hb);

    // 2. Per-chunk: attention + MLP (row-local after attn; no d_out scratch)
    for (int c = 0; c < 2; ++c) {
        int m0 = c * CHROWS;
        const short* Ac = Hb + (size_t)m0 * 120;
        mm<0, 120, 360, 8><<<dim3(256, 6), 256, 0, stream>>>(Ac, qkv_self_w, qkv_self_b,
                                                             QKVc, nullptr, 0);
        attn_flash<256, false><<<1536, 256, 0, stream>>>(QKVc, XOUTc);
        mm<0, 120, 360, 8><<<dim3(256, 6), 256, 0, stream>>>(Ac, qkv_mut_w, qkv_mut_b,
                                                             QKVc, nullptr, 0);
        attn_flash<128, true><<<3072, 128, 0, stream>>>(QKVc, XOUTc);
        mm<1, 240, 120, 8><<<dim3(256, 2), 256, 0, stream>>>(XOUTc, proj_w, proj_b,
                                                             TMPc, x, m0);
        ln_kernel<false><<<8192, 256, 0, stream>>>(TMPc, norm2_w, norm2_b, H2c);
        mm_mlp<<<dim3(256, 4), 256, 0, stream>>>(H2c, fc11_w, fc11_b,
                                                 fc12_w, fc12_b, HIDc);
        mm<4, 240, 120, 8><<<dim3(256, 2), 256, 0, stream>>>(HIDc, fc2_w, fc2_b,
                                                             out, TMPc, m0);
    }
}

// Round 7
// 573.123 us; speedup vs baseline: 1.2900x; 1.0447x over previous
//
#include <hip/hip_runtime.h>
#include <hip/hip_bf16.h>
#include <math.h>

// TMSA R13: revert MT=8 (R12 regression: VGPR 128 -> occ 18.8%, mm_mlp
// 43->46.5us), keep LN rewrite + per-chunk pipeline (R12 wins).
// New: NJ template axis - NJ=4 makes one wave cover all 4 n-tiles so each
// A-frag global load (16-line transaction) feeds 4 MFMAs instead of 2.
// Applied to mm<0> (QKV) only this round for clean counter attribution;
// mm<1>/mm<4>/mm_mlp stay at R11-proven MT=4/NJ=2 (72 VGPR, 43us).
//
// ws (bytes), guard 110,100,480. Per chunk c:
//   Hb   bf16 [0,31457280)            (both chunks, written once)
//   QKVc bf16 [31457280,78643200)     (dead after attn-mut)
//   XOUTc bf16 [78643200,110100480)   (dead after mm<1>)
//   TMPc fp32 [31457280,62914560)     (over dead QKV)
//   H2c  bf16 [62914560,78643200)     (over dead QKV)
//   HIDc bf16 [78643200,110100480)    (over dead XOUTc)

typedef __attribute__((ext_vector_type(8))) short bf16x8;
typedef __attribute__((ext_vector_type(4))) float f32x4;

#define SCALE2 (0.22360679774997896f * 1.44269504088896340f)  // d^-0.5 * log2(e)
#define CHROWS 65536
#define QPLANE 7864320u   // 65536*120 elems per q/k/v plane (chunk)

union B8U { bf16x8 v; uint4 u4; uint2 u2[2]; unsigned u[4]; short s[8]; };

__device__ __forceinline__ short bf16b(float f) {
    __hip_bfloat16 h = __float2bfloat16(f);
    return *reinterpret_cast<short*>(&h);
}
__device__ __forceinline__ float bf2f(short s) {
    return __uint_as_float(((unsigned)(unsigned short)s) << 16);
}
__device__ __forceinline__ unsigned packbf(float a, float b) {
    return (unsigned)(unsigned short)bf16b(a) |
           ((unsigned)(unsigned short)bf16b(b) << 16);
}

// LDS frag-index swizzle (R11-verified: writes 2-way free, reads contiguous)
__device__ __forceinline__ int swz(int idx) { return idx ^ ((idx >> 4) & 7); }

// partitioned row r -> global row g
__device__ __forceinline__ int rev_row(int r) {
    int w = r >> 8, t = r & 255;
    int w8 = w & 7, h8 = (w >> 3) & 7, d2 = (w >> 6) & 1, n2 = w >> 7;
    int www = t & 7, hh = (t >> 3) & 7, dd = (t >> 6) & 1, nn = t >> 7;
    int n = n2 * 2 + nn, d = d2 * 2 + dd;
    int Hc = h8 * 8 + hh, Wc = w8 * 8 + www;
    return ((n * 4 + d) << 12) + (Hc << 6) + Wc;
}
// global row g -> partitioned row
__device__ __forceinline__ int part_row(int g) {
    int ww = g & 63, hh = (g >> 6) & 63, d = (g >> 12) & 3, n = g >> 14;
    int w = ((n >> 1) * 2 + (d >> 1)) * 64 + ((hh >> 3) << 3) + (ww >> 3);
    int t = (((n & 1) * 2 + (d & 1)) << 6) + ((hh & 7) << 3) + (ww & 7);
    return (w << 8) + t;
}
__device__ __forceinline__ float gelu_exact(float x) {
    return 0.5f * x * (1.0f + erff(x * 0.70710678118654752f));
}

// load B-frag from a 20-elem bf16 row (stride 20), k = quad*8..+7, zero-padded.
__device__ __forceinline__ bf16x8 load_frag20(const short* row, int quad) {
    B8U r;
    const uint2* p = (const uint2*)(row + quad * 8);
    r.u2[0] = p[0]; r.u2[1] = p[1];
    if (quad == 2) { r.u[2] = 0; r.u[3] = 0; }
    else if (quad == 3) { r.u[0] = r.u[1] = r.u[2] = r.u[3] = 0; }
    return r.v;
}

// ---- W staging: fp32 (N x K) rows [bn,bn+64) -> bf16 frags, swizzled ------
template <int K>
__device__ __forceinline__ void stageW_frag(uint4* Wf, const float* __restrict__ W,
                                            int bn, int N, int tid) {
    constexpr int CH   = (K == 120) ? 16 : 32;    // padded chunks per row
    constexpr int NKT  = CH / 4;
    constexpr int ITER = 64 * CH / 256;
#pragma unroll
    for (int i = 0; i < ITER; ++i) {
        int c = i * 256 + tid;
        int row = c / CH, q = c % CH;
        int wr = bn + row; if (wr > N - 1) wr = N - 1;
        uint4 d = make_uint4(0u, 0u, 0u, 0u);
        if (q * 8 < K) {
            f32x4 w0 = *(const f32x4*)(W + (size_t)wr * K + q * 8);
            f32x4 w1 = *(const f32x4*)(W + (size_t)wr * K + q * 8 + 4);
            d = make_uint4(packbf(w0.x, w0.y), packbf(w0.z, w0.w),
                           packbf(w1.x, w1.y), packbf(w1.z, w1.w));
        }
        Wf[swz(((row >> 4) * NKT + (q >> 2)) * 64 + (q & 3) * 16 + (row & 15))] = d;
    }
}

// -------- LayerNorm (C=120) fp32 -> bf16, 2 rows/wave, width-32 butterfly ---
template <bool REMAP>
__global__ __launch_bounds__(256) void ln_kernel(const float* __restrict__ in,
                                                 const float* __restrict__ w,
                                                 const float* __restrict__ b,
                                                 short* __restrict__ out) {
    const int tid = threadIdx.x;
    const int lane = tid & 63, wave = tid >> 6;
    const int half = lane >> 5, hl = lane & 31;
    const int row = blockIdx.x * 8 + wave * 2 + half;
    const float* xr = in + (size_t)row * 120;
    f32x4 v = (f32x4){0.f, 0.f, 0.f, 0.f};
    if (hl < 30) v = *(const f32x4*)(xr + hl * 4);
    float s = (v.x + v.y) + (v.z + v.w);
#pragma unroll
    for (int off = 16; off; off >>= 1) s += __shfl_xor(s, off, 32);
    float mean = s * (1.f / 120.f);
    float d0 = v.x - mean, d1 = v.y - mean, d2 = v.z - mean, d3 = v.w - mean;
    float q = (hl < 30) ? (d0 * d0 + d1 * d1) + (d2 * d2 + d3 * d3) : 0.f;
#pragma unroll
    for (int off = 16; off; off >>= 1) q += __shfl_xor(q, off, 32);
    float rstd = rsqrtf(q * (1.f / 120.f) + 1e-5f);
    int orow = REMAP ? part_row(row) : row;
    if (hl < 30) {
        f32x4 wv = *(const f32x4*)(w + hl * 4);
        f32x4 bv = *(const f32x4*)(b + hl * 4);
        unsigned u0 = packbf(d0 * rstd * wv.x + bv.x, d1 * rstd * wv.y + bv.y);
        unsigned u1 = packbf(d2 * rstd * wv.z + bv.z, d3 * rstd * wv.w + bv.w);
        *(uint2*)(out + (size_t)orow * 120 + hl * 4) = make_uint2(u0, u1);
    }
}

// --- MFMA GEMM, W-in-LDS / A-direct. MT m-tiles/wave, NJ n-tiles/wave -------
// 4 waves = (4/NJ n-groups) x (NJ==2 ? 2 : 4 m-groups). Block M = waves_m*MT*16.
// MODE: 0 QKV scatter (q pre-scaled by SCALE2) | 1 proj(+x res -> TMPc local)
//       4 fc2(+TMPc res -> d_out @rev_row)
template <int MODE, int K, int N, int MT, int NJ>
__global__ __launch_bounds__(256) void mm(const short* __restrict__ A,
                                          const float* __restrict__ W,
                                          const float* __restrict__ bias,
                                          void* __restrict__ outp,
                                          const float* __restrict__ aux,
                                          int m0) {
    constexpr int NKT = (K + 31) / 32;        // 4 (K=120) or 8 (K=240)
    constexpr int WN  = 4 / NJ;               // waves along n
    constexpr int WM  = 4 / WN;               // waves along m
    __shared__ uint4 Wf[4 * NKT * 64];        // 16KB or 32KB
    const int tid = threadIdx.x;
    const int lane = tid & 63, wave = tid >> 6;
    const int quad = lane >> 4, l16 = lane & 15;
    const int wm = wave / WN, wn = wave % WN;
    const int bm  = blockIdx.x * (WM * MT * 16) + wm * (MT * 16);
    const int bnb = blockIdx.y * 64;
    const int wtile = wn * NJ;

    stageW_frag<K>(Wf, W, bnb, N, tid);

    const short* Ar[MT];
#pragma unroll
    for (int i = 0; i < MT; ++i) Ar[i] = A + (size_t)(bm + i * 16 + l16) * K;

    f32x4 acc[MT][NJ];
#pragma unroll
    for (int i = 0; i < MT; ++i)
#pragma unroll
        for (int j = 0; j < NJ; ++j) acc[i][j] = (f32x4){0.f, 0.f, 0.f, 0.f};

    __syncthreads();
#pragma unroll
    for (int kt = 0; kt < NKT; ++kt) {
        int k = kt * 32 + quad * 8;
        int kc = (k + 8 <= K) ? k : 0;        // clamp; W frag is zero there
        B8U bw[NJ];
#pragma unroll
        for (int j = 0; j < NJ; ++j)
            bw[j].u4 = Wf[swz(((wtile + j) * NKT + kt) * 64 + lane)];
#pragma unroll
        for (int i = 0; i < MT; ++i) {
            bf16x8 a = *(const bf16x8*)(Ar[i] + kc);
#pragma unroll
            for (int j = 0; j < NJ; ++j)
                acc[i][j] = __builtin_amdgcn_mfma_f32_16x16x32_bf16(a, bw[j].v, acc[i][j], 0, 0, 0);
        }
    }

#pragma unroll
    for (int j = 0; j < NJ; ++j) {
        const int n = bnb + (wtile + j) * 16 + l16;
        if (n >= N) continue;
        const float bs = bias[n];
        int which = 0, head = 0, e = 0;
        if (MODE == 0) { which = n / 120; int hn = n % 120; head = hn / 20; e = hn % 20; }
#pragma unroll
        for (int i = 0; i < MT; ++i) {
#pragma unroll
            for (int r = 0; r < 4; ++r) {
                int m = bm + i * 16 + quad * 4 + r;
                float val = acc[i][j][r] + bs;
                if (MODE == 0) {
                    if (which == 0) val *= SCALE2;
                    int wl = m >> 8, t = m & 255;
                    ((short*)outp)[(size_t)which * QPLANE +
                                   ((size_t)((wl * 6 + head) * 256 + t)) * 20 + e] = bf16b(val);
                } else if (MODE == 1) {
                    int g = rev_row(m0 + m);
                    val += aux[(size_t)g * 120 + n];
                    ((float*)outp)[(size_t)m * 120 + n] = val;   // chunk-local
                } else { // MODE 4: aux = TMPc (chunk-local); scatter to d_out
                    int g = rev_row(m0 + m);
                    val += aux[(size_t)m * 120 + n];
                    ((float*)outp)[(size_t)g * 120 + n] = val;
                }
            }
        }
    }
}

// ---- fused MLP up-projection: HID = gelu(A@W1^T+b1) * (A@W2^T+b2) ----------
// R11-proven config: MT=4, NJ=2, both W's resident (2x16KB swizzled frags).
__global__ __launch_bounds__(256) void mm_mlp(const short* __restrict__ A,
                                              const float* __restrict__ W1,
                                              const float* __restrict__ b1,
                                              const float* __restrict__ W2,
                                              const float* __restrict__ b2,
                                              short* __restrict__ outp) {
    __shared__ uint4 Wf[2][4 * 4 * 64];
    const int tid = threadIdx.x;
    const int lane = tid & 63, wave = tid >> 6;
    const int quad = lane >> 4, l16 = lane & 15;
    const int bm  = blockIdx.x * 128 + (wave >> 1) * 64;
    const int bnb = blockIdx.y * 64;
    const int wtile = (wave & 1) * 2;
    const int N = 240;

    stageW_frag<120>(Wf[0], W1, bnb, N, tid);
    stageW_frag<120>(Wf[1], W2, bnb, N, tid);

    const short* Ar[4];
#pragma unroll
    for (int i = 0; i < 4; ++i) Ar[i] = A + (size_t)(bm + i * 16 + l16) * 120;

    f32x4 acc1[4][2], acc2[4][2];
#pragma unroll
    for (int i = 0; i < 4; ++i)
#pragma unroll
        for (int j = 0; j < 2; ++j) {
            acc1[i][j] = (f32x4){0.f, 0.f, 0.f, 0.f};
            acc2[i][j] = (f32x4){0.f, 0.f, 0.f, 0.f};
        }

    __syncthreads();
#pragma unroll
    for (int kt = 0; kt < 4; ++kt) {
        int k = kt * 32 + quad * 8;
        int kc = (k + 8 <= 120) ? k : 0;
        B8U p0, p1, q0, q1;
        p0.u4 = Wf[0][swz(((wtile + 0) * 4 + kt) * 64 + lane)];
        p1.u4 = Wf[0][swz(((wtile + 1) * 4 + kt) * 64 + lane)];
        q0.u4 = Wf[1][swz(((wtile + 0) * 4 + kt) * 64 + lane)];
        q1.u4 = Wf[1][swz(((wtile + 1) * 4 + kt) * 64 + lane)];
#pragma unroll
        for (int i = 0; i < 4; ++i) {
            bf16x8 a = *(const bf16x8*)(Ar[i] + kc);
            acc1[i][0] = __builtin_amdgcn_mfma_f32_16x16x32_bf16(a, p0.v, acc1[i][0], 0, 0, 0);
            acc1[i][1] = __builtin_amdgcn_mfma_f32_16x16x32_bf16(a, p1.v, acc1[i][1], 0, 0, 0);
            acc2[i][0] = __builtin_amdgcn_mfma_f32_16x16x32_bf16(a, q0.v, acc2[i][0], 0, 0, 0);
            acc2[i][1] = __builtin_amdgcn_mfma_f32_16x16x32_bf16(a, q1.v, acc2[i][1], 0, 0, 0);
        }
    }

#pragma unroll
    for (int j = 0; j < 2; ++j) {
        const int n = bnb + wtile * 16 + j * 16 + l16;
        if (n >= N) continue;
        const float g1 = b1[n], g2 = b2[n];
#pragma unroll
        for (int i = 0; i < 4; ++i) {
#pragma unroll
            for (int r = 0; r < 4; ++r) {
                int m = bm + i * 16 + quad * 4 + r;
                float gv = acc1[i][j][r] + g1;
                float vv = acc2[i][j][r] + g2;
                outp[(size_t)m * 240 + n] = bf16b(gelu_exact(gv) * vv);
            }
        }
    }
}

// ---------------- MFMA flash attention, LDS-fed, zero-shuffle ----------------
template <int NK, bool MUT>
__global__ __launch_bounds__(NK) void attn_flash(const short* __restrict__ qkv,
                                                 short* __restrict__ xout) {
    constexpr int NKT = NK / 32;
    constexpr int VSTR2 = NK + 4;                  // u32 stride (16B-aligned rows)
    __shared__ __align__(16) short Kf[NKT * 2 * 48 * 8];
    __shared__ __align__(16) unsigned Vt2[11 * VSTR2];
    const int b = blockIdx.x;
    int wl, hd, half;
    if (MUT) { half = b & 1; hd = (b >> 1) % 6; wl = b / 12; }
    else     { half = 0;     hd = b % 6;        wl = b / 6;  }
    const int tid  = threadIdx.x;
    const int lane = tid & 63, wave = tid >> 6;
    const int quad = lane >> 4, l16 = lane & 15;

    const size_t rb = (size_t)(wl * 6 + hd) * 256;
    const short* qpl = qkv + rb * 20;
    const short* kpl = qkv + (size_t)QPLANE + rb * 20;
    const short* vpl = qkv + 2 * (size_t)QPLANE + rb * 20;
    const int koff = MUT ? half * 128 : 0;
    const int qoff = MUT ? (1 - half) * 128 : 0;

    // ---- stage V^T (u32 dim-pairs; row10 = ones at dim20) and K (frag order) ----
    {
        const uint2* p = (const uint2*)(vpl + (size_t)(koff + tid) * 20);
        unsigned tmp[10];
#pragma unroll
        for (int i = 0; i < 5; ++i) ((uint2*)tmp)[i] = p[i];
#pragma unroll
        for (int i = 0; i < 10; ++i) Vt2[i * VSTR2 + tid] = tmp[i];
        Vt2[10 * VSTR2 + tid] = 0x00003F80u;   // dim20 = bf16(1.0), dim21 = 0

        int skt = tid >> 5, sf = (tid >> 4) & 1, sl = tid & 15;
        int srow = koff + skt * 32 + sf * 4 + ((sl >> 2) << 3) + (sl & 3);
        const uint2* kp = (const uint2*)(kpl + (size_t)srow * 20);
        uint2 k0 = kp[0], k1 = kp[1], k2 = kp[2], k3 = kp[3], k4 = kp[4];
        uint4* dst = (uint4*)Kf + ((skt * 2 + sf) * 48 + sl);
        dst[0]  = make_uint4(k0.x, k0.y, k1.x, k1.y);   // quad0: d0-7
        dst[16] = make_uint4(k2.x, k2.y, k3.x, k3.y);   // quad1: d8-15
        dst[32] = make_uint4(k4.x, k4.y, 0u, 0u);       // quad2: d16-23
    }
    __syncthreads();

    const int quadc = quad < 3 ? quad : 2;             // quad3 aliases quad2 (x0)
    const uint4* kfrag = (const uint4*)Kf + quadc * 16 + l16;
    const unsigned sel = (l16 & 1) ? 0x07060302u : 0x05040100u;
    const unsigned* vbase0 = Vt2 + (l16 >> 1) * VSTR2;
    int r1 = 8 + (l16 >> 1); if (r1 > 10) r1 = 10;     // rows>=11 feed unused dims
    const unsigned* vbase1 = Vt2 + r1 * VSTR2;
    const f32x4 z4 = {0.f, 0.f, 0.f, 0.f};

#pragma unroll 1
    for (int g = 0; g < 2; ++g) {
        bf16x8 bq0 = load_frag20(qpl + (size_t)(qoff + wave * 64 + (g * 2 + 0) * 16 + l16) * 20, quad);
        bf16x8 bq1 = load_frag20(qpl + (size_t)(qoff + wave * 64 + (g * 2 + 1) * 16 + l16) * 20, quad);

        f32x4 accO[2][2];
        accO[0][0] = z4; accO[0][1] = z4; accO[1][0] = z4; accO[1][1] = z4;

#pragma unroll
        for (int kt = 0; kt < NKT; ++kt) {
            B8U ak0, ak1;
            ak0.u4 = kfrag[(kt * 2 + 0) * 48];
            ak1.u4 = kfrag[(kt * 2 + 1) * 48];
            B8U av0, av1;
            {
                uint4 va = *(const uint4*)(vbase0 + kt * 32 + quad * 8);
                uint4 vb = *(const uint4*)(vbase0 + kt * 32 + quad * 8 + 4);
                av0.u[0] = __builtin_amdgcn_perm(va.y, va.x, sel);
                av0.u[1] = __builtin_amdgcn_perm(va.w, va.z, sel);
                av0.u[2] = __builtin_amdgcn_perm(vb.y, vb.x, sel);
                av0.u[3] = __builtin_amdgcn_perm(vb.w, vb.z, sel);
                uint4 vc = *(const uint4*)(vbase1 + kt * 32 + quad * 8);
                uint4 vd = *(const uint4*)(vbase1 + kt * 32 + quad * 8 + 4);
                av1.u[0] = __builtin_amdgcn_perm(vc.y, vc.x, sel);
                av1.u[1] = __builtin_amdgcn_perm(vc.w, vc.z, sel);
                av1.u[2] = __builtin_amdgcn_perm(vd.y, vd.x, sel);
                av1.u[3] = __builtin_amdgcn_perm(vd.w, vd.z, sel);
            }
#pragma unroll
            for (int t = 0; t < 2; ++t) {
                bf16x8 bqt = t ? bq1 : bq0;
                f32x4 s0 = __builtin_amdgcn_mfma_f32_16x16x32_bf16(ak0.v, bqt, z4, 0, 0, 0);
                f32x4 s1 = __builtin_amdgcn_mfma_f32_16x16x32_bf16(ak1.v, bqt, z4, 0, 0, 0);
                float p0 = __builtin_amdgcn_exp2f(s0[0]), p1 = __builtin_amdgcn_exp2f(s0[1]);
                float p2 = __builtin_amdgcn_exp2f(s0[2]), p3 = __builtin_amdgcn_exp2f(s0[3]);
                float p4 = __builtin_amdgcn_exp2f(s1[0]), p5 = __builtin_amdgcn_exp2f(s1[1]);
                float p6 = __builtin_amdgcn_exp2f(s1[2]), p7 = __builtin_amdgcn_exp2f(s1[3]);
                B8U bp;   // P^T B-frag: j=0..3 <- s0 regs, j=4..7 <- s1 regs
                bp.u[0] = packbf(p0, p1);
                bp.u[1] = packbf(p2, p3);
                bp.u[2] = packbf(p4, p5);
                bp.u[3] = packbf(p6, p7);
                accO[t][0] = __builtin_amdgcn_mfma_f32_16x16x32_bf16(av0.v, bp.v, accO[t][0], 0, 0, 0);
                accO[t][1] = __builtin_amdgcn_mfma_f32_16x16x32_bf16(av1.v, bp.v, accO[t][1], 0, 0, 0);
            }
        }

        // epilogue: O^T C-layout (col l16=query, row quad*4+r=dim);
        // l = accO[t][1][0] on quad1 (dim20 ones-column)
#pragma unroll
        for (int t = 0; t < 2; ++t) {
            int nt = g * 2 + t;
            float l = __shfl(accO[t][1][0], 16 + l16, 64);
            float inv = 1.f / l;
            int tok = (MUT ? half * 128 : 0) + wave * 64 + nt * 16 + l16;
            short* orow = xout + (size_t)(wl * 256 + tok) * 240 + (MUT ? hd * 20 : 120 + hd * 20);
            unsigned lo = packbf(accO[t][0][0] * inv, accO[t][0][1] * inv);
            unsigned hi2 = packbf(accO[t][0][2] * inv, accO[t][0][3] * inv);
            *(uint2*)(orow + quad * 4) = make_uint2(lo, hi2);
            if (quad == 0) {
                unsigned lo2 = packbf(accO[t][1][0] * inv, accO[t][1][1] * inv);
                unsigned hi3 = packbf(accO[t][1][2] * inv, accO[t][1][3] * inv);
                *(uint2*)(orow + 16) = make_uint2(lo2, hi3);
            }
        }
    }
}

extern "C" void kernel_launch(void* const* d_in, const int* in_sizes, int n_in,
                              void* d_out, int out_size, void* d_ws, size_t ws_size,
                              hipStream_t stream) {
    const float* x          = (const float*)d_in[0];
    const float* norm1_w    = (const float*)d_in[1];
    const float* norm1_b    = (const float*)d_in[2];
    const float* qkv_self_w = (const float*)d_in[3];
    const float* qkv_self_b = (const float*)d_in[4];
    const float* qkv_mut_w  = (const float*)d_in[5];
    const float* qkv_mut_b  = (const float*)d_in[6];
    const float* proj_w     = (const float*)d_in[7];
    const float* proj_b     = (const float*)d_in[8];
    const float* norm2_w    = (const float*)d_in[9];
    const float* norm2_b    = (const float*)d_in[10];
    const float* fc11_w     = (const float*)d_in[11];
    const float* fc11_b     = (const float*)d_in[12];
    const float* fc12_w     = (const float*)d_in[13];
    const float* fc12_b     = (const float*)d_in[14];
    const float* fc2_w      = (const float*)d_in[15];
    const float* fc2_b      = (const float*)d_in[16];

    if (ws_size < 110100480u) return;

    char* wsb   = (char*)d_ws;
    short* Hb    = (short*)wsb;                   // 131072x120 bf16
    short* QKVc  = (short*)(wsb + 31457280);      // 3 planes, chunk
    short* XOUTc = (short*)(wsb + 78643200);      // 65536x240 bf16
    float* TMPc  = (float*)(wsb + 31457280);      // 65536x120 fp32 (over dead QKV)
    short* H2c   = (short*)(wsb + 62914560);      // 65536x120 bf16 (over dead QKV)
    short* HIDc  = (short*)(wsb + 78643200);      // 65536x240 bf16 (over dead XOUT)
    float* out   = (float*)d_out;                 // final output only

    // 1. LN1 + window partition -> Hb (bf16)
    ln_kernel<true><<<16384, 256, 0, stream>>>(x, norm1_w, norm1_b, Hb);

    // 2. Per-chunk: attention + MLP (row-local after attn; no d_out scratch)
    for (int c = 0; c < 2; ++c) {
        int m0 = c * CHROWS;
        const short* Ac = Hb + (size_t)m0 * 120;
        mm<0, 120, 360, 4, 4><<<dim3(256, 6), 256, 0, stream>>>(Ac, qkv_self_w, qkv_self_b,
                                                                QKVc, nullptr, 0);
        attn_flash<256, false><<<1536, 256, 0, stream>>>(QKVc, XOUTc);
        mm<0, 120, 360, 4, 4><<<dim3(256, 6), 256, 0, stream>>>(Ac, qkv_mut_w, qkv_mut_b,
                                                                QKVc, nullptr, 0);
        attn_flash<128, true><<<3072, 128, 0, stream>>>(QKVc, XOUTc);
        mm<1, 240, 120, 4, 2><<<dim3(512, 2), 256, 0, stream>>>(XOUTc, proj_w, proj_b,
                                                                TMPc, x, m0);
        ln_kernel<false><<<8192, 256, 0, stream>>>(TMPc, norm2_w, norm2_b, H2c);
        mm_mlp<<<dim3(512, 4), 256, 0, stream>>>(H2c, fc11_w, fc11_b,
                                                 fc12_w, fc12_b, HIDc);
        mm<4, 240, 120, 4, 2><<<dim3(512, 2), 256, 0, stream>>>(HIDc, fc2_w, fc2_b,
                                                                out, TMPc, m0);
    }
}

// Round 8
// 572.015 us; speedup vs baseline: 1.2925x; 1.0019x over previous
//
#include <hip/hip_runtime.h>
#include <hip/hip_bf16.h>
#include <math.h>

// TMSA R14: kill MLP scatter/gather transactions.
// R13 post-mortem: NJ=4 confirmed on mm<0> (one A-load feeds 4 MFMAs). mm_mlp
// still #1 at 43us: 32x 2B scattered stores (~512 write lines/wave) + 16
// 16-line A-loads + erff VALU. R14:
//  - mm_mlp: MT=2/NJ=4 (A-loads halve, acc stays 64 regs; W frags consumed
//    one-at-a-time to keep live regs ~90), epilogue via LDS transpose
//    (S[128][80] bf16 over dead Wf; quad-rows hit disjoint bank sets) then
//    coalesced uint4 copy-out.
//  - mm<1>/mm<4>: NJ=4 rollout (block 256x64, grid (256,2)).
// ln/attn/pipeline unchanged (R12/R13-verified).
//
// ws (bytes), guard 110,100,480. Per chunk c:
//   Hb   bf16 [0,31457280)            (both chunks, written once)
//   QKVc bf16 [31457280,78643200)     (dead after attn-mut)
//   XOUTc bf16 [78643200,110100480)   (dead after mm<1>)
//   TMPc fp32 [31457280,62914560)     (over dead QKV)
//   H2c  bf16 [62914560,78643200)     (over dead QKV)
//   HIDc bf16 [78643200,110100480)    (over dead XOUTc)

typedef __attribute__((ext_vector_type(8))) short bf16x8;
typedef __attribute__((ext_vector_type(4))) float f32x4;

#define SCALE2 (0.22360679774997896f * 1.44269504088896340f)  // d^-0.5 * log2(e)
#define CHROWS 65536
#define QPLANE 7864320u   // 65536*120 elems per q/k/v plane (chunk)

union B8U { bf16x8 v; uint4 u4; uint2 u2[2]; unsigned u[4]; short s[8]; };

__device__ __forceinline__ short bf16b(float f) {
    __hip_bfloat16 h = __float2bfloat16(f);
    return *reinterpret_cast<short*>(&h);
}
__device__ __forceinline__ float bf2f(short s) {
    return __uint_as_float(((unsigned)(unsigned short)s) << 16);
}
__device__ __forceinline__ unsigned packbf(float a, float b) {
    return (unsigned)(unsigned short)bf16b(a) |
           ((unsigned)(unsigned short)bf16b(b) << 16);
}

// LDS frag-index swizzle (R11-verified: writes 2-way free, reads contiguous)
__device__ __forceinline__ int swz(int idx) { return idx ^ ((idx >> 4) & 7); }

// partitioned row r -> global row g
__device__ __forceinline__ int rev_row(int r) {
    int w = r >> 8, t = r & 255;
    int w8 = w & 7, h8 = (w >> 3) & 7, d2 = (w >> 6) & 1, n2 = w >> 7;
    int www = t & 7, hh = (t >> 3) & 7, dd = (t >> 6) & 1, nn = t >> 7;
    int n = n2 * 2 + nn, d = d2 * 2 + dd;
    int Hc = h8 * 8 + hh, Wc = w8 * 8 + www;
    return ((n * 4 + d) << 12) + (Hc << 6) + Wc;
}
// global row g -> partitioned row
__device__ __forceinline__ int part_row(int g) {
    int ww = g & 63, hh = (g >> 6) & 63, d = (g >> 12) & 3, n = g >> 14;
    int w = ((n >> 1) * 2 + (d >> 1)) * 64 + ((hh >> 3) << 3) + (ww >> 3);
    int t = (((n & 1) * 2 + (d & 1)) << 6) + ((hh & 7) << 3) + (ww & 7);
    return (w << 8) + t;
}
__device__ __forceinline__ float gelu_exact(float x) {
    return 0.5f * x * (1.0f + erff(x * 0.70710678118654752f));
}

// load B-frag from a 20-elem bf16 row (stride 20), k = quad*8..+7, zero-padded.
__device__ __forceinline__ bf16x8 load_frag20(const short* row, int quad) {
    B8U r;
    const uint2* p = (const uint2*)(row + quad * 8);
    r.u2[0] = p[0]; r.u2[1] = p[1];
    if (quad == 2) { r.u[2] = 0; r.u[3] = 0; }
    else if (quad == 3) { r.u[0] = r.u[1] = r.u[2] = r.u[3] = 0; }
    return r.v;
}

// ---- W staging: fp32 (N x K) rows [bn,bn+64) -> bf16 frags, swizzled ------
template <int K>
__device__ __forceinline__ void stageW_frag(uint4* Wf, const float* __restrict__ W,
                                            int bn, int N, int tid) {
    constexpr int CH   = (K == 120) ? 16 : 32;    // padded chunks per row
    constexpr int NKT  = CH / 4;
    constexpr int ITER = 64 * CH / 256;
#pragma unroll
    for (int i = 0; i < ITER; ++i) {
        int c = i * 256 + tid;
        int row = c / CH, q = c % CH;
        int wr = bn + row; if (wr > N - 1) wr = N - 1;
        uint4 d = make_uint4(0u, 0u, 0u, 0u);
        if (q * 8 < K) {
            f32x4 w0 = *(const f32x4*)(W + (size_t)wr * K + q * 8);
            f32x4 w1 = *(const f32x4*)(W + (size_t)wr * K + q * 8 + 4);
            d = make_uint4(packbf(w0.x, w0.y), packbf(w0.z, w0.w),
                           packbf(w1.x, w1.y), packbf(w1.z, w1.w));
        }
        Wf[swz(((row >> 4) * NKT + (q >> 2)) * 64 + (q & 3) * 16 + (row & 15))] = d;
    }
}

// -------- LayerNorm (C=120) fp32 -> bf16, 2 rows/wave, width-32 butterfly ---
template <bool REMAP>
__global__ __launch_bounds__(256) void ln_kernel(const float* __restrict__ in,
                                                 const float* __restrict__ w,
                                                 const float* __restrict__ b,
                                                 short* __restrict__ out) {
    const int tid = threadIdx.x;
    const int lane = tid & 63, wave = tid >> 6;
    const int half = lane >> 5, hl = lane & 31;
    const int row = blockIdx.x * 8 + wave * 2 + half;
    const float* xr = in + (size_t)row * 120;
    f32x4 v = (f32x4){0.f, 0.f, 0.f, 0.f};
    if (hl < 30) v = *(const f32x4*)(xr + hl * 4);
    float s = (v.x + v.y) + (v.z + v.w);
#pragma unroll
    for (int off = 16; off; off >>= 1) s += __shfl_xor(s, off, 32);
    float mean = s * (1.f / 120.f);
    float d0 = v.x - mean, d1 = v.y - mean, d2 = v.z - mean, d3 = v.w - mean;
    float q = (hl < 30) ? (d0 * d0 + d1 * d1) + (d2 * d2 + d3 * d3) : 0.f;
#pragma unroll
    for (int off = 16; off; off >>= 1) q += __shfl_xor(q, off, 32);
    float rstd = rsqrtf(q * (1.f / 120.f) + 1e-5f);
    int orow = REMAP ? part_row(row) : row;
    if (hl < 30) {
        f32x4 wv = *(const f32x4*)(w + hl * 4);
        f32x4 bv = *(const f32x4*)(b + hl * 4);
        unsigned u0 = packbf(d0 * rstd * wv.x + bv.x, d1 * rstd * wv.y + bv.y);
        unsigned u1 = packbf(d2 * rstd * wv.z + bv.z, d3 * rstd * wv.w + bv.w);
        *(uint2*)(out + (size_t)orow * 120 + hl * 4) = make_uint2(u0, u1);
    }
}

// --- MFMA GEMM, W-in-LDS / A-direct. MT m-tiles/wave, NJ n-tiles/wave -------
// 4 waves = (4/NJ n-groups) x (NJ==2 ? 2 : 4 m-groups). Block M = waves_m*MT*16.
// MODE: 0 QKV scatter (q pre-scaled by SCALE2) | 1 proj(+x res -> TMPc local)
//       4 fc2(+TMPc res -> d_out @rev_row)
template <int MODE, int K, int N, int MT, int NJ>
__global__ __launch_bounds__(256) void mm(const short* __restrict__ A,
                                          const float* __restrict__ W,
                                          const float* __restrict__ bias,
                                          void* __restrict__ outp,
                                          const float* __restrict__ aux,
                                          int m0) {
    constexpr int NKT = (K + 31) / 32;        // 4 (K=120) or 8 (K=240)
    constexpr int WN  = 4 / NJ;               // waves along n
    constexpr int WM  = 4 / WN;               // waves along m
    __shared__ uint4 Wf[4 * NKT * 64];        // 16KB or 32KB
    const int tid = threadIdx.x;
    const int lane = tid & 63, wave = tid >> 6;
    const int quad = lane >> 4, l16 = lane & 15;
    const int wm = wave / WN, wn = wave % WN;
    const int bm  = blockIdx.x * (WM * MT * 16) + wm * (MT * 16);
    const int bnb = blockIdx.y * 64;
    const int wtile = wn * NJ;

    stageW_frag<K>(Wf, W, bnb, N, tid);

    const short* Ar[MT];
#pragma unroll
    for (int i = 0; i < MT; ++i) Ar[i] = A + (size_t)(bm + i * 16 + l16) * K;

    f32x4 acc[MT][NJ];
#pragma unroll
    for (int i = 0; i < MT; ++i)
#pragma unroll
        for (int j = 0; j < NJ; ++j) acc[i][j] = (f32x4){0.f, 0.f, 0.f, 0.f};

    __syncthreads();
#pragma unroll
    for (int kt = 0; kt < NKT; ++kt) {
        int k = kt * 32 + quad * 8;
        int kc = (k + 8 <= K) ? k : 0;        // clamp; W frag is zero there
        B8U bw[NJ];
#pragma unroll
        for (int j = 0; j < NJ; ++j)
            bw[j].u4 = Wf[swz(((wtile + j) * NKT + kt) * 64 + lane)];
#pragma unroll
        for (int i = 0; i < MT; ++i) {
            bf16x8 a = *(const bf16x8*)(Ar[i] + kc);
#pragma unroll
            for (int j = 0; j < NJ; ++j)
                acc[i][j] = __builtin_amdgcn_mfma_f32_16x16x32_bf16(a, bw[j].v, acc[i][j], 0, 0, 0);
        }
    }

#pragma unroll
    for (int j = 0; j < NJ; ++j) {
        const int n = bnb + (wtile + j) * 16 + l16;
        if (n >= N) continue;
        const float bs = bias[n];
        int which = 0, head = 0, e = 0;
        if (MODE == 0) { which = n / 120; int hn = n % 120; head = hn / 20; e = hn % 20; }
#pragma unroll
        for (int i = 0; i < MT; ++i) {
#pragma unroll
            for (int r = 0; r < 4; ++r) {
                int m = bm + i * 16 + quad * 4 + r;
                float val = acc[i][j][r] + bs;
                if (MODE == 0) {
                    if (which == 0) val *= SCALE2;
                    int wl = m >> 8, t = m & 255;
                    ((short*)outp)[(size_t)which * QPLANE +
                                   ((size_t)((wl * 6 + head) * 256 + t)) * 20 + e] = bf16b(val);
                } else if (MODE == 1) {
                    int g = rev_row(m0 + m);
                    val += aux[(size_t)g * 120 + n];
                    ((float*)outp)[(size_t)m * 120 + n] = val;   // chunk-local
                } else { // MODE 4: aux = TMPc (chunk-local); scatter to d_out
                    int g = rev_row(m0 + m);
                    val += aux[(size_t)m * 120 + n];
                    ((float*)outp)[(size_t)g * 120 + n] = val;
                }
            }
        }
    }
}

// ---- fused MLP up-projection: HID = gelu(A@W1^T+b1) * (A@W2^T+b2) ----------
// MT=2/NJ=4: 8 A-loads feed 64 MFMAs/wave; acc 64 regs; W frags consumed
// one-at-a-time. Epilogue: LDS transpose (S[128][80] bf16 over dead Wf) ->
// coalesced uint4 copy-out.
__global__ __launch_bounds__(256) void mm_mlp(const short* __restrict__ A,
                                              const float* __restrict__ W1,
                                              const float* __restrict__ b1,
                                              const float* __restrict__ W2,
                                              const float* __restrict__ b2,
                                              short* __restrict__ outp) {
    __shared__ uint4 Wf[2][1024];   // 32KB; epilogue aliases as S[128][80] bf16
    const int tid = threadIdx.x;
    const int lane = tid & 63, wave = tid >> 6;
    const int quad = lane >> 4, l16 = lane & 15;
    const int bm0 = blockIdx.x * 128;
    const int bnb = blockIdx.y * 64;
    const int N = 240;

    stageW_frag<120>(Wf[0], W1, bnb, N, tid);
    stageW_frag<120>(Wf[1], W2, bnb, N, tid);

    const short* Ar[2];
#pragma unroll
    for (int i = 0; i < 2; ++i)
        Ar[i] = A + (size_t)(bm0 + wave * 32 + i * 16 + l16) * 120;

    f32x4 acc1[2][4], acc2[2][4];
#pragma unroll
    for (int i = 0; i < 2; ++i)
#pragma unroll
        for (int j = 0; j < 4; ++j) {
            acc1[i][j] = (f32x4){0.f, 0.f, 0.f, 0.f};
            acc2[i][j] = (f32x4){0.f, 0.f, 0.f, 0.f};
        }

    __syncthreads();
#pragma unroll
    for (int kt = 0; kt < 4; ++kt) {
        int k = kt * 32 + quad * 8;
        int kc = (k + 8 <= 120) ? k : 0;
        bf16x8 a0 = *(const bf16x8*)(Ar[0] + kc);
        bf16x8 a1 = *(const bf16x8*)(Ar[1] + kc);
#pragma unroll
        for (int j = 0; j < 4; ++j) {
            B8U w1f; w1f.u4 = Wf[0][swz((j * 4 + kt) * 64 + lane)];
            acc1[0][j] = __builtin_amdgcn_mfma_f32_16x16x32_bf16(a0, w1f.v, acc1[0][j], 0, 0, 0);
            acc1[1][j] = __builtin_amdgcn_mfma_f32_16x16x32_bf16(a1, w1f.v, acc1[1][j], 0, 0, 0);
            B8U w2f; w2f.u4 = Wf[1][swz((j * 4 + kt) * 64 + lane)];
            acc2[0][j] = __builtin_amdgcn_mfma_f32_16x16x32_bf16(a0, w2f.v, acc2[0][j], 0, 0, 0);
            acc2[1][j] = __builtin_amdgcn_mfma_f32_16x16x32_bf16(a1, w2f.v, acc2[1][j], 0, 0, 0);
        }
    }

    // epilogue: gelu*v -> LDS tile (stride 80 shorts: quad-rows on disjoint
    // bank sets) -> coalesced uint4 copy-out
    __syncthreads();                     // all waves done reading Wf
    short* S = (short*)&Wf[0][0];        // [128][80]
#pragma unroll
    for (int j = 0; j < 4; ++j) {
        int n = bnb + j * 16 + l16;
        int ncl = n < N ? n : N - 1;
        float g1 = b1[ncl], g2 = b2[ncl];
#pragma unroll
        for (int i = 0; i < 2; ++i) {
#pragma unroll
            for (int r = 0; r < 4; ++r) {
                int lm = wave * 32 + i * 16 + quad * 4 + r;
                float gv = acc1[i][j][r] + g1;
                float vv = acc2[i][j][r] + g2;
                S[lm * 80 + j * 16 + l16] = bf16b(gelu_exact(gv) * vv);
            }
        }
    }
    __syncthreads();
    const int row = tid >> 2, sl = tid & 3;
#pragma unroll
    for (int s2 = 0; s2 < 2; ++s2) {
        int col = (sl + s2 * 4) * 8;
        if (bnb + col < N) {
            uint4 v = *(const uint4*)(S + row * 80 + col);
            *(uint4*)(outp + (size_t)(bm0 + row) * 240 + bnb + col) = v;
        }
    }
}

// ---------------- MFMA flash attention, LDS-fed, zero-shuffle ----------------
template <int NK, bool MUT>
__global__ __launch_bounds__(NK) void attn_flash(const short* __restrict__ qkv,
                                                 short* __restrict__ xout) {
    constexpr int NKT = NK / 32;
    constexpr int VSTR2 = NK + 4;                  // u32 stride (16B-aligned rows)
    __shared__ __align__(16) short Kf[NKT * 2 * 48 * 8];
    __shared__ __align__(16) unsigned Vt2[11 * VSTR2];
    const int b = blockIdx.x;
    int wl, hd, half;
    if (MUT) { half = b & 1; hd = (b >> 1) % 6; wl = b / 12; }
    else     { half = 0;     hd = b % 6;        wl = b / 6;  }
    const int tid  = threadIdx.x;
    const int lane = tid & 63, wave = tid >> 6;
    const int quad = lane >> 4, l16 = lane & 15;

    const size_t rb = (size_t)(wl * 6 + hd) * 256;
    const short* qpl = qkv + rb * 20;
    const short* kpl = qkv + (size_t)QPLANE + rb * 20;
    const short* vpl = qkv + 2 * (size_t)QPLANE + rb * 20;
    const int koff = MUT ? half * 128 : 0;
    const int qoff = MUT ? (1 - half) * 128 : 0;

    // ---- stage V^T (u32 dim-pairs; row10 = ones at dim20) and K (frag order) ----
    {
        const uint2* p = (const uint2*)(vpl + (size_t)(koff + tid) * 20);
        unsigned tmp[10];
#pragma unroll
        for (int i = 0; i < 5; ++i) ((uint2*)tmp)[i] = p[i];
#pragma unroll
        for (int i = 0; i < 10; ++i) Vt2[i * VSTR2 + tid] = tmp[i];
        Vt2[10 * VSTR2 + tid] = 0x00003F80u;   // dim20 = bf16(1.0), dim21 = 0

        int skt = tid >> 5, sf = (tid >> 4) & 1, sl = tid & 15;
        int srow = koff + skt * 32 + sf * 4 + ((sl >> 2) << 3) + (sl & 3);
        const uint2* kp = (const uint2*)(kpl + (size_t)srow * 20);
        uint2 k0 = kp[0], k1 = kp[1], k2 = kp[2], k3 = kp[3], k4 = kp[4];
        uint4* dst = (uint4*)Kf + ((skt * 2 + sf) * 48 + sl);
        dst[0]  = make_uint4(k0.x, k0.y, k1.x, k1.y);   // quad0: d0-7
        dst[16] = make_uint4(k2.x, k2.y, k3.x, k3.y);   // quad1: d8-15
        dst[32] = make_uint4(k4.x, k4.y, 0u, 0u);       // quad2: d16-23
    }
    __syncthreads();

    const int quadc = quad < 3 ? quad : 2;             // quad3 aliases quad2 (x0)
    const uint4* kfrag = (const uint4*)Kf + quadc * 16 + l16;
    const unsigned sel = (l16 & 1) ? 0x07060302u : 0x05040100u;
    const unsigned* vbase0 = Vt2 + (l16 >> 1) * VSTR2;
    int r1 = 8 + (l16 >> 1); if (r1 > 10) r1 = 10;     // rows>=11 feed unused dims
    const unsigned* vbase1 = Vt2 + r1 * VSTR2;
    const f32x4 z4 = {0.f, 0.f, 0.f, 0.f};

#pragma unroll 1
    for (int g = 0; g < 2; ++g) {
        bf16x8 bq0 = load_frag20(qpl + (size_t)(qoff + wave * 64 + (g * 2 + 0) * 16 + l16) * 20, quad);
        bf16x8 bq1 = load_frag20(qpl + (size_t)(qoff + wave * 64 + (g * 2 + 1) * 16 + l16) * 20, quad);

        f32x4 accO[2][2];
        accO[0][0] = z4; accO[0][1] = z4; accO[1][0] = z4; accO[1][1] = z4;

#pragma unroll
        for (int kt = 0; kt < NKT; ++kt) {
            B8U ak0, ak1;
            ak0.u4 = kfrag[(kt * 2 + 0) * 48];
            ak1.u4 = kfrag[(kt * 2 + 1) * 48];
            B8U av0, av1;
            {
                uint4 va = *(const uint4*)(vbase0 + kt * 32 + quad * 8);
                uint4 vb = *(const uint4*)(vbase0 + kt * 32 + quad * 8 + 4);
                av0.u[0] = __builtin_amdgcn_perm(va.y, va.x, sel);
                av0.u[1] = __builtin_amdgcn_perm(va.w, va.z, sel);
                av0.u[2] = __builtin_amdgcn_perm(vb.y, vb.x, sel);
                av0.u[3] = __builtin_amdgcn_perm(vb.w, vb.z, sel);
                uint4 vc = *(const uint4*)(vbase1 + kt * 32 + quad * 8);
                uint4 vd = *(const uint4*)(vbase1 + kt * 32 + quad * 8 + 4);
                av1.u[0] = __builtin_amdgcn_perm(vc.y, vc.x, sel);
                av1.u[1] = __builtin_amdgcn_perm(vc.w, vc.z, sel);
                av1.u[2] = __builtin_amdgcn_perm(vd.y, vd.x, sel);
                av1.u[3] = __builtin_amdgcn_perm(vd.w, vd.z, sel);
            }
#pragma unroll
            for (int t = 0; t < 2; ++t) {
                bf16x8 bqt = t ? bq1 : bq0;
                f32x4 s0 = __builtin_amdgcn_mfma_f32_16x16x32_bf16(ak0.v, bqt, z4, 0, 0, 0);
                f32x4 s1 = __builtin_amdgcn_mfma_f32_16x16x32_bf16(ak1.v, bqt, z4, 0, 0, 0);
                float p0 = __builtin_amdgcn_exp2f(s0[0]), p1 = __builtin_amdgcn_exp2f(s0[1]);
                float p2 = __builtin_amdgcn_exp2f(s0[2]), p3 = __builtin_amdgcn_exp2f(s0[3]);
                float p4 = __builtin_amdgcn_exp2f(s1[0]), p5 = __builtin_amdgcn_exp2f(s1[1]);
                float p6 = __builtin_amdgcn_exp2f(s1[2]), p7 = __builtin_amdgcn_exp2f(s1[3]);
                B8U bp;   // P^T B-frag: j=0..3 <- s0 regs, j=4..7 <- s1 regs
                bp.u[0] = packbf(p0, p1);
                bp.u[1] = packbf(p2, p3);
                bp.u[2] = packbf(p4, p5);
                bp.u[3] = packbf(p6, p7);
                accO[t][0] = __builtin_amdgcn_mfma_f32_16x16x32_bf16(av0.v, bp.v, accO[t][0], 0, 0, 0);
                accO[t][1] = __builtin_amdgcn_mfma_f32_16x16x32_bf16(av1.v, bp.v, accO[t][1], 0, 0, 0);
            }
        }

        // epilogue: O^T C-layout (col l16=query, row quad*4+r=dim);
        // l = accO[t][1][0] on quad1 (dim20 ones-column)
#pragma unroll
        for (int t = 0; t < 2; ++t) {
            int nt = g * 2 + t;
            float l = __shfl(accO[t][1][0], 16 + l16, 64);
            float inv = 1.f / l;
            int tok = (MUT ? half * 128 : 0) + wave * 64 + nt * 16 + l16;
            short* orow = xout + (size_t)(wl * 256 + tok) * 240 + (MUT ? hd * 20 : 120 + hd * 20);
            unsigned lo = packbf(accO[t][0][0] * inv, accO[t][0][1] * inv);
            unsigned hi2 = packbf(accO[t][0][2] * inv, accO[t][0][3] * inv);
            *(uint2*)(orow + quad * 4) = make_uint2(lo, hi2);
            if (quad == 0) {
                unsigned lo2 = packbf(accO[t][1][0] * inv, accO[t][1][1] * inv);
                unsigned hi3 = packbf(accO[t][1][2] * inv, accO[t][1][3] * inv);
                *(uint2*)(orow + 16) = make_uint2(lo2, hi3);
            }
        }
    }
}

extern "C" void kernel_launch(void* const* d_in, const int* in_sizes, int n_in,
                              void* d_out, int out_size, void* d_ws, size_t ws_size,
                              hipStream_t stream) {
    const float* x          = (const float*)d_in[0];
    const float* norm1_w    = (const float*)d_in[1];
    const float* norm1_b    = (const float*)d_in[2];
    const float* qkv_self_w = (const float*)d_in[3];
    const float* qkv_self_b = (const float*)d_in[4];
    const float* qkv_mut_w  = (const float*)d_in[5];
    const float* qkv_mut_b  = (const float*)d_in[6];
    const float* proj_w     = (const float*)d_in[7];
    const float* proj_b     = (const float*)d_in[8];
    const float* norm2_w    = (const float*)d_in[9];
    const float* norm2_b    = (const float*)d_in[10];
    const float* fc11_w     = (const float*)d_in[11];
    const float* fc11_b     = (const float*)d_in[12];
    const float* fc12_w     = (const float*)d_in[13];
    const float* fc12_b     = (const float*)d_in[14];
    const float* fc2_w      = (const float*)d_in[15];
    const float* fc2_b      = (const float*)d_in[16];

    if (ws_size < 110100480u) return;

    char* wsb   = (char*)d_ws;
    short* Hb    = (short*)wsb;                   // 131072x120 bf16
    short* QKVc  = (short*)(wsb + 31457280);      // 3 planes, chunk
    short* XOUTc = (short*)(wsb + 78643200);      // 65536x240 bf16
    float* TMPc  = (float*)(wsb + 31457280);      // 65536x120 fp32 (over dead QKV)
    short* H2c   = (short*)(wsb + 62914560);      // 65536x120 bf16 (over dead QKV)
    short* HIDc  = (short*)(wsb + 78643200);      // 65536x240 bf16 (over dead XOUT)
    float* out   = (float*)d_out;                 // final output only

    // 1. LN1 + window partition -> Hb (bf16)
    ln_kernel<true><<<16384, 256, 0, stream>>>(x, norm1_w, norm1_b, Hb);

    // 2. Per-chunk: attention + MLP (row-local after attn; no d_out scratch)
    for (int c = 0; c < 2; ++c) {
        int m0 = c * CHROWS;
        const short* Ac = Hb + (size_t)m0 * 120;
        mm<0, 120, 360, 4, 4><<<dim3(256, 6), 256, 0, stream>>>(Ac, qkv_self_w, qkv_self_b,
                                                                QKVc, nullptr, 0);
        attn_flash<256, false><<<1536, 256, 0, stream>>>(QKVc, XOUTc);
        mm<0, 120, 360, 4, 4><<<dim3(256, 6), 256, 0, stream>>>(Ac, qkv_mut_w, qkv_mut_b,
                                                                QKVc, nullptr, 0);
        attn_flash<128, true><<<3072, 128, 0, stream>>>(QKVc, XOUTc);
        mm<1, 240, 120, 4, 4><<<dim3(256, 2), 256, 0, stream>>>(XOUTc, proj_w, proj_b,
                                                                TMPc, x, m0);
        ln_kernel<false><<<8192, 256, 0, stream>>>(TMPc, norm2_w, norm2_b, H2c);
        mm_mlp<<<dim3(512, 4), 256, 0, stream>>>(H2c, fc11_w, fc11_b,
                                                 fc12_w, fc12_b, HIDc);
        mm<4, 240, 120, 4, 4><<<dim3(256, 2), 256, 0, stream>>>(HIDc, fc2_w, fc2_b,
                                                                out, TMPc, m0);
    }
}